// Round 15
// baseline (199.213 us; speedup 1.0000x reference)
//
#include <hip/hip_runtime.h>
#include <math.h>

#define DD    128
#define DFF   256
#define NHH   4
#define HDD   32
#define BB    8
#define TT    1024
#define NTOK  (BB*TT)          // 8192
#define LDK   72               // padded LDS row stride (bf16 elements) for GEMM tiles
#define QKVN  384              // fused QKV row width

// bf16 weight workspace offsets (elements)
#define WB_MEGATE 0
#define WB_MEVAL  196608
#define WB_MEOUT  393216
#define WB_BRIN   589824
#define WB_BROUT  737280
#define WB_BRG    786432
#define WB_BRV    884736
#define WB_BRF    983040
#define WB_OUTW   1081344
#define WB_TOT    1097728

typedef __bf16 bf16x8 __attribute__((ext_vector_type(8)));
typedef float  f32x4  __attribute__((ext_vector_type(4)));

// ---------------- wave helpers (wave64) ----------------
__device__ __forceinline__ float wsum(float v){
#pragma unroll
  for(int o=32;o>0;o>>=1) v += __shfl_xor(v,o,64);
  return v;
}
__device__ __forceinline__ float wmaxr(float v){
#pragma unroll
  for(int o=32;o>0;o>>=1) v = fmaxf(v,__shfl_xor(v,o,64));
  return v;
}
__device__ __forceinline__ unsigned short f2bf(float x){
  __bf16 h = (__bf16)x;
  unsigned short u;
  __builtin_memcpy(&u, &h, 2);
  return u;
}

// stage 16 consecutive fp32 (global) -> 16 bf16 in LDS
__device__ __forceinline__ void stage16(const float* __restrict__ gp,
                                        unsigned short* __restrict__ dst){
  float4 f0 = *reinterpret_cast<const float4*>(gp);
  float4 f1 = *reinterpret_cast<const float4*>(gp+4);
  float4 f2 = *reinterpret_cast<const float4*>(gp+8);
  float4 f3 = *reinterpret_cast<const float4*>(gp+12);
  float f[16] = {f0.x,f0.y,f0.z,f0.w, f1.x,f1.y,f1.z,f1.w,
                 f2.x,f2.y,f2.z,f2.w, f3.x,f3.y,f3.z,f3.w};
  unsigned short h[16];
#pragma unroll
  for(int j=0;j<16;j++) h[j] = f2bf(f[j]);
  *reinterpret_cast<uint4*>(dst)   = *reinterpret_cast<const uint4*>(h);
  *reinterpret_cast<uint4*>(dst+8) = *reinterpret_cast<const uint4*>(h+8);
}

// stage 16 consecutive bf16 (global) -> LDS (pure copy, 2x16B)
__device__ __forceinline__ void stage16bf(const unsigned short* __restrict__ gp,
                                          unsigned short* __restrict__ dst){
  const uint4* s = reinterpret_cast<const uint4*>(gp);
  *reinterpret_cast<uint4*>(dst)   = s[0];
  *reinterpret_cast<uint4*>(dst+8) = s[1];
}

// stage 16 fp32 from registers with LN affine -> LDS bf16 (fr base must be compile-time)
__device__ __forceinline__ void stageLN(const float* __restrict__ fr,
                                        float mean, float rstd,
                                        const float* __restrict__ g,
                                        const float* __restrict__ b,
                                        unsigned short* __restrict__ dst){
  unsigned short h[16];
#pragma unroll
  for(int j=0;j<16;j++){
    float y = (fr[j]-mean)*rstd*g[j] + b[j];
    h[j] = f2bf(y);
  }
  *reinterpret_cast<uint4*>(dst)   = *reinterpret_cast<const uint4*>(h);
  *reinterpret_cast<uint4*>(dst+8) = *reinterpret_cast<const uint4*>(h+8);
}

// ---------------- one-time weight fp32->bf16 conversion (qscale folded into br_in Q rows) ----------------
__global__ __launch_bounds__(256) void wconv(
    const float* __restrict__ a0, const float* __restrict__ a1, const float* __restrict__ a2,
    const float* __restrict__ a3, const float* __restrict__ a4, const float* __restrict__ a5,
    const float* __restrict__ a6, const float* __restrict__ a7, const float* __restrict__ a8,
    unsigned short* __restrict__ dst, float qsc){
  size_t i = ((size_t)blockIdx.x*256 + threadIdx.x)*4;
  if(i >= WB_TOT) return;
  const float* s; size_t off = i; float sc = 1.0f;
  if(i < WB_MEVAL){ s=a0; }
  else if(i < WB_MEOUT){ s=a1; off = i-WB_MEVAL; }
  else if(i < WB_BRIN ){ s=a2; off = i-WB_MEOUT; }
  else if(i < WB_BROUT){ s=a3; off = i-WB_BRIN;
    int row = (int)(off>>7); if((row % 384) < 128) sc = qsc; }
  else if(i < WB_BRG ){ s=a4; off = i-WB_BROUT; }
  else if(i < WB_BRV ){ s=a5; off = i-WB_BRG; }
  else if(i < WB_BRF ){ s=a6; off = i-WB_BRV; }
  else if(i < WB_OUTW){ s=a7; off = i-WB_BRF; }
  else { s=a8; off = i-WB_OUTW; }
  float4 v = *reinterpret_cast<const float4*>(s + off);
  unsigned short h4[4] = {f2bf(v.x*sc), f2bf(v.y*sc), f2bf(v.z*sc), f2bf(v.w*sc)};
  *reinterpret_cast<uint2*>(dst + i) = *reinterpret_cast<const uint2*>(h4);
}

// ---------------- routing: one wave per token (LN fused) ----------------
__global__ __launch_bounds__(256) void routing_kernel(
    const float* __restrict__ x,
    const float* __restrict__ gr_g, const float* __restrict__ gr_b,
    const float* __restrict__ q6,   const float* __restrict__ logtemp,
    const float* __restrict__ grp_g,const float* __restrict__ grp_b,
    const float* __restrict__ gpw,  const float* __restrict__ gpb,
    float* __restrict__ gw_out, float* __restrict__ coef, float* __restrict__ part){
  __shared__ float sp[4][9];
  int lane = threadIdx.x & 63;
  int wv   = threadIdx.x >> 6;
  int t    = (blockIdx.x<<2) + wv;
  const float* xr = x + (size_t)t*DD;
  float r0 = xr[lane], r1 = xr[lane+64];
  float mn = wsum(r0+r1) * (1.0f/DD);
  float d0 = r0-mn, d1 = r1-mn;
  float vv = wsum(d0*d0 + d1*d1) * (1.0f/DD);
  float rstd = rsqrtf(vv + 1e-5f);
  float x0 = d0*rstd, x1 = d1*rstd;
  float h0 = x0*gr_g[lane]+gr_b[lane];
  float h1 = x1*gr_g[lane+64]+gr_b[lane+64];
  float sb[6];
#pragma unroll
  for(int j=0;j<6;j++){
    float p = h0*q6[j*DD+lane] + h1*q6[j*DD+lane+64];
    sb[j] = tanhf(wsum(p));
  }
  float sim = 0.f;
#pragma unroll
  for(int j=0;j<6;j++) sim += ((lane>>(5-j))&1) ? sb[j] : -sb[j];
  float temp = expf(logtemp[0]); temp = fminf(fmaxf(temp,0.1f),5.0f);
  float mx = wmaxr(sim);
  float p  = expf((sim-mx)/temp);
  float w  = p / wsum(p);
  float sh[6];
#pragma unroll
  for(int j=0;j<6;j++) sh[j] = wsum(((lane>>(5-j))&1) ? w : -w);
  const float A0[6]={0,1,1,0,1,1}, A1[6]={0,-1,0,1,0,0}, A2[6]={-1,0,-1,-1,0,-1};
  float l0=0,l1=0,l2=0;
#pragma unroll
  for(int j=0;j<6;j++){ l0+=sh[j]*A0[j]; l1+=sh[j]*A1[j]; l2+=sh[j]*A2[j]; }
  float m3 = fmaxf(l0,fmaxf(l1,l2));
  float e0=expf(l0-m3), e1=expf(l1-m3), e2=expf(l2-m3);
  float inv3 = 1.0f/(e0+e1+e2);
  float g0=e0*inv3, g1=e1*inv3, g2=e2*inv3;
  if(lane==0){ gw_out[t*3]=g0; gw_out[t*3+1]=g1; gw_out[t*3+2]=g2; }
  float gwv[3]={g0,g1,g2};
  float pw[6];
#pragma unroll
  for(int g=0; g<3; g++){
    float hg0 = x0*grp_g[g*DD+lane]    + grp_b[g*DD+lane];
    float hg1 = x1*grp_g[g*DD+lane+64] + grp_b[g*DD+lane+64];
    float q0 = wsum(hg0*gpw[(g*2+0)*DD+lane] + hg1*gpw[(g*2+0)*DD+lane+64]) + gpb[g*2+0];
    float q1 = wsum(hg0*gpw[(g*2+1)*DD+lane] + hg1*gpw[(g*2+1)*DD+lane+64]) + gpb[g*2+1];
    float mm = fmaxf(q0,q1);
    float a0 = expf(q0-mm), a1 = expf(q1-mm);
    float inv = 1.0f/(a0+a1);
    float w0 = a0*inv, w1 = a1*inv;
    pw[g*2]=w0; pw[g*2+1]=w1;
    float invs = 1.0f/(w0+w1+1e-8f);
    if(lane==0){
      coef[(size_t)(2*g  )*NTOK + t] = gwv[g]*w0*invs;
      coef[(size_t)(2*g+1)*NTOK + t] = gwv[g]*w1*invs;
    }
  }
  if(lane==0){
    sp[wv][0]=g0; sp[wv][1]=g1; sp[wv][2]=g2;
#pragma unroll
    for(int k=0;k<6;k++) sp[wv][3+k]=pw[k];
  }
  __syncthreads();
  if(threadIdx.x<9){
    part[blockIdx.x*9+threadIdx.x] =
      sp[0][threadIdx.x]+sp[1][threadIdx.x]+sp[2][threadIdx.x]+sp[3][threadIdx.x];
  }
}

// ---------------- load-balance loss reduce (deterministic, parallel) ----------------
__global__ __launch_bounds__(256) void lb_kernel(const float* __restrict__ part, float* __restrict__ outlb){
  __shared__ float sm[4][9];
  float acc[9] = {};
  for(int i=threadIdx.x; i<2048; i+=256){
#pragma unroll
    for(int c=0;c<9;c++) acc[c] += part[i*9+c];
  }
#pragma unroll
  for(int c=0;c<9;c++) acc[c] = wsum(acc[c]);
  int wv = threadIdx.x>>6, lane = threadIdx.x&63;
  if(lane==0){
#pragma unroll
    for(int c=0;c<9;c++) sm[wv][c]=acc[c];
  }
  __syncthreads();
  if(threadIdx.x==0){
    const float invN = 1.0f/(float)NTOK;
    float lb=0;
#pragma unroll
    for(int c=0;c<9;c++){
      float s = sm[0][c]+sm[1][c]+sm[2][c]+sm[3][c];
      float mw = s*invN;
      lb -= mw*logf(mw+1e-8f);
    }
    outlb[0] = lb*0.01f;
  }
}

// ---------------- bf16 MFMA GEMM, BM=128 x BN=64, 512 threads (8 waves, 4x2 of 32x32) ----------------
// MODE 0: store (OBF->bf16)  3: resid+acc  5: BW*sigmoid(gptr[0])*(resid+acc)
// LN=1: K==128, A fp32, LN fused. SUM=1 (with LN): A-row = sum of 3 go + 3 bsum rows.
// ABF=1: A bf16. PSEL/RSEL: 0 = z*stride, 1 = pairsA[z], 2 = pairsB[z].
// QKV=1: blockIdx.x<2 -> Q (pairsA A, sv/bv LN), else KV (pairsB A, resid/gptr LN).
template<int MODE,int LN,int ABF,int OBF,int PSEL,int RSEL,int SUM,int QKV>
__global__ __launch_bounds__(512) void gemm_mfma(
    const void* __restrict__ Ap, const unsigned short* __restrict__ W, void* __restrict__ Cp,
    int M, int N, int K,
    const float* __restrict__ sv, const float* __restrict__ bv,
    const float* __restrict__ resid, const float* __restrict__ gptr,
    size_t az, size_t wz, size_t cz, size_t pz, size_t rz, size_t gz){
  __shared__ unsigned short As[128*LDK];
  __shared__ unsigned short Ws[64*LDK];
  const int z = blockIdx.z;
  const float* A = (const float*)Ap;
  const unsigned short* Ab = (const unsigned short*)Ap;
  if(QKV){
    bool isQ = (blockIdx.x < 2);
    int s = isQ ? ((z==1)?1:0) : ((z==0)?1:2);
    A += (size_t)s*NTOK*DD;
    if(!isQ){ sv = resid; bv = gptr; }
  } else if(PSEL==0){ A += z*az; Ab += z*az; }
  else if(PSEL==1){ int s = (z==1)?1:0; A += (size_t)s*NTOK*DD; Ab += (size_t)s*NTOK*DD; }
  else            { int s = (z==0)?1:2; A += (size_t)s*NTOK*DD; Ab += (size_t)s*NTOK*DD; }
  W += z*wz;
  float* C = (float*)Cp + z*cz;
  unsigned short* Cb = (unsigned short*)Cp + z*cz;
  const float* rs = resid;
  if(RSEL==0) rs += z*rz;
  else { int s = (z==1)?1:0; rs += (size_t)s*NTOK*DD; }
  sv += z*pz; bv += z*pz;
  const float* gp2 = gptr + z*gz;
  int tid  = threadIdx.x;
  int m0   = blockIdx.y*128, n0 = blockIdx.x*64;
  int w    = tid>>6, lane = tid&63;
  int wr   = (w>>1)*32, wc = (w&1)*32;
  int r    = tid>>2, seg = (tid&3)*16;      // r: 0..127 (A rows)
  f32x4 acc[2][2] = {};
  auto step = [&](){
#pragma unroll
    for(int kk=0;kk<64;kk+=32){
      int ko = kk + (lane>>4)*8;
      bf16x8 a0 = *reinterpret_cast<const bf16x8*>(&As[(wr    + (lane&15))*LDK + ko]);
      bf16x8 a1 = *reinterpret_cast<const bf16x8*>(&As[(wr+16 + (lane&15))*LDK + ko]);
      bf16x8 b0 = *reinterpret_cast<const bf16x8*>(&Ws[(wc    + (lane&15))*LDK + ko]);
      bf16x8 b1 = *reinterpret_cast<const bf16x8*>(&Ws[(wc+16 + (lane&15))*LDK + ko]);
      acc[0][0] = __builtin_amdgcn_mfma_f32_16x16x32_bf16(a0,b0,acc[0][0],0,0,0);
      acc[0][1] = __builtin_amdgcn_mfma_f32_16x16x32_bf16(a0,b1,acc[0][1],0,0,0);
      acc[1][0] = __builtin_amdgcn_mfma_f32_16x16x32_bf16(a1,b0,acc[1][0],0,0,0);
      acc[1][1] = __builtin_amdgcn_mfma_f32_16x16x32_bf16(a1,b1,acc[1][1],0,0,0);
    }
  };
  if(LN){
    float fr[32]; float mean, rstd;
    if(SUM){
#pragma unroll
      for(int j=0;j<32;j++) fr[j]=0.f;
#pragma unroll
      for(int s=0;s<3;s++){
        const float* r1 = A     + (size_t)s*NTOK*DD + (size_t)(m0+r)*K + seg;
        const float* r2 = resid + (size_t)s*NTOK*DD + (size_t)(m0+r)*K + seg;
#pragma unroll
        for(int j=0;j<4;j++){
          float4 v1 = *reinterpret_cast<const float4*>(r1 + j*4);
          float4 v2 = *reinterpret_cast<const float4*>(r2 + j*4);
          fr[j*4]+=v1.x+v2.x; fr[j*4+1]+=v1.y+v2.y; fr[j*4+2]+=v1.z+v2.z; fr[j*4+3]+=v1.w+v2.w;
          float4 w1 = *reinterpret_cast<const float4*>(r1 + 64 + j*4);
          float4 w2 = *reinterpret_cast<const float4*>(r2 + 64 + j*4);
          fr[16+j*4]+=w1.x+w2.x; fr[16+j*4+1]+=w1.y+w2.y; fr[16+j*4+2]+=w1.z+w2.z; fr[16+j*4+3]+=w1.w+w2.w;
        }
      }
    } else {
      const float* arow = A + (size_t)(m0+r)*K + seg;   // K==128
#pragma unroll
      for(int j=0;j<4;j++) *reinterpret_cast<float4*>(&fr[j*4])    = *reinterpret_cast<const float4*>(arow + j*4);
#pragma unroll
      for(int j=0;j<4;j++) *reinterpret_cast<float4*>(&fr[16+j*4]) = *reinterpret_cast<const float4*>(arow + 64 + j*4);
    }
    float s1=0.f, s2=0.f;
#pragma unroll
    for(int j=0;j<32;j++){ s1 += fr[j]; s2 += fr[j]*fr[j]; }
    s1 += __shfl_xor(s1,1,64); s1 += __shfl_xor(s1,2,64);
    s2 += __shfl_xor(s2,1,64); s2 += __shfl_xor(s2,2,64);
    mean = s1*(1.0f/DD);
    float var = s2*(1.0f/DD) - mean*mean;
    rstd = rsqrtf(var + 1e-5f);
#pragma unroll
    for(int kh=0; kh<2; ++kh){            // static unroll: fr index compile-time
      __syncthreads();
      stageLN(fr + kh*16, mean, rstd, sv + kh*64 + seg, bv + kh*64 + seg, &As[r*LDK + seg]);
      if(tid < 256) stage16bf(W + (size_t)(n0+r)*K + kh*64 + seg, &Ws[r*LDK + seg]);
      __syncthreads();
      step();
    }
  } else {
    for(int k0=0;k0<K;k0+=64){
      __syncthreads();
      if(ABF) stage16bf(Ab + (size_t)(m0+r)*K + k0 + seg, &As[r*LDK + seg]);
      else    stage16(A  + (size_t)(m0+r)*K + k0 + seg, &As[r*LDK + seg]);
      if(tid < 256) stage16bf(W + (size_t)(n0+r)*K + k0 + seg, &Ws[r*LDK + seg]);
      __syncthreads();
      step();
    }
  }
#pragma unroll
  for(int i=0;i<2;i++){
#pragma unroll
    for(int j=0;j<2;j++){
      int mb = m0 + wr + i*16 + (lane>>4)*4;
      int n  = n0 + wc + j*16 + (lane&15);
#pragma unroll
      for(int rg=0;rg<4;rg++){
        int m = mb + rg;
        float v = acc[i][j][rg];
        size_t o = (size_t)m*N + n;
        if(MODE==0){ if(OBF) Cb[o] = f2bf(v); else C[o] = v; }
        else if(MODE==3){ C[o] = rs[o] + v; }
        else if(MODE==5){
          float gs = (0.5f/3.0f)/(1.0f+expf(-gp2[0]));
          C[o] = gs*(rs[o]+v);
        }
      }
    }
  }
}

// ---------------- dual-W bf16 MFMA GEMM, BM=128 x BN=64, 512 threads ----------------
__global__ __launch_bounds__(512) void gemm_dual(
    const float* __restrict__ A, const unsigned short* __restrict__ G,
    const unsigned short* __restrict__ V,
    unsigned short* __restrict__ C, int M, int N, int K,
    const float* __restrict__ sv, const float* __restrict__ bv,
    size_t az, size_t wz, size_t cz, size_t pz){
  __shared__ unsigned short As[128*LDK];
  __shared__ unsigned short Gs[64*LDK];
  __shared__ unsigned short Vs[64*LDK];
  const int z = blockIdx.z;
  A += z*az; G += z*wz; V += z*wz; C += z*cz; sv += z*pz; bv += z*pz;
  int tid  = threadIdx.x;
  int m0   = blockIdx.y*128, n0 = blockIdx.x*64;
  int w    = tid>>6, lane = tid&63;
  int wr   = (w>>1)*32, wc = (w&1)*32;
  int r    = tid>>2, seg = (tid&3)*16;
  f32x4 accg[2][2] = {};
  f32x4 accv[2][2] = {};
  float fr[32]; float mean, rstd;
  {
    const float* arow = A + (size_t)(m0+r)*K + seg;   // K==128
#pragma unroll
    for(int j=0;j<4;j++) *reinterpret_cast<float4*>(&fr[j*4])    = *reinterpret_cast<const float4*>(arow + j*4);
#pragma unroll
    for(int j=0;j<4;j++) *reinterpret_cast<float4*>(&fr[16+j*4]) = *reinterpret_cast<const float4*>(arow + 64 + j*4);
    float s1=0.f, s2=0.f;
#pragma unroll
    for(int j=0;j<32;j++){ s1 += fr[j]; s2 += fr[j]*fr[j]; }
    s1 += __shfl_xor(s1,1,64); s1 += __shfl_xor(s1,2,64);
    s2 += __shfl_xor(s2,1,64); s2 += __shfl_xor(s2,2,64);
    mean = s1*(1.0f/DD);
    float var = s2*(1.0f/DD) - mean*mean;
    rstd = rsqrtf(var + 1e-5f);
  }
#pragma unroll
  for(int kh=0; kh<2; ++kh){              // static unroll: fr index compile-time
    int k0 = kh*64;
    __syncthreads();
    stageLN(fr + kh*16, mean, rstd, sv + k0 + seg, bv + k0 + seg, &As[r*LDK + seg]);
    if(tid < 256){
      stage16bf(G + (size_t)(n0+r)*K + k0 + seg, &Gs[r*LDK + seg]);
      stage16bf(V + (size_t)(n0+r)*K + k0 + seg, &Vs[r*LDK + seg]);
    }
    __syncthreads();
#pragma unroll
    for(int kk=0;kk<64;kk+=32){
      int ko = kk + (lane>>4)*8;
      bf16x8 a0 = *reinterpret_cast<const bf16x8*>(&As[(wr    + (lane&15))*LDK + ko]);
      bf16x8 a1 = *reinterpret_cast<const bf16x8*>(&As[(wr+16 + (lane&15))*LDK + ko]);
      bf16x8 g0 = *reinterpret_cast<const bf16x8*>(&Gs[(wc    + (lane&15))*LDK + ko]);
      bf16x8 g1 = *reinterpret_cast<const bf16x8*>(&Gs[(wc+16 + (lane&15))*LDK + ko]);
      bf16x8 v0 = *reinterpret_cast<const bf16x8*>(&Vs[(wc    + (lane&15))*LDK + ko]);
      bf16x8 v1 = *reinterpret_cast<const bf16x8*>(&Vs[(wc+16 + (lane&15))*LDK + ko]);
      accg[0][0] = __builtin_amdgcn_mfma_f32_16x16x32_bf16(a0,g0,accg[0][0],0,0,0);
      accg[0][1] = __builtin_amdgcn_mfma_f32_16x16x32_bf16(a0,g1,accg[0][1],0,0,0);
      accg[1][0] = __builtin_amdgcn_mfma_f32_16x16x32_bf16(a1,g0,accg[1][0],0,0,0);
      accg[1][1] = __builtin_amdgcn_mfma_f32_16x16x32_bf16(a1,g1,accg[1][1],0,0,0);
      accv[0][0] = __builtin_amdgcn_mfma_f32_16x16x32_bf16(a0,v0,accv[0][0],0,0,0);
      accv[0][1] = __builtin_amdgcn_mfma_f32_16x16x32_bf16(a0,v1,accv[0][1],0,0,0);
      accv[1][0] = __builtin_amdgcn_mfma_f32_16x16x32_bf16(a1,v0,accv[1][0],0,0,0);
      accv[1][1] = __builtin_amdgcn_mfma_f32_16x16x32_bf16(a1,v1,accv[1][1],0,0,0);
    }
  }
#pragma unroll
  for(int i=0;i<2;i++){
#pragma unroll
    for(int j=0;j<2;j++){
      int mb = m0 + wr + i*16 + (lane>>4)*4;
      int n  = n0 + wc + j*16 + (lane&15);
#pragma unroll
      for(int rg=0;rg<4;rg++){
        float gg = accg[i][j][rg];
        float vv = accv[i][j][rg];
        float sg = gg/(1.0f+expf(-gg));
        C[(size_t)(mb+rg)*N + n] = f2bf(sg*vv);
      }
    }
  }
}

// ---------------- MoE pair-combine GEMM, BM=128 x BN=64, 512 threads: K=DFF ----------------
__global__ __launch_bounds__(512) void gemm_moe2(
    const unsigned short* __restrict__ Ab, const unsigned short* __restrict__ Wb,
    float* __restrict__ Cb, const float* __restrict__ coef){
  __shared__ unsigned short As0[128*LDK];
  __shared__ unsigned short As1[128*LDK];
  __shared__ unsigned short Ws0[64*LDK];
  __shared__ unsigned short Ws1[64*LDK];
  const int g = blockIdx.z;
  const unsigned short* A0 = Ab + (size_t)(2*g)*NTOK*DFF;
  const unsigned short* A1 = A0 + (size_t)NTOK*DFF;
  const unsigned short* W0 = Wb + (size_t)(2*g)*DD*DFF;
  const unsigned short* W1 = W0 + (size_t)DD*DFF;
  float* C = Cb + (size_t)g*NTOK*DD;
  const float* c0 = coef + (size_t)(2*g)*NTOK;
  const float* c1 = c0 + NTOK;
  int tid  = threadIdx.x;
  int m0   = blockIdx.y*128, n0 = blockIdx.x*64;
  int w    = tid>>6, lane = tid&63;
  int wr   = (w>>1)*32, wc = (w&1)*32;
  int r    = tid>>2, seg = (tid&3)*16;
  f32x4 a0acc[2][2] = {};
  f32x4 a1acc[2][2] = {};
  for(int k0=0;k0<DFF;k0+=64){
    __syncthreads();
    stage16bf(A0 + (size_t)(m0+r)*DFF + k0 + seg, &As0[r*LDK + seg]);
    stage16bf(A1 + (size_t)(m0+r)*DFF + k0 + seg, &As1[r*LDK + seg]);
    if(tid < 256){
      stage16bf(W0 + (size_t)(n0+r)*DFF + k0 + seg, &Ws0[r*LDK + seg]);
      stage16bf(W1 + (size_t)(n0+r)*DFF + k0 + seg, &Ws1[r*LDK + seg]);
    }
    __syncthreads();
#pragma unroll
    for(int kk=0;kk<64;kk+=32){
      int ko = kk + (lane>>4)*8;
      bf16x8 x00 = *reinterpret_cast<const bf16x8*>(&As0[(wr    + (lane&15))*LDK + ko]);
      bf16x8 x01 = *reinterpret_cast<const bf16x8*>(&As0[(wr+16 + (lane&15))*LDK + ko]);
      bf16x8 x10 = *reinterpret_cast<const bf16x8*>(&As1[(wr    + (lane&15))*LDK + ko]);
      bf16x8 x11 = *reinterpret_cast<const bf16x8*>(&As1[(wr+16 + (lane&15))*LDK + ko]);
      bf16x8 w00 = *reinterpret_cast<const bf16x8*>(&Ws0[(wc    + (lane&15))*LDK + ko]);
      bf16x8 w01 = *reinterpret_cast<const bf16x8*>(&Ws0[(wc+16 + (lane&15))*LDK + ko]);
      bf16x8 w10 = *reinterpret_cast<const bf16x8*>(&Ws1[(wc    + (lane&15))*LDK + ko]);
      bf16x8 w11 = *reinterpret_cast<const bf16x8*>(&Ws1[(wc+16 + (lane&15))*LDK + ko]);
      a0acc[0][0] = __builtin_amdgcn_mfma_f32_16x16x32_bf16(x00,w00,a0acc[0][0],0,0,0);
      a0acc[0][1] = __builtin_amdgcn_mfma_f32_16x16x32_bf16(x00,w01,a0acc[0][1],0,0,0);
      a0acc[1][0] = __builtin_amdgcn_mfma_f32_16x16x32_bf16(x01,w00,a0acc[1][0],0,0,0);
      a0acc[1][1] = __builtin_amdgcn_mfma_f32_16x16x32_bf16(x01,w01,a0acc[1][1],0,0,0);
      a1acc[0][0] = __builtin_amdgcn_mfma_f32_16x16x32_bf16(x10,w10,a1acc[0][0],0,0,0);
      a1acc[0][1] = __builtin_amdgcn_mfma_f32_16x16x32_bf16(x10,w11,a1acc[0][1],0,0,0);
      a1acc[1][0] = __builtin_amdgcn_mfma_f32_16x16x32_bf16(x11,w10,a1acc[1][0],0,0,0);
      a1acc[1][1] = __builtin_amdgcn_mfma_f32_16x16x32_bf16(x11,w11,a1acc[1][1],0,0,0);
    }
  }
#pragma unroll
  for(int i=0;i<2;i++){
#pragma unroll
    for(int j=0;j<2;j++){
      int mb = m0 + wr + i*16 + (lane>>4)*4;
      int n  = n0 + wc + j*16 + (lane&15);
#pragma unroll
      for(int rg=0;rg<4;rg++){
        int m = mb + rg;
        C[(size_t)m*DD + n] = c0[m]*a0acc[i][j][rg] + c1[m]*a1acc[i][j][rg];
      }
    }
  }
}

// ---------------- fused MFMA flash attention: 16 q-rows/wave, full KV per block ----------------
// grid (16, NH, 24): bx = q-block (64 rows); z = b + 8*bridge. Writes normalized bf16 obuf.
#define PSW(row) (((row)&8)<<1)              // Ps col ^= 16 when row bit3 set
#define VSW(row) ((((row)>>3)&3)<<3)         // Vt col ^= 8*((row>>3)&3)
__global__ __launch_bounds__(256) void attn_fused(
    const unsigned short* __restrict__ qkv,
    unsigned short* __restrict__ obuf){
  __shared__ __align__(16) unsigned short Ks[64*40];
  __shared__ __align__(16) unsigned short Vt[48*72];
  __shared__ __align__(16) unsigned short Ps[4][16*72];
  const int tid = threadIdx.x;
  const int w = tid>>6, lane = tid&63;
  const int lr = lane&15, lg = lane>>4;
  const int bx = blockIdx.x;
  const int h = blockIdx.y;
  const int b = blockIdx.z & 7, br = blockIdx.z >> 3;
  const int qtok0 = b*TT + bx*64 + w*16;
  for(int idx=tid; idx<16*72; idx+=256)
    Vt[32*72 + idx] = (idx < 64) ? (unsigned short)0x3F80 : (unsigned short)0;
  const unsigned short* qp = qkv + (size_t)br*NTOK*QKVN + (size_t)(qtok0 + lr)*QKVN + h*HDD + lg*8;
  bf16x8 qa = *reinterpret_cast<const bf16x8*>(qp);
  f32x4 o0 = {}, o1 = {}, o2 = {};
  float m[4] = {-1e30f,-1e30f,-1e30f,-1e30f};
  const unsigned short* KVbase = qkv + (size_t)br*NTOK*QKVN + (size_t)(b*TT)*QKVN + DD + h*HDD;

  for(int t0=0; t0<TT; t0+=64){
    __syncthreads();
#pragma unroll
    for(int s2=0;s2<2;s2++){
      int i   = tid + s2*256;
      int key = i>>3, seg = (i&7)*4;
      const unsigned short* src = KVbase + (size_t)(t0+key)*QKVN + seg;
      *reinterpret_cast<uint2*>(&Ks[key*40+seg]) = *reinterpret_cast<const uint2*>(src);
      unsigned short vs[4];
      *reinterpret_cast<uint2*>(vs) = *reinterpret_cast<const uint2*>(src + DD);
      const int kc = key ^ VSW(seg);
      Vt[(seg  )*72+kc] = vs[0];
      Vt[(seg+1)*72+kc] = vs[1];
      Vt[(seg+2)*72+kc] = vs[2];
      Vt[(seg+3)*72+kc] = vs[3];
    }
    __syncthreads();
    f32x4 s[4];
#pragma unroll
    for(int f=0;f<4;f++){
      bf16x8 kb = *reinterpret_cast<const bf16x8*>(&Ks[(f*16+lr)*40 + lg*8]);
      f32x4 z = {};
      s[f] = __builtin_amdgcn_mfma_f32_16x16x32_bf16(qa,kb,z,0,0,0);
    }
    float tmax[4]; bool need=false;
#pragma unroll
    for(int r=0;r<4;r++){
      tmax[r] = fmaxf(fmaxf(s[0][r],s[1][r]),fmaxf(s[2][r],s[3][r]));
      need = need || (tmax[r] > m[r] + 8.0f);
    }
    if(__any(need)){
#pragma unroll
      for(int r=0;r<4;r++){
        float t = tmax[r];
#pragma unroll
        for(int off=1;off<16;off<<=1) t = fmaxf(t,__shfl_xor(t,off,64));
        float nm = fmaxf(m[r],t);
        float sc = __builtin_amdgcn_exp2f(m[r]-nm);
        m[r] = nm; o0[r] *= sc; o1[r] *= sc; o2[r] *= sc;
      }
    }
#pragma unroll
    for(int r=0;r<4;r++){
      const int q = lg*4+r;
      const int cw = PSW(q);
#pragma unroll
      for(int f=0;f<4;f++){
        float p = __builtin_amdgcn_exp2f(s[f][r]-m[r]);
        Ps[w][q*72 + ((f*16+lr)^cw)] = f2bf(p);
      }
    }
    const int pw_ = PSW(lr);
    bf16x8 pa0 = *reinterpret_cast<const bf16x8*>(&Ps[w][lr*72 + ((lg*8   )^pw_)]);
    bf16x8 pa1 = *reinterpret_cast<const bf16x8*>(&Ps[w][lr*72 + ((lg*8+32)^pw_)]);
    {
      const int r_ = lr, vw = VSW(r_);
      bf16x8 vb0 = *reinterpret_cast<const bf16x8*>(&Vt[r_*72 + ((lg*8   )^vw)]);
      bf16x8 vb1 = *reinterpret_cast<const bf16x8*>(&Vt[r_*72 + ((lg*8+32)^vw)]);
      o0 = __builtin_amdgcn_mfma_f32_16x16x32_bf16(pa0,vb0,o0,0,0,0);
      o0 = __builtin_amdgcn_mfma_f32_16x16x32_bf16(pa1,vb1,o0,0,0,0);
    }
    {
      const int r_ = 16+lr, vw = VSW(r_);
      bf16x8 vb0 = *reinterpret_cast<const bf16x8*>(&Vt[r_*72 + ((lg*8   )^vw)]);
      bf16x8 vb1 = *reinterpret_cast<const bf16x8*>(&Vt[r_*72 + ((lg*8+32)^vw)]);
      o1 = __builtin_amdgcn_mfma_f32_16x16x32_bf16(pa0,vb0,o1,0,0,0);
      o1 = __builtin_amdgcn_mfma_f32_16x16x32_bf16(pa1,vb1,o1,0,0,0);
    }
    {
      const int r_ = 32+lr, vw = VSW(r_);
      bf16x8 vb0 = *reinterpret_cast<const bf16x8*>(&Vt[r_*72 + ((lg*8   )^vw)]);
      bf16x8 vb1 = *reinterpret_cast<const bf16x8*>(&Vt[r_*72 + ((lg*8+32)^vw)]);
      o2 = __builtin_amdgcn_mfma_f32_16x16x32_bf16(pa0,vb0,o2,0,0,0);
      o2 = __builtin_amdgcn_mfma_f32_16x16x32_bf16(pa1,vb1,o2,0,0,0);
    }
  }
#pragma unroll
  for(int r=0;r<4;r++){
    float lsr = __shfl(o2[r], lane & 48, 64);   // broadcast col-0 (row-sum)
    float inv = 1.0f/lsr;
    int row = qtok0 + lg*4 + r;
    unsigned short* orow = obuf + (size_t)br*NTOK*DD + (size_t)row*DD + h*HDD;
    orow[lr]    = f2bf(o0[r]*inv);
    orow[16+lr] = f2bf(o1[r]*inv);
  }
}

// ---------------- launch ----------------
extern "C" void kernel_launch(void* const* d_in, const int* in_sizes, int n_in,
                              void* d_out, int out_size, void* d_ws, size_t ws_size,
                              hipStream_t stream){
  (void)in_sizes; (void)n_in; (void)out_size; (void)ws_size;
  const float* x       = (const float*)d_in[0];
  const float* gr_g    = (const float*)d_in[1];
  const float* gr_b    = (const float*)d_in[2];
  const float* q6_w    = (const float*)d_in[3];
  const float* logtemp = (const float*)d_in[4];
  const float* grp_g   = (const float*)d_in[5];
  const float* grp_b   = (const float*)d_in[6];
  const float* gpw     = (const float*)d_in[7];
  const float* gpb     = (const float*)d_in[8];
  const float* me_g    = (const float*)d_in[9];
  const float* me_b    = (const float*)d_in[10];
  const float* me_gate = (const float*)d_in[11];
  const float* me_val  = (const float*)d_in[12];
  const float* me_out  = (const float*)d_in[13];
  const float* br_in   = (const float*)d_in[14];
  const float* br_outw = (const float*)d_in[15];
  const float* nq_g    = (const float*)d_in[16];
  const float* nq_b    = (const float*)d_in[17];
  const float* nkv_g   = (const float*)d_in[18];
  const float* nkv_b   = (const float*)d_in[19];
  const float* nff_g   = (const float*)d_in[20];
  const float* nff_b   = (const float*)d_in[21];
  const float* brg_w   = (const float*)d_in[22];
  const float* brv_w   = (const float*)d_in[23];
  const float* brf_w   = (const float*)d_in[24];
  const float* br_gate = (const float*)d_in[25];
  const float* on_g    = (const float*)d_in[26];
  const float* on_b    = (const float*)d_in[27];
  const float* out_w   = (const float*)d_in[28];
  float* out = (float*)d_out;
  float* ws  = (float*)d_ws;

  float* coef  = ws;                                        // 49152
  float* part  = ws + 65536;                                // 18432
  unsigned short* gvb6 = (unsigned short*)(ws + 131072);    // 6*8192*256 bf16
  float* go    = ws + 6731072;                              // 3*1048576 fp32
  unsigned short* qkv  = (unsigned short*)(ws + 9900000);   // 3*8192*384 bf16
  unsigned short* obuf = (unsigned short*)(ws + 14700000);  // 3*8192*128 bf16
  unsigned short* wbf  = (unsigned short*)(ws + 21400000);  // WB_TOT bf16 weights
  float* xb    = ws + 23000000;                             // 3*1048576 fp32
  unsigned short* gvb2 = (unsigned short*)(ws + 26200000);  // 3*8192*256 bf16
  float* bsum  = ws + 29400000;                             // 3*1048576 fp32
  float* gw    = ws + 32700000;                             // 24576

  // 1/sqrt(32) * log2(e): softmax runs in the exp2 domain (folded into Q weights)
  const float qscale = 0.17677669529663687f * 1.4426950408889634f;

  // 0. one-time weight conversion fp32 -> bf16 (qscale folded into br_in Q rows)
  wconv<<<1072,256,0,stream>>>(me_gate, me_val, me_out, br_in, br_outw,
                               brg_w, brv_w, brf_w, out_w, wbf, qscale);

  // 1. routing (fused LN) + lb
  routing_kernel<<<2048,256,0,stream>>>(x, gr_g, gr_b, q6_w, logtemp,
                                        grp_g, grp_b, gpw, gpb, gw, coef, part);
  lb_kernel<<<1,256,0,stream>>>(part, out + 1048576);

  // 2. MoE: all 6 experts in one dual dispatch; pair-combine into go (z=group)
  gemm_dual<<<dim3(4,64,6),512,0,stream>>>(x, wbf+WB_MEGATE, wbf+WB_MEVAL, gvb6,
      NTOK,DFF,DD, me_g, me_b, 0, (size_t)DFF*DD, (size_t)NTOK*DFF, DD);
  gemm_moe2<<<dim3(2,64,3),512,0,stream>>>(gvb6, wbf+WB_MEOUT, go, coef);

  // 3. bridges: fused QKV projection, attn (full-KV, bf16 out), out-proj+resid, FFN, bridge-scale
  gemm_mfma<0,1,0,1,0,0,0,1><<<dim3(6,64,3),512,0,stream>>>(go, wbf+WB_BRIN, qkv,
      NTOK,QKVN,DD, nq_g, nq_b, nkv_g, nkv_b,
      0, (size_t)QKVN*DD, (size_t)NTOK*QKVN, DD, 0, 0);
  attn_fused<<<dim3(16,NHH,24),256,0,stream>>>(qkv, obuf);
  gemm_mfma<3,0,1,0,0,1,0,0><<<dim3(2,64,3),512,0,stream>>>(obuf, wbf+WB_BROUT, xb,
      NTOK,DD,DD, nullptr, nullptr, go, nullptr,
      (size_t)NTOK*DD, (size_t)DD*DD, (size_t)NTOK*DD, 0, 0, 0);
  gemm_dual<<<dim3(4,64,3),512,0,stream>>>(xb, wbf+WB_BRG, wbf+WB_BRV, gvb2,
      NTOK,2*DD,DD, nff_g, nff_b, (size_t)NTOK*DD, (size_t)2*DD*DD, (size_t)NTOK*2*DD, DD);
  gemm_mfma<5,0,1,0,0,0,0,0><<<dim3(2,64,3),512,0,stream>>>(gvb2, wbf+WB_BRF, bsum,
      NTOK,DD,2*DD, nullptr, nullptr, xb, br_gate,
      (size_t)NTOK*2*DD, (size_t)DD*2*DD, (size_t)NTOK*DD, 0, (size_t)NTOK*DD, 1);

  // 4. final: LN over (go0+go1+go2+bsum0+bsum1+bsum2), projection
  gemm_mfma<0,1,0,0,0,0,1,0><<<dim3(2,64,1),512,0,stream>>>(go, wbf+WB_OUTW, out,
      NTOK,DD,DD, on_g, on_b, bsum, nullptr,
      0, 0, 0, 0, 0, 0);
}

// Round 16
// 193.504 us; speedup vs baseline: 1.0295x; 1.0295x over previous
//
#include <hip/hip_runtime.h>
#include <math.h>

#define DD    128
#define DFF   256
#define NHH   4
#define HDD   32
#define BB    8
#define TT    1024
#define NTOK  (BB*TT)          // 8192
#define LDK   72               // padded LDS row stride (bf16 elements) for GEMM tiles
#define QKVN  384              // fused QKV row width

// bf16 weight workspace offsets (elements)
#define WB_MEGATE 0
#define WB_MEVAL  196608
#define WB_MEOUT  393216
#define WB_BRIN   589824
#define WB_BROUT  737280
#define WB_BRG    786432
#define WB_BRV    884736
#define WB_BRF    983040
#define WB_OUTW   1081344
#define WB_TOT    1097728

typedef __bf16 bf16x8 __attribute__((ext_vector_type(8)));
typedef float  f32x4  __attribute__((ext_vector_type(4)));

// ---------------- wave helpers (wave64) ----------------
__device__ __forceinline__ float wsum(float v){
#pragma unroll
  for(int o=32;o>0;o>>=1) v += __shfl_xor(v,o,64);
  return v;
}
__device__ __forceinline__ float wmaxr(float v){
#pragma unroll
  for(int o=32;o>0;o>>=1) v = fmaxf(v,__shfl_xor(v,o,64));
  return v;
}
__device__ __forceinline__ unsigned short f2bf(float x){
  __bf16 h = (__bf16)x;
  unsigned short u;
  __builtin_memcpy(&u, &h, 2);
  return u;
}

// stage 16 consecutive fp32 (global) -> 16 bf16 in LDS
__device__ __forceinline__ void stage16(const float* __restrict__ gp,
                                        unsigned short* __restrict__ dst){
  float4 f0 = *reinterpret_cast<const float4*>(gp);
  float4 f1 = *reinterpret_cast<const float4*>(gp+4);
  float4 f2 = *reinterpret_cast<const float4*>(gp+8);
  float4 f3 = *reinterpret_cast<const float4*>(gp+12);
  float f[16] = {f0.x,f0.y,f0.z,f0.w, f1.x,f1.y,f1.z,f1.w,
                 f2.x,f2.y,f2.z,f2.w, f3.x,f3.y,f3.z,f3.w};
  unsigned short h[16];
#pragma unroll
  for(int j=0;j<16;j++) h[j] = f2bf(f[j]);
  *reinterpret_cast<uint4*>(dst)   = *reinterpret_cast<const uint4*>(h);
  *reinterpret_cast<uint4*>(dst+8) = *reinterpret_cast<const uint4*>(h+8);
}

// stage 16 consecutive bf16 (global) -> LDS (pure copy, 2x16B)
__device__ __forceinline__ void stage16bf(const unsigned short* __restrict__ gp,
                                          unsigned short* __restrict__ dst){
  const uint4* s = reinterpret_cast<const uint4*>(gp);
  *reinterpret_cast<uint4*>(dst)   = s[0];
  *reinterpret_cast<uint4*>(dst+8) = s[1];
}

// stage 16 fp32 from registers with LN affine -> LDS bf16 (fr base must be compile-time)
__device__ __forceinline__ void stageLN(const float* __restrict__ fr,
                                        float mean, float rstd,
                                        const float* __restrict__ g,
                                        const float* __restrict__ b,
                                        unsigned short* __restrict__ dst){
  unsigned short h[16];
#pragma unroll
  for(int j=0;j<16;j++){
    float y = (fr[j]-mean)*rstd*g[j] + b[j];
    h[j] = f2bf(y);
  }
  *reinterpret_cast<uint4*>(dst)   = *reinterpret_cast<const uint4*>(h);
  *reinterpret_cast<uint4*>(dst+8) = *reinterpret_cast<const uint4*>(h+8);
}

// ---------------- one-time weight fp32->bf16 conversion (qscale folded into br_in Q rows) ----------------
__global__ __launch_bounds__(256) void wconv(
    const float* __restrict__ a0, const float* __restrict__ a1, const float* __restrict__ a2,
    const float* __restrict__ a3, const float* __restrict__ a4, const float* __restrict__ a5,
    const float* __restrict__ a6, const float* __restrict__ a7, const float* __restrict__ a8,
    unsigned short* __restrict__ dst, float qsc){
  size_t i = ((size_t)blockIdx.x*256 + threadIdx.x)*4;
  if(i >= WB_TOT) return;
  const float* s; size_t off = i; float sc = 1.0f;
  if(i < WB_MEVAL){ s=a0; }
  else if(i < WB_MEOUT){ s=a1; off = i-WB_MEVAL; }
  else if(i < WB_BRIN ){ s=a2; off = i-WB_MEOUT; }
  else if(i < WB_BROUT){ s=a3; off = i-WB_BRIN;
    int row = (int)(off>>7); if((row % 384) < 128) sc = qsc; }
  else if(i < WB_BRG ){ s=a4; off = i-WB_BROUT; }
  else if(i < WB_BRV ){ s=a5; off = i-WB_BRG; }
  else if(i < WB_BRF ){ s=a6; off = i-WB_BRV; }
  else if(i < WB_OUTW){ s=a7; off = i-WB_BRF; }
  else { s=a8; off = i-WB_OUTW; }
  float4 v = *reinterpret_cast<const float4*>(s + off);
  unsigned short h4[4] = {f2bf(v.x*sc), f2bf(v.y*sc), f2bf(v.z*sc), f2bf(v.w*sc)};
  *reinterpret_cast<uint2*>(dst + i) = *reinterpret_cast<const uint2*>(h4);
}

// ---------------- routing: one wave per token (LN fused) ----------------
__global__ __launch_bounds__(256) void routing_kernel(
    const float* __restrict__ x,
    const float* __restrict__ gr_g, const float* __restrict__ gr_b,
    const float* __restrict__ q6,   const float* __restrict__ logtemp,
    const float* __restrict__ grp_g,const float* __restrict__ grp_b,
    const float* __restrict__ gpw,  const float* __restrict__ gpb,
    float* __restrict__ gw_out, float* __restrict__ coef, float* __restrict__ part){
  __shared__ float sp[4][9];
  int lane = threadIdx.x & 63;
  int wv   = threadIdx.x >> 6;
  int t    = (blockIdx.x<<2) + wv;
  const float* xr = x + (size_t)t*DD;
  float r0 = xr[lane], r1 = xr[lane+64];
  float mn = wsum(r0+r1) * (1.0f/DD);
  float d0 = r0-mn, d1 = r1-mn;
  float vv = wsum(d0*d0 + d1*d1) * (1.0f/DD);
  float rstd = rsqrtf(vv + 1e-5f);
  float x0 = d0*rstd, x1 = d1*rstd;
  float h0 = x0*gr_g[lane]+gr_b[lane];
  float h1 = x1*gr_g[lane+64]+gr_b[lane+64];
  float sb[6];
#pragma unroll
  for(int j=0;j<6;j++){
    float p = h0*q6[j*DD+lane] + h1*q6[j*DD+lane+64];
    sb[j] = tanhf(wsum(p));
  }
  float sim = 0.f;
#pragma unroll
  for(int j=0;j<6;j++) sim += ((lane>>(5-j))&1) ? sb[j] : -sb[j];
  float temp = expf(logtemp[0]); temp = fminf(fmaxf(temp,0.1f),5.0f);
  float mx = wmaxr(sim);
  float p  = expf((sim-mx)/temp);
  float w  = p / wsum(p);
  float sh[6];
#pragma unroll
  for(int j=0;j<6;j++) sh[j] = wsum(((lane>>(5-j))&1) ? w : -w);
  const float A0[6]={0,1,1,0,1,1}, A1[6]={0,-1,0,1,0,0}, A2[6]={-1,0,-1,-1,0,-1};
  float l0=0,l1=0,l2=0;
#pragma unroll
  for(int j=0;j<6;j++){ l0+=sh[j]*A0[j]; l1+=sh[j]*A1[j]; l2+=sh[j]*A2[j]; }
  float m3 = fmaxf(l0,fmaxf(l1,l2));
  float e0=expf(l0-m3), e1=expf(l1-m3), e2=expf(l2-m3);
  float inv3 = 1.0f/(e0+e1+e2);
  float g0=e0*inv3, g1=e1*inv3, g2=e2*inv3;
  if(lane==0){ gw_out[t*3]=g0; gw_out[t*3+1]=g1; gw_out[t*3+2]=g2; }
  float gwv[3]={g0,g1,g2};
  float pw[6];
#pragma unroll
  for(int g=0; g<3; g++){
    float hg0 = x0*grp_g[g*DD+lane]    + grp_b[g*DD+lane];
    float hg1 = x1*grp_g[g*DD+lane+64] + grp_b[g*DD+lane+64];
    float q0 = wsum(hg0*gpw[(g*2+0)*DD+lane] + hg1*gpw[(g*2+0)*DD+lane+64]) + gpb[g*2+0];
    float q1 = wsum(hg0*gpw[(g*2+1)*DD+lane] + hg1*gpw[(g*2+1)*DD+lane+64]) + gpb[g*2+1];
    float mm = fmaxf(q0,q1);
    float a0 = expf(q0-mm), a1 = expf(q1-mm);
    float inv = 1.0f/(a0+a1);
    float w0 = a0*inv, w1 = a1*inv;
    pw[g*2]=w0; pw[g*2+1]=w1;
    float invs = 1.0f/(w0+w1+1e-8f);
    if(lane==0){
      coef[(size_t)(2*g  )*NTOK + t] = gwv[g]*w0*invs;
      coef[(size_t)(2*g+1)*NTOK + t] = gwv[g]*w1*invs;
    }
  }
  if(lane==0){
    sp[wv][0]=g0; sp[wv][1]=g1; sp[wv][2]=g2;
#pragma unroll
    for(int k=0;k<6;k++) sp[wv][3+k]=pw[k];
  }
  __syncthreads();
  if(threadIdx.x<9){
    part[blockIdx.x*9+threadIdx.x] =
      sp[0][threadIdx.x]+sp[1][threadIdx.x]+sp[2][threadIdx.x]+sp[3][threadIdx.x];
  }
}

// ---------------- load-balance loss reduce (deterministic, parallel) ----------------
__global__ __launch_bounds__(256) void lb_kernel(const float* __restrict__ part, float* __restrict__ outlb){
  __shared__ float sm[4][9];
  float acc[9] = {};
  for(int i=threadIdx.x; i<2048; i+=256){
#pragma unroll
    for(int c=0;c<9;c++) acc[c] += part[i*9+c];
  }
#pragma unroll
  for(int c=0;c<9;c++) acc[c] = wsum(acc[c]);
  int wv = threadIdx.x>>6, lane = threadIdx.x&63;
  if(lane==0){
#pragma unroll
    for(int c=0;c<9;c++) sm[wv][c]=acc[c];
  }
  __syncthreads();
  if(threadIdx.x==0){
    const float invN = 1.0f/(float)NTOK;
    float lb=0;
#pragma unroll
    for(int c=0;c<9;c++){
      float s = sm[0][c]+sm[1][c]+sm[2][c]+sm[3][c];
      float mw = s*invN;
      lb -= mw*logf(mw+1e-8f);
    }
    outlb[0] = lb*0.01f;
  }
}

// ---------------- bf16 MFMA GEMM (z-batched): C = epi(LN?(A) @ W^T), W pre-converted bf16 ----------------
// MODE 0: store (OBF->bf16)  3: resid+acc  5: BW*sigmoid(gptr[0])*(resid+acc)
// LN=1: K==128, A fp32, LN fused. SUM=1 (with LN): A-row = sum of 3 go + 3 bsum rows.
// ABF=1: A bf16. PSEL/RSEL: 0 = z*stride, 1 = pairsA[z], 2 = pairsB[z].
// QKV=1: blockIdx.x<2 -> Q (pairsA A, sv/bv LN), else KV (pairsB A, resid/gptr LN).
template<int MODE,int LN,int ABF,int OBF,int PSEL,int RSEL,int SUM,int QKV>
__global__ __launch_bounds__(256) void gemm_mfma(
    const void* __restrict__ Ap, const unsigned short* __restrict__ W, void* __restrict__ Cp,
    int M, int N, int K,
    const float* __restrict__ sv, const float* __restrict__ bv,
    const float* __restrict__ resid, const float* __restrict__ gptr,
    size_t az, size_t wz, size_t cz, size_t pz, size_t rz, size_t gz){
  __shared__ unsigned short As[64*LDK];
  __shared__ unsigned short Ws[64*LDK];
  const int z = blockIdx.z;
  const float* A = (const float*)Ap;
  const unsigned short* Ab = (const unsigned short*)Ap;
  if(QKV){
    bool isQ = (blockIdx.x < 2);
    int s = isQ ? ((z==1)?1:0) : ((z==0)?1:2);
    A += (size_t)s*NTOK*DD;
    if(!isQ){ sv = resid; bv = gptr; }
  } else if(PSEL==0){ A += z*az; Ab += z*az; }
  else if(PSEL==1){ int s = (z==1)?1:0; A += (size_t)s*NTOK*DD; Ab += (size_t)s*NTOK*DD; }
  else            { int s = (z==0)?1:2; A += (size_t)s*NTOK*DD; Ab += (size_t)s*NTOK*DD; }
  W += z*wz;
  float* C = (float*)Cp + z*cz;
  unsigned short* Cb = (unsigned short*)Cp + z*cz;
  const float* rs = resid;
  if(RSEL==0) rs += z*rz;
  else { int s = (z==1)?1:0; rs += (size_t)s*NTOK*DD; }
  sv += z*pz; bv += z*pz;
  const float* gp2 = gptr + z*gz;
  int tid  = threadIdx.x;
  int m0   = blockIdx.y*64, n0 = blockIdx.x*64;
  int w    = tid>>6, lane = tid&63;
  int wr   = (w>>1)*32, wc = (w&1)*32;
  int r    = tid>>2, seg = (tid&3)*16;
  f32x4 acc[2][2] = {};
  auto step = [&](){
#pragma unroll
    for(int kk=0;kk<64;kk+=32){
      int ko = kk + (lane>>4)*8;
      bf16x8 a0 = *reinterpret_cast<const bf16x8*>(&As[(wr    + (lane&15))*LDK + ko]);
      bf16x8 a1 = *reinterpret_cast<const bf16x8*>(&As[(wr+16 + (lane&15))*LDK + ko]);
      bf16x8 b0 = *reinterpret_cast<const bf16x8*>(&Ws[(wc    + (lane&15))*LDK + ko]);
      bf16x8 b1 = *reinterpret_cast<const bf16x8*>(&Ws[(wc+16 + (lane&15))*LDK + ko]);
      acc[0][0] = __builtin_amdgcn_mfma_f32_16x16x32_bf16(a0,b0,acc[0][0],0,0,0);
      acc[0][1] = __builtin_amdgcn_mfma_f32_16x16x32_bf16(a0,b1,acc[0][1],0,0,0);
      acc[1][0] = __builtin_amdgcn_mfma_f32_16x16x32_bf16(a1,b0,acc[1][0],0,0,0);
      acc[1][1] = __builtin_amdgcn_mfma_f32_16x16x32_bf16(a1,b1,acc[1][1],0,0,0);
    }
  };
  if(LN){
    float fr[32]; float mean, rstd;
    if(SUM){
#pragma unroll
      for(int j=0;j<32;j++) fr[j]=0.f;
#pragma unroll
      for(int s=0;s<3;s++){
        const float* r1 = A     + (size_t)s*NTOK*DD + (size_t)(m0+r)*K + seg;
        const float* r2 = resid + (size_t)s*NTOK*DD + (size_t)(m0+r)*K + seg;
#pragma unroll
        for(int j=0;j<4;j++){
          float4 v1 = *reinterpret_cast<const float4*>(r1 + j*4);
          float4 v2 = *reinterpret_cast<const float4*>(r2 + j*4);
          fr[j*4]+=v1.x+v2.x; fr[j*4+1]+=v1.y+v2.y; fr[j*4+2]+=v1.z+v2.z; fr[j*4+3]+=v1.w+v2.w;
          float4 w1 = *reinterpret_cast<const float4*>(r1 + 64 + j*4);
          float4 w2 = *reinterpret_cast<const float4*>(r2 + 64 + j*4);
          fr[16+j*4]+=w1.x+w2.x; fr[16+j*4+1]+=w1.y+w2.y; fr[16+j*4+2]+=w1.z+w2.z; fr[16+j*4+3]+=w1.w+w2.w;
        }
      }
    } else {
      const float* arow = A + (size_t)(m0+r)*K + seg;   // K==128
#pragma unroll
      for(int j=0;j<4;j++) *reinterpret_cast<float4*>(&fr[j*4])    = *reinterpret_cast<const float4*>(arow + j*4);
#pragma unroll
      for(int j=0;j<4;j++) *reinterpret_cast<float4*>(&fr[16+j*4]) = *reinterpret_cast<const float4*>(arow + 64 + j*4);
    }
    float s1=0.f, s2=0.f;
#pragma unroll
    for(int j=0;j<32;j++){ s1 += fr[j]; s2 += fr[j]*fr[j]; }
    s1 += __shfl_xor(s1,1,64); s1 += __shfl_xor(s1,2,64);
    s2 += __shfl_xor(s2,1,64); s2 += __shfl_xor(s2,2,64);
    mean = s1*(1.0f/DD);
    float var = s2*(1.0f/DD) - mean*mean;
    rstd = rsqrtf(var + 1e-5f);
#pragma unroll
    for(int kh=0; kh<2; ++kh){            // static unroll: fr index compile-time
      __syncthreads();
      stageLN(fr + kh*16, mean, rstd, sv + kh*64 + seg, bv + kh*64 + seg, &As[r*LDK + seg]);
      stage16bf(W + (size_t)(n0+r)*K + kh*64 + seg, &Ws[r*LDK + seg]);
      __syncthreads();
      step();
    }
  } else {
    for(int k0=0;k0<K;k0+=64){
      __syncthreads();
      if(ABF) stage16bf(Ab + (size_t)(m0+r)*K + k0 + seg, &As[r*LDK + seg]);
      else    stage16(A  + (size_t)(m0+r)*K + k0 + seg, &As[r*LDK + seg]);
      stage16bf(W + (size_t)(n0+r)*K + k0 + seg, &Ws[r*LDK + seg]);
      __syncthreads();
      step();
    }
  }
#pragma unroll
  for(int i=0;i<2;i++){
#pragma unroll
    for(int j=0;j<2;j++){
      int mb = m0 + wr + i*16 + (lane>>4)*4;
      int n  = n0 + wc + j*16 + (lane&15);
#pragma unroll
      for(int rg=0;rg<4;rg++){
        int m = mb + rg;
        float v = acc[i][j][rg];
        size_t o = (size_t)m*N + n;
        if(MODE==0){ if(OBF) Cb[o] = f2bf(v); else C[o] = v; }
        else if(MODE==3){ C[o] = rs[o] + v; }
        else if(MODE==5){
          float gs = (0.5f/3.0f)/(1.0f+expf(-gp2[0]));
          C[o] = gs*(rs[o]+v);
        }
      }
    }
  }
}

// ---------------- dual-W bf16 MFMA GEMM (z-batched): C(bf16) = silu(LN(A)@G^T)*(LN(A)@V^T), K==128 ----------------
__global__ __launch_bounds__(256) void gemm_dual(
    const float* __restrict__ A, const unsigned short* __restrict__ G,
    const unsigned short* __restrict__ V,
    unsigned short* __restrict__ C, int M, int N, int K,
    const float* __restrict__ sv, const float* __restrict__ bv,
    size_t az, size_t wz, size_t cz, size_t pz){
  __shared__ unsigned short As[64*LDK];
  __shared__ unsigned short Gs[64*LDK];
  __shared__ unsigned short Vs[64*LDK];
  const int z = blockIdx.z;
  A += z*az; G += z*wz; V += z*wz; C += z*cz; sv += z*pz; bv += z*pz;
  int tid  = threadIdx.x;
  int m0   = blockIdx.y*64, n0 = blockIdx.x*64;
  int w    = tid>>6, lane = tid&63;
  int wr   = (w>>1)*32, wc = (w&1)*32;
  int r    = tid>>2, seg = (tid&3)*16;
  f32x4 accg[2][2] = {};
  f32x4 accv[2][2] = {};
  float fr[32]; float mean, rstd;
  {
    const float* arow = A + (size_t)(m0+r)*K + seg;   // K==128
#pragma unroll
    for(int j=0;j<4;j++) *reinterpret_cast<float4*>(&fr[j*4])    = *reinterpret_cast<const float4*>(arow + j*4);
#pragma unroll
    for(int j=0;j<4;j++) *reinterpret_cast<float4*>(&fr[16+j*4]) = *reinterpret_cast<const float4*>(arow + 64 + j*4);
    float s1=0.f, s2=0.f;
#pragma unroll
    for(int j=0;j<32;j++){ s1 += fr[j]; s2 += fr[j]*fr[j]; }
    s1 += __shfl_xor(s1,1,64); s1 += __shfl_xor(s1,2,64);
    s2 += __shfl_xor(s2,1,64); s2 += __shfl_xor(s2,2,64);
    mean = s1*(1.0f/DD);
    float var = s2*(1.0f/DD) - mean*mean;
    rstd = rsqrtf(var + 1e-5f);
  }
#pragma unroll
  for(int kh=0; kh<2; ++kh){              // static unroll: fr index compile-time
    int k0 = kh*64;
    __syncthreads();
    stageLN(fr + kh*16, mean, rstd, sv + k0 + seg, bv + k0 + seg, &As[r*LDK + seg]);
    stage16bf(G + (size_t)(n0+r)*K + k0 + seg, &Gs[r*LDK + seg]);
    stage16bf(V + (size_t)(n0+r)*K + k0 + seg, &Vs[r*LDK + seg]);
    __syncthreads();
#pragma unroll
    for(int kk=0;kk<64;kk+=32){
      int ko = kk + (lane>>4)*8;
      bf16x8 a0 = *reinterpret_cast<const bf16x8*>(&As[(wr    + (lane&15))*LDK + ko]);
      bf16x8 a1 = *reinterpret_cast<const bf16x8*>(&As[(wr+16 + (lane&15))*LDK + ko]);
      bf16x8 g0 = *reinterpret_cast<const bf16x8*>(&Gs[(wc    + (lane&15))*LDK + ko]);
      bf16x8 g1 = *reinterpret_cast<const bf16x8*>(&Gs[(wc+16 + (lane&15))*LDK + ko]);
      bf16x8 v0 = *reinterpret_cast<const bf16x8*>(&Vs[(wc    + (lane&15))*LDK + ko]);
      bf16x8 v1 = *reinterpret_cast<const bf16x8*>(&Vs[(wc+16 + (lane&15))*LDK + ko]);
      accg[0][0] = __builtin_amdgcn_mfma_f32_16x16x32_bf16(a0,g0,accg[0][0],0,0,0);
      accg[0][1] = __builtin_amdgcn_mfma_f32_16x16x32_bf16(a0,g1,accg[0][1],0,0,0);
      accg[1][0] = __builtin_amdgcn_mfma_f32_16x16x32_bf16(a1,g0,accg[1][0],0,0,0);
      accg[1][1] = __builtin_amdgcn_mfma_f32_16x16x32_bf16(a1,g1,accg[1][1],0,0,0);
      accv[0][0] = __builtin_amdgcn_mfma_f32_16x16x32_bf16(a0,v0,accv[0][0],0,0,0);
      accv[0][1] = __builtin_amdgcn_mfma_f32_16x16x32_bf16(a0,v1,accv[0][1],0,0,0);
      accv[1][0] = __builtin_amdgcn_mfma_f32_16x16x32_bf16(a1,v0,accv[1][0],0,0,0);
      accv[1][1] = __builtin_amdgcn_mfma_f32_16x16x32_bf16(a1,v1,accv[1][1],0,0,0);
    }
  }
#pragma unroll
  for(int i=0;i<2;i++){
#pragma unroll
    for(int j=0;j<2;j++){
      int mb = m0 + wr + i*16 + (lane>>4)*4;
      int n  = n0 + wc + j*16 + (lane&15);
#pragma unroll
      for(int rg=0;rg<4;rg++){
        float gg = accg[i][j][rg];
        float vv = accv[i][j][rg];
        float sg = gg/(1.0f+expf(-gg));
        C[(size_t)(mb+rg)*N + n] = f2bf(sg*vv);
      }
    }
  }
}

// ---------------- MoE pair-combine GEMM: go[g] = c0*(A0@W0^T) + c1*(A1@W1^T), K=DFF ----------------
__global__ __launch_bounds__(256) void gemm_moe2(
    const unsigned short* __restrict__ Ab, const unsigned short* __restrict__ Wb,
    float* __restrict__ Cb, const float* __restrict__ coef){
  __shared__ unsigned short As0[64*LDK];
  __shared__ unsigned short As1[64*LDK];
  __shared__ unsigned short Ws0[64*LDK];
  __shared__ unsigned short Ws1[64*LDK];
  const int g = blockIdx.z;
  const unsigned short* A0 = Ab + (size_t)(2*g)*NTOK*DFF;
  const unsigned short* A1 = A0 + (size_t)NTOK*DFF;
  const unsigned short* W0 = Wb + (size_t)(2*g)*DD*DFF;
  const unsigned short* W1 = W0 + (size_t)DD*DFF;
  float* C = Cb + (size_t)g*NTOK*DD;
  const float* c0 = coef + (size_t)(2*g)*NTOK;
  const float* c1 = c0 + NTOK;
  int tid  = threadIdx.x;
  int m0   = blockIdx.y*64, n0 = blockIdx.x*64;
  int w    = tid>>6, lane = tid&63;
  int wr   = (w>>1)*32, wc = (w&1)*32;
  int r    = tid>>2, seg = (tid&3)*16;
  f32x4 a0acc[2][2] = {};
  f32x4 a1acc[2][2] = {};
  for(int k0=0;k0<DFF;k0+=64){
    __syncthreads();
    stage16bf(A0 + (size_t)(m0+r)*DFF + k0 + seg, &As0[r*LDK + seg]);
    stage16bf(A1 + (size_t)(m0+r)*DFF + k0 + seg, &As1[r*LDK + seg]);
    stage16bf(W0 + (size_t)(n0+r)*DFF + k0 + seg, &Ws0[r*LDK + seg]);
    stage16bf(W1 + (size_t)(n0+r)*DFF + k0 + seg, &Ws1[r*LDK + seg]);
    __syncthreads();
#pragma unroll
    for(int kk=0;kk<64;kk+=32){
      int ko = kk + (lane>>4)*8;
      bf16x8 x00 = *reinterpret_cast<const bf16x8*>(&As0[(wr    + (lane&15))*LDK + ko]);
      bf16x8 x01 = *reinterpret_cast<const bf16x8*>(&As0[(wr+16 + (lane&15))*LDK + ko]);
      bf16x8 x10 = *reinterpret_cast<const bf16x8*>(&As1[(wr    + (lane&15))*LDK + ko]);
      bf16x8 x11 = *reinterpret_cast<const bf16x8*>(&As1[(wr+16 + (lane&15))*LDK + ko]);
      bf16x8 w00 = *reinterpret_cast<const bf16x8*>(&Ws0[(wc    + (lane&15))*LDK + ko]);
      bf16x8 w01 = *reinterpret_cast<const bf16x8*>(&Ws0[(wc+16 + (lane&15))*LDK + ko]);
      bf16x8 w10 = *reinterpret_cast<const bf16x8*>(&Ws1[(wc    + (lane&15))*LDK + ko]);
      bf16x8 w11 = *reinterpret_cast<const bf16x8*>(&Ws1[(wc+16 + (lane&15))*LDK + ko]);
      a0acc[0][0] = __builtin_amdgcn_mfma_f32_16x16x32_bf16(x00,w00,a0acc[0][0],0,0,0);
      a0acc[0][1] = __builtin_amdgcn_mfma_f32_16x16x32_bf16(x00,w01,a0acc[0][1],0,0,0);
      a0acc[1][0] = __builtin_amdgcn_mfma_f32_16x16x32_bf16(x01,w00,a0acc[1][0],0,0,0);
      a0acc[1][1] = __builtin_amdgcn_mfma_f32_16x16x32_bf16(x01,w01,a0acc[1][1],0,0,0);
      a1acc[0][0] = __builtin_amdgcn_mfma_f32_16x16x32_bf16(x10,w10,a1acc[0][0],0,0,0);
      a1acc[0][1] = __builtin_amdgcn_mfma_f32_16x16x32_bf16(x10,w11,a1acc[0][1],0,0,0);
      a1acc[1][0] = __builtin_amdgcn_mfma_f32_16x16x32_bf16(x11,w10,a1acc[1][0],0,0,0);
      a1acc[1][1] = __builtin_amdgcn_mfma_f32_16x16x32_bf16(x11,w11,a1acc[1][1],0,0,0);
    }
  }
#pragma unroll
  for(int i=0;i<2;i++){
#pragma unroll
    for(int j=0;j<2;j++){
      int mb = m0 + wr + i*16 + (lane>>4)*4;
      int n  = n0 + wc + j*16 + (lane&15);
#pragma unroll
      for(int rg=0;rg<4;rg++){
        int m = mb + rg;
        C[(size_t)m*DD + n] = c0[m]*a0acc[i][j][rg] + c1[m]*a1acc[i][j][rg];
      }
    }
  }
}

// ---------------- fused MFMA flash attention: 16 q-rows/wave, full KV per block ----------------
// flat grid 1536 with XCD-aware remap: residue n%8 owns 12 complete (h,b,br) groups
// so all 16 q-blocks sharing one KV slice land on one XCD's L2.
#define PSW(row) (((row)&8)<<1)              // Ps col ^= 16 when row bit3 set
#define VSW(row) ((((row)>>3)&3)<<3)         // Vt col ^= 8*((row>>3)&3)
__global__ __launch_bounds__(256) void attn_fused(
    const unsigned short* __restrict__ qkv,
    unsigned short* __restrict__ obuf){
  __shared__ __align__(16) unsigned short Ks[64*40];
  __shared__ __align__(16) unsigned short Vt[48*72];
  __shared__ __align__(16) unsigned short Ps[4][16*72];
  const int tid = threadIdx.x;
  const int w = tid>>6, lane = tid&63;
  const int lr = lane&15, lg = lane>>4;
  // XCD-aware decode: n%8 = XCD residue; each residue owns 12 groups of 16 blocks
  const int n_  = blockIdx.x;
  const int kx  = n_ & 7, jx = n_ >> 3;        // jx: 0..191
  const int grp = kx*12 + (jx>>4);             // 0..95 (bijective)
  const int bx  = jx & 15;
  const int h   = grp & 3;
  const int b   = (grp>>2) & 7;
  const int br  = grp >> 5;
  const int qtok0 = b*TT + bx*64 + w*16;
  for(int idx=tid; idx<16*72; idx+=256)
    Vt[32*72 + idx] = (idx < 64) ? (unsigned short)0x3F80 : (unsigned short)0;
  const unsigned short* qp = qkv + (size_t)br*NTOK*QKVN + (size_t)(qtok0 + lr)*QKVN + h*HDD + lg*8;
  bf16x8 qa = *reinterpret_cast<const bf16x8*>(qp);
  f32x4 o0 = {}, o1 = {}, o2 = {};
  float m[4] = {-1e30f,-1e30f,-1e30f,-1e30f};
  const unsigned short* KVbase = qkv + (size_t)br*NTOK*QKVN + (size_t)(b*TT)*QKVN + DD + h*HDD;

  for(int t0=0; t0<TT; t0+=64){
    __syncthreads();
#pragma unroll
    for(int s2=0;s2<2;s2++){
      int i   = tid + s2*256;
      int key = i>>3, seg = (i&7)*4;
      const unsigned short* src = KVbase + (size_t)(t0+key)*QKVN + seg;
      *reinterpret_cast<uint2*>(&Ks[key*40+seg]) = *reinterpret_cast<const uint2*>(src);
      unsigned short vs[4];
      *reinterpret_cast<uint2*>(vs) = *reinterpret_cast<const uint2*>(src + DD);
      const int kc = key ^ VSW(seg);
      Vt[(seg  )*72+kc] = vs[0];
      Vt[(seg+1)*72+kc] = vs[1];
      Vt[(seg+2)*72+kc] = vs[2];
      Vt[(seg+3)*72+kc] = vs[3];
    }
    __syncthreads();
    f32x4 s[4];
#pragma unroll
    for(int f=0;f<4;f++){
      bf16x8 kb = *reinterpret_cast<const bf16x8*>(&Ks[(f*16+lr)*40 + lg*8]);
      f32x4 z = {};
      s[f] = __builtin_amdgcn_mfma_f32_16x16x32_bf16(qa,kb,z,0,0,0);
    }
    float tmax[4]; bool need=false;
#pragma unroll
    for(int r=0;r<4;r++){
      tmax[r] = fmaxf(fmaxf(s[0][r],s[1][r]),fmaxf(s[2][r],s[3][r]));
      need = need || (tmax[r] > m[r] + 8.0f);
    }
    if(__any(need)){
#pragma unroll
      for(int r=0;r<4;r++){
        float t = tmax[r];
#pragma unroll
        for(int off=1;off<16;off<<=1) t = fmaxf(t,__shfl_xor(t,off,64));
        float nm = fmaxf(m[r],t);
        float sc = __builtin_amdgcn_exp2f(m[r]-nm);
        m[r] = nm; o0[r] *= sc; o1[r] *= sc; o2[r] *= sc;
      }
    }
#pragma unroll
    for(int r=0;r<4;r++){
      const int q = lg*4+r;
      const int cw = PSW(q);
#pragma unroll
      for(int f=0;f<4;f++){
        float p = __builtin_amdgcn_exp2f(s[f][r]-m[r]);
        Ps[w][q*72 + ((f*16+lr)^cw)] = f2bf(p);
      }
    }
    const int pw_ = PSW(lr);
    bf16x8 pa0 = *reinterpret_cast<const bf16x8*>(&Ps[w][lr*72 + ((lg*8   )^pw_)]);
    bf16x8 pa1 = *reinterpret_cast<const bf16x8*>(&Ps[w][lr*72 + ((lg*8+32)^pw_)]);
    {
      const int r_ = lr, vw = VSW(r_);
      bf16x8 vb0 = *reinterpret_cast<const bf16x8*>(&Vt[r_*72 + ((lg*8   )^vw)]);
      bf16x8 vb1 = *reinterpret_cast<const bf16x8*>(&Vt[r_*72 + ((lg*8+32)^vw)]);
      o0 = __builtin_amdgcn_mfma_f32_16x16x32_bf16(pa0,vb0,o0,0,0,0);
      o0 = __builtin_amdgcn_mfma_f32_16x16x32_bf16(pa1,vb1,o0,0,0,0);
    }
    {
      const int r_ = 16+lr, vw = VSW(r_);
      bf16x8 vb0 = *reinterpret_cast<const bf16x8*>(&Vt[r_*72 + ((lg*8   )^vw)]);
      bf16x8 vb1 = *reinterpret_cast<const bf16x8*>(&Vt[r_*72 + ((lg*8+32)^vw)]);
      o1 = __builtin_amdgcn_mfma_f32_16x16x32_bf16(pa0,vb0,o1,0,0,0);
      o1 = __builtin_amdgcn_mfma_f32_16x16x32_bf16(pa1,vb1,o1,0,0,0);
    }
    {
      const int r_ = 32+lr, vw = VSW(r_);
      bf16x8 vb0 = *reinterpret_cast<const bf16x8*>(&Vt[r_*72 + ((lg*8   )^vw)]);
      bf16x8 vb1 = *reinterpret_cast<const bf16x8*>(&Vt[r_*72 + ((lg*8+32)^vw)]);
      o2 = __builtin_amdgcn_mfma_f32_16x16x32_bf16(pa0,vb0,o2,0,0,0);
      o2 = __builtin_amdgcn_mfma_f32_16x16x32_bf16(pa1,vb1,o2,0,0,0);
    }
  }
#pragma unroll
  for(int r=0;r<4;r++){
    float lsr = __shfl(o2[r], lane & 48, 64);   // broadcast col-0 (row-sum)
    float inv = 1.0f/lsr;
    int row = qtok0 + lg*4 + r;
    unsigned short* orow = obuf + (size_t)br*NTOK*DD + (size_t)row*DD + h*HDD;
    orow[lr]    = f2bf(o0[r]*inv);
    orow[16+lr] = f2bf(o1[r]*inv);
  }
}

// ---------------- launch ----------------
extern "C" void kernel_launch(void* const* d_in, const int* in_sizes, int n_in,
                              void* d_out, int out_size, void* d_ws, size_t ws_size,
                              hipStream_t stream){
  (void)in_sizes; (void)n_in; (void)out_size; (void)ws_size;
  const float* x       = (const float*)d_in[0];
  const float* gr_g    = (const float*)d_in[1];
  const float* gr_b    = (const float*)d_in[2];
  const float* q6_w    = (const float*)d_in[3];
  const float* logtemp = (const float*)d_in[4];
  const float* grp_g   = (const float*)d_in[5];
  const float* grp_b   = (const float*)d_in[6];
  const float* gpw     = (const float*)d_in[7];
  const float* gpb     = (const float*)d_in[8];
  const float* me_g    = (const float*)d_in[9];
  const float* me_b    = (const float*)d_in[10];
  const float* me_gate = (const float*)d_in[11];
  const float* me_val  = (const float*)d_in[12];
  const float* me_out  = (const float*)d_in[13];
  const float* br_in   = (const float*)d_in[14];
  const float* br_outw = (const float*)d_in[15];
  const float* nq_g    = (const float*)d_in[16];
  const float* nq_b    = (const float*)d_in[17];
  const float* nkv_g   = (const float*)d_in[18];
  const float* nkv_b   = (const float*)d_in[19];
  const float* nff_g   = (const float*)d_in[20];
  const float* nff_b   = (const float*)d_in[21];
  const float* brg_w   = (const float*)d_in[22];
  const float* brv_w   = (const float*)d_in[23];
  const float* brf_w   = (const float*)d_in[24];
  const float* br_gate = (const float*)d_in[25];
  const float* on_g    = (const float*)d_in[26];
  const float* on_b    = (const float*)d_in[27];
  const float* out_w   = (const float*)d_in[28];
  float* out = (float*)d_out;
  float* ws  = (float*)d_ws;

  float* coef  = ws;                                        // 49152
  float* part  = ws + 65536;                                // 18432
  unsigned short* gvb6 = (unsigned short*)(ws + 131072);    // 6*8192*256 bf16
  float* go    = ws + 6731072;                              // 3*1048576 fp32
  unsigned short* qkv  = (unsigned short*)(ws + 9900000);   // 3*8192*384 bf16
  unsigned short* obuf = (unsigned short*)(ws + 14700000);  // 3*8192*128 bf16
  unsigned short* wbf  = (unsigned short*)(ws + 21400000);  // WB_TOT bf16 weights
  float* xb    = ws + 23000000;                             // 3*1048576 fp32
  unsigned short* gvb2 = (unsigned short*)(ws + 26200000);  // 3*8192*256 bf16
  float* bsum  = ws + 29400000;                             // 3*1048576 fp32
  float* gw    = ws + 32700000;                             // 24576

  // 1/sqrt(32) * log2(e): softmax runs in the exp2 domain (folded into Q weights)
  const float qscale = 0.17677669529663687f * 1.4426950408889634f;

  // 0. one-time weight conversion fp32 -> bf16 (qscale folded into br_in Q rows)
  wconv<<<1072,256,0,stream>>>(me_gate, me_val, me_out, br_in, br_outw,
                               brg_w, brv_w, brf_w, out_w, wbf, qscale);

  // 1. routing (fused LN) + lb
  routing_kernel<<<2048,256,0,stream>>>(x, gr_g, gr_b, q6_w, logtemp,
                                        grp_g, grp_b, gpw, gpb, gw, coef, part);
  lb_kernel<<<1,256,0,stream>>>(part, out + 1048576);

  // 2. MoE: all 6 experts in one dual dispatch; pair-combine into go (z=group)
  gemm_dual<<<dim3(4,128,6),256,0,stream>>>(x, wbf+WB_MEGATE, wbf+WB_MEVAL, gvb6,
      NTOK,DFF,DD, me_g, me_b, 0, (size_t)DFF*DD, (size_t)NTOK*DFF, DD);
  gemm_moe2<<<dim3(2,128,3),256,0,stream>>>(gvb6, wbf+WB_MEOUT, go, coef);

  // 3. bridges: fused QKV projection, attn (full-KV, XCD-swizzled, bf16 out), out-proj+resid, FFN, bridge-scale
  gemm_mfma<0,1,0,1,0,0,0,1><<<dim3(6,128,3),256,0,stream>>>(go, wbf+WB_BRIN, qkv,
      NTOK,QKVN,DD, nq_g, nq_b, nkv_g, nkv_b,
      0, (size_t)QKVN*DD, (size_t)NTOK*QKVN, DD, 0, 0);
  attn_fused<<<1536,256,0,stream>>>(qkv, obuf);
  gemm_mfma<3,0,1,0,0,1,0,0><<<dim3(2,128,3),256,0,stream>>>(obuf, wbf+WB_BROUT, xb,
      NTOK,DD,DD, nullptr, nullptr, go, nullptr,
      (size_t)NTOK*DD, (size_t)DD*DD, (size_t)NTOK*DD, 0, 0, 0);
  gemm_dual<<<dim3(4,128,3),256,0,stream>>>(xb, wbf+WB_BRG, wbf+WB_BRV, gvb2,
      NTOK,2*DD,DD, nff_g, nff_b, (size_t)NTOK*DD, (size_t)2*DD*DD, (size_t)NTOK*2*DD, DD);
  gemm_mfma<5,0,1,0,0,0,0,0><<<dim3(2,128,3),256,0,stream>>>(gvb2, wbf+WB_BRF, bsum,
      NTOK,DD,2*DD, nullptr, nullptr, xb, br_gate,
      (size_t)NTOK*2*DD, (size_t)DD*2*DD, (size_t)NTOK*DD, 0, (size_t)NTOK*DD, 1);

  // 4. final: LN over (go0+go1+go2+bsum0+bsum1+bsum2), projection
  gemm_mfma<0,1,0,0,0,0,1,0><<<dim3(2,128,1),256,0,stream>>>(go, wbf+WB_OUTW, out,
      NTOK,DD,DD, on_g, on_b, bsum, nullptr,
      0, 0, 0, 0, 0, 0);
}

// Round 17
// 191.066 us; speedup vs baseline: 1.0426x; 1.0128x over previous
//
#include <hip/hip_runtime.h>
#include <math.h>

#define DD    128
#define DFF   256
#define NHH   4
#define HDD   32
#define BB    8
#define TT    1024
#define NTOK  (BB*TT)          // 8192
#define LDK   72               // padded LDS row stride (bf16 elements) for GEMM tiles
#define QKVN  384              // fused QKV row width

// bf16 weight workspace offsets (elements)
#define WB_MEGATE 0
#define WB_MEVAL  196608
#define WB_MEOUT  393216
#define WB_BRIN   589824
#define WB_BROUT  737280
#define WB_BRG    786432
#define WB_BRV    884736
#define WB_BRF    983040
#define WB_OUTW   1081344
#define WB_TOT    1097728

typedef __bf16 bf16x8 __attribute__((ext_vector_type(8)));
typedef float  f32x4  __attribute__((ext_vector_type(4)));

// ---------------- wave helpers (wave64) ----------------
__device__ __forceinline__ float wsum(float v){
#pragma unroll
  for(int o=32;o>0;o>>=1) v += __shfl_xor(v,o,64);
  return v;
}
__device__ __forceinline__ float wmaxr(float v){
#pragma unroll
  for(int o=32;o>0;o>>=1) v = fmaxf(v,__shfl_xor(v,o,64));
  return v;
}
__device__ __forceinline__ unsigned short f2bf(float x){
  __bf16 h = (__bf16)x;
  unsigned short u;
  __builtin_memcpy(&u, &h, 2);
  return u;
}

// stage 16 consecutive fp32 (global) -> 16 bf16 in LDS
__device__ __forceinline__ void stage16(const float* __restrict__ gp,
                                        unsigned short* __restrict__ dst){
  float4 f0 = *reinterpret_cast<const float4*>(gp);
  float4 f1 = *reinterpret_cast<const float4*>(gp+4);
  float4 f2 = *reinterpret_cast<const float4*>(gp+8);
  float4 f3 = *reinterpret_cast<const float4*>(gp+12);
  float f[16] = {f0.x,f0.y,f0.z,f0.w, f1.x,f1.y,f1.z,f1.w,
                 f2.x,f2.y,f2.z,f2.w, f3.x,f3.y,f3.z,f3.w};
  unsigned short h[16];
#pragma unroll
  for(int j=0;j<16;j++) h[j] = f2bf(f[j]);
  *reinterpret_cast<uint4*>(dst)   = *reinterpret_cast<const uint4*>(h);
  *reinterpret_cast<uint4*>(dst+8) = *reinterpret_cast<const uint4*>(h+8);
}

// stage 16 consecutive bf16 (global) -> LDS (pure copy, 2x16B)
__device__ __forceinline__ void stage16bf(const unsigned short* __restrict__ gp,
                                          unsigned short* __restrict__ dst){
  const uint4* s = reinterpret_cast<const uint4*>(gp);
  *reinterpret_cast<uint4*>(dst)   = s[0];
  *reinterpret_cast<uint4*>(dst+8) = s[1];
}

// stage 16 fp32 from registers with LN affine -> LDS bf16 (fr base must be compile-time)
__device__ __forceinline__ void stageLN(const float* __restrict__ fr,
                                        float mean, float rstd,
                                        const float* __restrict__ g,
                                        const float* __restrict__ b,
                                        unsigned short* __restrict__ dst){
  unsigned short h[16];
#pragma unroll
  for(int j=0;j<16;j++){
    float y = (fr[j]-mean)*rstd*g[j] + b[j];
    h[j] = f2bf(y);
  }
  *reinterpret_cast<uint4*>(dst)   = *reinterpret_cast<const uint4*>(h);
  *reinterpret_cast<uint4*>(dst+8) = *reinterpret_cast<const uint4*>(h+8);
}

// ---------------- one-time weight fp32->bf16 conversion (qscale folded into br_in Q rows) ----------------
__global__ __launch_bounds__(256) void wconv(
    const float* __restrict__ a0, const float* __restrict__ a1, const float* __restrict__ a2,
    const float* __restrict__ a3, const float* __restrict__ a4, const float* __restrict__ a5,
    const float* __restrict__ a6, const float* __restrict__ a7, const float* __restrict__ a8,
    unsigned short* __restrict__ dst, float qsc){
  size_t i = ((size_t)blockIdx.x*256 + threadIdx.x)*4;
  if(i >= WB_TOT) return;
  const float* s; size_t off = i; float sc = 1.0f;
  if(i < WB_MEVAL){ s=a0; }
  else if(i < WB_MEOUT){ s=a1; off = i-WB_MEVAL; }
  else if(i < WB_BRIN ){ s=a2; off = i-WB_MEOUT; }
  else if(i < WB_BROUT){ s=a3; off = i-WB_BRIN;
    int row = (int)(off>>7); if((row % 384) < 128) sc = qsc; }
  else if(i < WB_BRG ){ s=a4; off = i-WB_BROUT; }
  else if(i < WB_BRV ){ s=a5; off = i-WB_BRG; }
  else if(i < WB_BRF ){ s=a6; off = i-WB_BRV; }
  else if(i < WB_OUTW){ s=a7; off = i-WB_BRF; }
  else { s=a8; off = i-WB_OUTW; }
  float4 v = *reinterpret_cast<const float4*>(s + off);
  unsigned short h4[4] = {f2bf(v.x*sc), f2bf(v.y*sc), f2bf(v.z*sc), f2bf(v.w*sc)};
  *reinterpret_cast<uint2*>(dst + i) = *reinterpret_cast<const uint2*>(h4);
}

// ---------------- routing: one wave per token (LN fused) ----------------
__global__ __launch_bounds__(256) void routing_kernel(
    const float* __restrict__ x,
    const float* __restrict__ gr_g, const float* __restrict__ gr_b,
    const float* __restrict__ q6,   const float* __restrict__ logtemp,
    const float* __restrict__ grp_g,const float* __restrict__ grp_b,
    const float* __restrict__ gpw,  const float* __restrict__ gpb,
    float* __restrict__ gw_out, float* __restrict__ coef, float* __restrict__ part){
  __shared__ float sp[4][9];
  int lane = threadIdx.x & 63;
  int wv   = threadIdx.x >> 6;
  int t    = (blockIdx.x<<2) + wv;
  const float* xr = x + (size_t)t*DD;
  float r0 = xr[lane], r1 = xr[lane+64];
  float mn = wsum(r0+r1) * (1.0f/DD);
  float d0 = r0-mn, d1 = r1-mn;
  float vv = wsum(d0*d0 + d1*d1) * (1.0f/DD);
  float rstd = rsqrtf(vv + 1e-5f);
  float x0 = d0*rstd, x1 = d1*rstd;
  float h0 = x0*gr_g[lane]+gr_b[lane];
  float h1 = x1*gr_g[lane+64]+gr_b[lane+64];
  float sb[6];
#pragma unroll
  for(int j=0;j<6;j++){
    float p = h0*q6[j*DD+lane] + h1*q6[j*DD+lane+64];
    sb[j] = tanhf(wsum(p));
  }
  float sim = 0.f;
#pragma unroll
  for(int j=0;j<6;j++) sim += ((lane>>(5-j))&1) ? sb[j] : -sb[j];
  float temp = expf(logtemp[0]); temp = fminf(fmaxf(temp,0.1f),5.0f);
  float mx = wmaxr(sim);
  float p  = expf((sim-mx)/temp);
  float w  = p / wsum(p);
  float sh[6];
#pragma unroll
  for(int j=0;j<6;j++) sh[j] = wsum(((lane>>(5-j))&1) ? w : -w);
  const float A0[6]={0,1,1,0,1,1}, A1[6]={0,-1,0,1,0,0}, A2[6]={-1,0,-1,-1,0,-1};
  float l0=0,l1=0,l2=0;
#pragma unroll
  for(int j=0;j<6;j++){ l0+=sh[j]*A0[j]; l1+=sh[j]*A1[j]; l2+=sh[j]*A2[j]; }
  float m3 = fmaxf(l0,fmaxf(l1,l2));
  float e0=expf(l0-m3), e1=expf(l1-m3), e2=expf(l2-m3);
  float inv3 = 1.0f/(e0+e1+e2);
  float g0=e0*inv3, g1=e1*inv3, g2=e2*inv3;
  if(lane==0){ gw_out[t*3]=g0; gw_out[t*3+1]=g1; gw_out[t*3+2]=g2; }
  float gwv[3]={g0,g1,g2};
  float pw[6];
#pragma unroll
  for(int g=0; g<3; g++){
    float hg0 = x0*grp_g[g*DD+lane]    + grp_b[g*DD+lane];
    float hg1 = x1*grp_g[g*DD+lane+64] + grp_b[g*DD+lane+64];
    float q0 = wsum(hg0*gpw[(g*2+0)*DD+lane] + hg1*gpw[(g*2+0)*DD+lane+64]) + gpb[g*2+0];
    float q1 = wsum(hg0*gpw[(g*2+1)*DD+lane] + hg1*gpw[(g*2+1)*DD+lane+64]) + gpb[g*2+1];
    float mm = fmaxf(q0,q1);
    float a0 = expf(q0-mm), a1 = expf(q1-mm);
    float inv = 1.0f/(a0+a1);
    float w0 = a0*inv, w1 = a1*inv;
    pw[g*2]=w0; pw[g*2+1]=w1;
    float invs = 1.0f/(w0+w1+1e-8f);
    if(lane==0){
      coef[(size_t)(2*g  )*NTOK + t] = gwv[g]*w0*invs;
      coef[(size_t)(2*g+1)*NTOK + t] = gwv[g]*w1*invs;
    }
  }
  if(lane==0){
    sp[wv][0]=g0; sp[wv][1]=g1; sp[wv][2]=g2;
#pragma unroll
    for(int k=0;k<6;k++) sp[wv][3+k]=pw[k];
  }
  __syncthreads();
  if(threadIdx.x<9){
    part[blockIdx.x*9+threadIdx.x] =
      sp[0][threadIdx.x]+sp[1][threadIdx.x]+sp[2][threadIdx.x]+sp[3][threadIdx.x];
  }
}

// ---------------- load-balance loss reduce (deterministic, parallel) ----------------
__global__ __launch_bounds__(256) void lb_kernel(const float* __restrict__ part, float* __restrict__ outlb){
  __shared__ float sm[4][9];
  float acc[9] = {};
  for(int i=threadIdx.x; i<2048; i+=256){
#pragma unroll
    for(int c=0;c<9;c++) acc[c] += part[i*9+c];
  }
#pragma unroll
  for(int c=0;c<9;c++) acc[c] = wsum(acc[c]);
  int wv = threadIdx.x>>6, lane = threadIdx.x&63;
  if(lane==0){
#pragma unroll
    for(int c=0;c<9;c++) sm[wv][c]=acc[c];
  }
  __syncthreads();
  if(threadIdx.x==0){
    const float invN = 1.0f/(float)NTOK;
    float lb=0;
#pragma unroll
    for(int c=0;c<9;c++){
      float s = sm[0][c]+sm[1][c]+sm[2][c]+sm[3][c];
      float mw = s*invN;
      lb -= mw*logf(mw+1e-8f);
    }
    outlb[0] = lb*0.01f;
  }
}

// ---------------- bf16 MFMA GEMM (z-batched): C = epi(LN?(A) @ W^T), W pre-converted bf16 ----------------
// MODE 0: store (OBF->bf16)  3: resid+acc  5: BW*sigmoid(gptr[0])*(resid+acc)
// LN=1: K==128, A fp32, LN fused. SUM=1 (with LN): A-row = sum of 3 go + 3 bsum rows.
// ABF=1: A bf16. PSEL/RSEL: 0 = z*stride, 1 = pairsA[z], 2 = pairsB[z].
// QKV=1: blockIdx.x<2 -> Q (pairsA A, sv/bv LN), else KV (pairsB A, resid/gptr LN).
template<int MODE,int LN,int ABF,int OBF,int PSEL,int RSEL,int SUM,int QKV>
__global__ __launch_bounds__(256) void gemm_mfma(
    const void* __restrict__ Ap, const unsigned short* __restrict__ W, void* __restrict__ Cp,
    int M, int N, int K,
    const float* __restrict__ sv, const float* __restrict__ bv,
    const float* __restrict__ resid, const float* __restrict__ gptr,
    size_t az, size_t wz, size_t cz, size_t pz, size_t rz, size_t gz){
  __shared__ unsigned short As[64*LDK];
  __shared__ unsigned short Ws[64*LDK];
  const int z = blockIdx.z;
  const float* A = (const float*)Ap;
  const unsigned short* Ab = (const unsigned short*)Ap;
  if(QKV){
    bool isQ = (blockIdx.x < 2);
    int s = isQ ? ((z==1)?1:0) : ((z==0)?1:2);
    A += (size_t)s*NTOK*DD;
    if(!isQ){ sv = resid; bv = gptr; }
  } else if(PSEL==0){ A += z*az; Ab += z*az; }
  else if(PSEL==1){ int s = (z==1)?1:0; A += (size_t)s*NTOK*DD; Ab += (size_t)s*NTOK*DD; }
  else            { int s = (z==0)?1:2; A += (size_t)s*NTOK*DD; Ab += (size_t)s*NTOK*DD; }
  W += z*wz;
  float* C = (float*)Cp + z*cz;
  unsigned short* Cb = (unsigned short*)Cp + z*cz;
  const float* rs = resid;
  if(RSEL==0) rs += z*rz;
  else { int s = (z==1)?1:0; rs += (size_t)s*NTOK*DD; }
  sv += z*pz; bv += z*pz;
  const float* gp2 = gptr + z*gz;
  int tid  = threadIdx.x;
  int m0   = blockIdx.y*64, n0 = blockIdx.x*64;
  int w    = tid>>6, lane = tid&63;
  int wr   = (w>>1)*32, wc = (w&1)*32;
  int r    = tid>>2, seg = (tid&3)*16;
  f32x4 acc[2][2] = {};
  auto step = [&](){
#pragma unroll
    for(int kk=0;kk<64;kk+=32){
      int ko = kk + (lane>>4)*8;
      bf16x8 a0 = *reinterpret_cast<const bf16x8*>(&As[(wr    + (lane&15))*LDK + ko]);
      bf16x8 a1 = *reinterpret_cast<const bf16x8*>(&As[(wr+16 + (lane&15))*LDK + ko]);
      bf16x8 b0 = *reinterpret_cast<const bf16x8*>(&Ws[(wc    + (lane&15))*LDK + ko]);
      bf16x8 b1 = *reinterpret_cast<const bf16x8*>(&Ws[(wc+16 + (lane&15))*LDK + ko]);
      acc[0][0] = __builtin_amdgcn_mfma_f32_16x16x32_bf16(a0,b0,acc[0][0],0,0,0);
      acc[0][1] = __builtin_amdgcn_mfma_f32_16x16x32_bf16(a0,b1,acc[0][1],0,0,0);
      acc[1][0] = __builtin_amdgcn_mfma_f32_16x16x32_bf16(a1,b0,acc[1][0],0,0,0);
      acc[1][1] = __builtin_amdgcn_mfma_f32_16x16x32_bf16(a1,b1,acc[1][1],0,0,0);
    }
  };
  if(LN){
    float fr[32]; float mean, rstd;
    if(SUM){
#pragma unroll
      for(int j=0;j<32;j++) fr[j]=0.f;
#pragma unroll
      for(int s=0;s<3;s++){
        const float* r1 = A     + (size_t)s*NTOK*DD + (size_t)(m0+r)*K + seg;
        const float* r2 = resid + (size_t)s*NTOK*DD + (size_t)(m0+r)*K + seg;
#pragma unroll
        for(int j=0;j<4;j++){
          float4 v1 = *reinterpret_cast<const float4*>(r1 + j*4);
          float4 v2 = *reinterpret_cast<const float4*>(r2 + j*4);
          fr[j*4]+=v1.x+v2.x; fr[j*4+1]+=v1.y+v2.y; fr[j*4+2]+=v1.z+v2.z; fr[j*4+3]+=v1.w+v2.w;
          float4 w1 = *reinterpret_cast<const float4*>(r1 + 64 + j*4);
          float4 w2 = *reinterpret_cast<const float4*>(r2 + 64 + j*4);
          fr[16+j*4]+=w1.x+w2.x; fr[16+j*4+1]+=w1.y+w2.y; fr[16+j*4+2]+=w1.z+w2.z; fr[16+j*4+3]+=w1.w+w2.w;
        }
      }
    } else {
      const float* arow = A + (size_t)(m0+r)*K + seg;   // K==128
#pragma unroll
      for(int j=0;j<4;j++) *reinterpret_cast<float4*>(&fr[j*4])    = *reinterpret_cast<const float4*>(arow + j*4);
#pragma unroll
      for(int j=0;j<4;j++) *reinterpret_cast<float4*>(&fr[16+j*4]) = *reinterpret_cast<const float4*>(arow + 64 + j*4);
    }
    float s1=0.f, s2=0.f;
#pragma unroll
    for(int j=0;j<32;j++){ s1 += fr[j]; s2 += fr[j]*fr[j]; }
    s1 += __shfl_xor(s1,1,64); s1 += __shfl_xor(s1,2,64);
    s2 += __shfl_xor(s2,1,64); s2 += __shfl_xor(s2,2,64);
    mean = s1*(1.0f/DD);
    float var = s2*(1.0f/DD) - mean*mean;
    rstd = rsqrtf(var + 1e-5f);
#pragma unroll
    for(int kh=0; kh<2; ++kh){            // static unroll: fr index compile-time
      __syncthreads();
      stageLN(fr + kh*16, mean, rstd, sv + kh*64 + seg, bv + kh*64 + seg, &As[r*LDK + seg]);
      stage16bf(W + (size_t)(n0+r)*K + kh*64 + seg, &Ws[r*LDK + seg]);
      __syncthreads();
      step();
    }
  } else {
    for(int k0=0;k0<K;k0+=64){
      __syncthreads();
      if(ABF) stage16bf(Ab + (size_t)(m0+r)*K + k0 + seg, &As[r*LDK + seg]);
      else    stage16(A  + (size_t)(m0+r)*K + k0 + seg, &As[r*LDK + seg]);
      stage16bf(W + (size_t)(n0+r)*K + k0 + seg, &Ws[r*LDK + seg]);
      __syncthreads();
      step();
    }
  }
#pragma unroll
  for(int i=0;i<2;i++){
#pragma unroll
    for(int j=0;j<2;j++){
      int mb = m0 + wr + i*16 + (lane>>4)*4;
      int n  = n0 + wc + j*16 + (lane&15);
#pragma unroll
      for(int rg=0;rg<4;rg++){
        int m = mb + rg;
        float v = acc[i][j][rg];
        size_t o = (size_t)m*N + n;
        if(MODE==0){ if(OBF) Cb[o] = f2bf(v); else C[o] = v; }
        else if(MODE==3){ C[o] = rs[o] + v; }
        else if(MODE==5){
          float gs = (0.5f/3.0f)/(1.0f+expf(-gp2[0]));
          C[o] = gs*(rs[o]+v);
        }
      }
    }
  }
}

// ---------------- dual-W bf16 MFMA GEMM (z-batched): C(bf16) = silu(LN(A)@G^T)*(LN(A)@V^T), K==128 ----------------
__global__ __launch_bounds__(256) void gemm_dual(
    const float* __restrict__ A, const unsigned short* __restrict__ G,
    const unsigned short* __restrict__ V,
    unsigned short* __restrict__ C, int M, int N, int K,
    const float* __restrict__ sv, const float* __restrict__ bv,
    size_t az, size_t wz, size_t cz, size_t pz){
  __shared__ unsigned short As[64*LDK];
  __shared__ unsigned short Gs[64*LDK];
  __shared__ unsigned short Vs[64*LDK];
  const int z = blockIdx.z;
  A += z*az; G += z*wz; V += z*wz; C += z*cz; sv += z*pz; bv += z*pz;
  int tid  = threadIdx.x;
  int m0   = blockIdx.y*64, n0 = blockIdx.x*64;
  int w    = tid>>6, lane = tid&63;
  int wr   = (w>>1)*32, wc = (w&1)*32;
  int r    = tid>>2, seg = (tid&3)*16;
  f32x4 accg[2][2] = {};
  f32x4 accv[2][2] = {};
  float fr[32]; float mean, rstd;
  {
    const float* arow = A + (size_t)(m0+r)*K + seg;   // K==128
#pragma unroll
    for(int j=0;j<4;j++) *reinterpret_cast<float4*>(&fr[j*4])    = *reinterpret_cast<const float4*>(arow + j*4);
#pragma unroll
    for(int j=0;j<4;j++) *reinterpret_cast<float4*>(&fr[16+j*4]) = *reinterpret_cast<const float4*>(arow + 64 + j*4);
    float s1=0.f, s2=0.f;
#pragma unroll
    for(int j=0;j<32;j++){ s1 += fr[j]; s2 += fr[j]*fr[j]; }
    s1 += __shfl_xor(s1,1,64); s1 += __shfl_xor(s1,2,64);
    s2 += __shfl_xor(s2,1,64); s2 += __shfl_xor(s2,2,64);
    mean = s1*(1.0f/DD);
    float var = s2*(1.0f/DD) - mean*mean;
    rstd = rsqrtf(var + 1e-5f);
  }
#pragma unroll
  for(int kh=0; kh<2; ++kh){              // static unroll: fr index compile-time
    int k0 = kh*64;
    __syncthreads();
    stageLN(fr + kh*16, mean, rstd, sv + k0 + seg, bv + k0 + seg, &As[r*LDK + seg]);
    stage16bf(G + (size_t)(n0+r)*K + k0 + seg, &Gs[r*LDK + seg]);
    stage16bf(V + (size_t)(n0+r)*K + k0 + seg, &Vs[r*LDK + seg]);
    __syncthreads();
#pragma unroll
    for(int kk=0;kk<64;kk+=32){
      int ko = kk + (lane>>4)*8;
      bf16x8 a0 = *reinterpret_cast<const bf16x8*>(&As[(wr    + (lane&15))*LDK + ko]);
      bf16x8 a1 = *reinterpret_cast<const bf16x8*>(&As[(wr+16 + (lane&15))*LDK + ko]);
      bf16x8 g0 = *reinterpret_cast<const bf16x8*>(&Gs[(wc    + (lane&15))*LDK + ko]);
      bf16x8 g1 = *reinterpret_cast<const bf16x8*>(&Gs[(wc+16 + (lane&15))*LDK + ko]);
      bf16x8 v0 = *reinterpret_cast<const bf16x8*>(&Vs[(wc    + (lane&15))*LDK + ko]);
      bf16x8 v1 = *reinterpret_cast<const bf16x8*>(&Vs[(wc+16 + (lane&15))*LDK + ko]);
      accg[0][0] = __builtin_amdgcn_mfma_f32_16x16x32_bf16(a0,g0,accg[0][0],0,0,0);
      accg[0][1] = __builtin_amdgcn_mfma_f32_16x16x32_bf16(a0,g1,accg[0][1],0,0,0);
      accg[1][0] = __builtin_amdgcn_mfma_f32_16x16x32_bf16(a1,g0,accg[1][0],0,0,0);
      accg[1][1] = __builtin_amdgcn_mfma_f32_16x16x32_bf16(a1,g1,accg[1][1],0,0,0);
      accv[0][0] = __builtin_amdgcn_mfma_f32_16x16x32_bf16(a0,v0,accv[0][0],0,0,0);
      accv[0][1] = __builtin_amdgcn_mfma_f32_16x16x32_bf16(a0,v1,accv[0][1],0,0,0);
      accv[1][0] = __builtin_amdgcn_mfma_f32_16x16x32_bf16(a1,v0,accv[1][0],0,0,0);
      accv[1][1] = __builtin_amdgcn_mfma_f32_16x16x32_bf16(a1,v1,accv[1][1],0,0,0);
    }
  }
#pragma unroll
  for(int i=0;i<2;i++){
#pragma unroll
    for(int j=0;j<2;j++){
      int mb = m0 + wr + i*16 + (lane>>4)*4;
      int n  = n0 + wc + j*16 + (lane&15);
#pragma unroll
      for(int rg=0;rg<4;rg++){
        float gg = accg[i][j][rg];
        float vv = accv[i][j][rg];
        float sg = gg/(1.0f+expf(-gg));
        C[(size_t)(mb+rg)*N + n] = f2bf(sg*vv);
      }
    }
  }
}

// ---------------- MoE pair-combine GEMM: go[g] = c0*(A0@W0^T) + c1*(A1@W1^T), K=DFF ----------------
__global__ __launch_bounds__(256) void gemm_moe2(
    const unsigned short* __restrict__ Ab, const unsigned short* __restrict__ Wb,
    float* __restrict__ Cb, const float* __restrict__ coef){
  __shared__ unsigned short As0[64*LDK];
  __shared__ unsigned short As1[64*LDK];
  __shared__ unsigned short Ws0[64*LDK];
  __shared__ unsigned short Ws1[64*LDK];
  const int g = blockIdx.z;
  const unsigned short* A0 = Ab + (size_t)(2*g)*NTOK*DFF;
  const unsigned short* A1 = A0 + (size_t)NTOK*DFF;
  const unsigned short* W0 = Wb + (size_t)(2*g)*DD*DFF;
  const unsigned short* W1 = W0 + (size_t)DD*DFF;
  float* C = Cb + (size_t)g*NTOK*DD;
  const float* c0 = coef + (size_t)(2*g)*NTOK;
  const float* c1 = c0 + NTOK;
  int tid  = threadIdx.x;
  int m0   = blockIdx.y*64, n0 = blockIdx.x*64;
  int w    = tid>>6, lane = tid&63;
  int wr   = (w>>1)*32, wc = (w&1)*32;
  int r    = tid>>2, seg = (tid&3)*16;
  f32x4 a0acc[2][2] = {};
  f32x4 a1acc[2][2] = {};
  for(int k0=0;k0<DFF;k0+=64){
    __syncthreads();
    stage16bf(A0 + (size_t)(m0+r)*DFF + k0 + seg, &As0[r*LDK + seg]);
    stage16bf(A1 + (size_t)(m0+r)*DFF + k0 + seg, &As1[r*LDK + seg]);
    stage16bf(W0 + (size_t)(n0+r)*DFF + k0 + seg, &Ws0[r*LDK + seg]);
    stage16bf(W1 + (size_t)(n0+r)*DFF + k0 + seg, &Ws1[r*LDK + seg]);
    __syncthreads();
#pragma unroll
    for(int kk=0;kk<64;kk+=32){
      int ko = kk + (lane>>4)*8;
      bf16x8 x00 = *reinterpret_cast<const bf16x8*>(&As0[(wr    + (lane&15))*LDK + ko]);
      bf16x8 x01 = *reinterpret_cast<const bf16x8*>(&As0[(wr+16 + (lane&15))*LDK + ko]);
      bf16x8 x10 = *reinterpret_cast<const bf16x8*>(&As1[(wr    + (lane&15))*LDK + ko]);
      bf16x8 x11 = *reinterpret_cast<const bf16x8*>(&As1[(wr+16 + (lane&15))*LDK + ko]);
      bf16x8 w00 = *reinterpret_cast<const bf16x8*>(&Ws0[(wc    + (lane&15))*LDK + ko]);
      bf16x8 w01 = *reinterpret_cast<const bf16x8*>(&Ws0[(wc+16 + (lane&15))*LDK + ko]);
      bf16x8 w10 = *reinterpret_cast<const bf16x8*>(&Ws1[(wc    + (lane&15))*LDK + ko]);
      bf16x8 w11 = *reinterpret_cast<const bf16x8*>(&Ws1[(wc+16 + (lane&15))*LDK + ko]);
      a0acc[0][0] = __builtin_amdgcn_mfma_f32_16x16x32_bf16(x00,w00,a0acc[0][0],0,0,0);
      a0acc[0][1] = __builtin_amdgcn_mfma_f32_16x16x32_bf16(x00,w01,a0acc[0][1],0,0,0);
      a0acc[1][0] = __builtin_amdgcn_mfma_f32_16x16x32_bf16(x01,w00,a0acc[1][0],0,0,0);
      a0acc[1][1] = __builtin_amdgcn_mfma_f32_16x16x32_bf16(x01,w01,a0acc[1][1],0,0,0);
      a1acc[0][0] = __builtin_amdgcn_mfma_f32_16x16x32_bf16(x10,w10,a1acc[0][0],0,0,0);
      a1acc[0][1] = __builtin_amdgcn_mfma_f32_16x16x32_bf16(x10,w11,a1acc[0][1],0,0,0);
      a1acc[1][0] = __builtin_amdgcn_mfma_f32_16x16x32_bf16(x11,w10,a1acc[1][0],0,0,0);
      a1acc[1][1] = __builtin_amdgcn_mfma_f32_16x16x32_bf16(x11,w11,a1acc[1][1],0,0,0);
    }
  }
#pragma unroll
  for(int i=0;i<2;i++){
#pragma unroll
    for(int j=0;j<2;j++){
      int mb = m0 + wr + i*16 + (lane>>4)*4;
      int n  = n0 + wc + j*16 + (lane&15);
#pragma unroll
      for(int rg=0;rg<4;rg++){
        int m = mb + rg;
        C[(size_t)m*DD + n] = c0[m]*a0acc[i][j][rg] + c1[m]*a1acc[i][j][rg];
      }
    }
  }
}

// ---------------- fused MFMA flash attention: double-buffered K/V, 1 barrier/tile ----------------
// flat grid 1536 with XCD-aware remap (R16). Issue-early/write-late staging (T14).
#define PSW(row) (((row)&8)<<1)              // Ps col ^= 16 when row bit3 set
#define VSW(row) ((((row)>>3)&3)<<3)         // Vt col ^= 8*((row>>3)&3)
__global__ __launch_bounds__(256) void attn_fused(
    const unsigned short* __restrict__ qkv,
    unsigned short* __restrict__ obuf){
  __shared__ __align__(16) unsigned short Ks[2][64*40];
  __shared__ __align__(16) unsigned short Vt[2][32*72];
  __shared__ __align__(16) unsigned short Vones[16*72];
  __shared__ __align__(16) unsigned short Ps[4][16*72];
  const int tid = threadIdx.x;
  const int w = tid>>6, lane = tid&63;
  const int lr = lane&15, lg = lane>>4;
  // XCD-aware decode: n%8 = XCD residue; each residue owns 12 groups of 16 blocks
  const int n_  = blockIdx.x;
  const int kx  = n_ & 7, jx = n_ >> 3;        // jx: 0..191
  const int grp = kx*12 + (jx>>4);             // 0..95 (bijective)
  const int bx  = jx & 15;
  const int h   = grp & 3;
  const int b   = (grp>>2) & 7;
  const int br  = grp >> 5;
  const int qtok0 = b*TT + bx*64 + w*16;
  for(int idx=tid; idx<16*72; idx+=256)
    Vones[idx] = (idx < 64) ? (unsigned short)0x3F80 : (unsigned short)0;
  const unsigned short* qp = qkv + (size_t)br*NTOK*QKVN + (size_t)(qtok0 + lr)*QKVN + h*HDD + lg*8;
  bf16x8 qa = *reinterpret_cast<const bf16x8*>(qp);
  f32x4 o0 = {}, o1 = {}, o2 = {};
  float m[4] = {-1e30f,-1e30f,-1e30f,-1e30f};
  const unsigned short* KVbase = qkv + (size_t)br*NTOK*QKVN + (size_t)(b*TT)*QKVN + DD + h*HDD;
  const int skey0 = (tid    )>>3, sseg0 = ((tid    )&7)*4;
  const int skey1 = (tid+256)>>3, sseg1 = ((tid+256)&7)*4;

  // prologue: stage tile 0 into buffer 0
  {
    const unsigned short* s0 = KVbase + (size_t)skey0*QKVN + sseg0;
    const unsigned short* s1 = KVbase + (size_t)skey1*QKVN + sseg1;
    uint2 k0v = *reinterpret_cast<const uint2*>(s0);
    uint2 v0v = *reinterpret_cast<const uint2*>(s0 + DD);
    uint2 k1v = *reinterpret_cast<const uint2*>(s1);
    uint2 v1v = *reinterpret_cast<const uint2*>(s1 + DD);
    *reinterpret_cast<uint2*>(&Ks[0][skey0*40+sseg0]) = k0v;
    *reinterpret_cast<uint2*>(&Ks[0][skey1*40+sseg1]) = k1v;
    unsigned short vs[4];
    *reinterpret_cast<uint2*>(vs) = v0v;
    { const int kc = skey0 ^ VSW(sseg0);
      Vt[0][(sseg0  )*72+kc]=vs[0]; Vt[0][(sseg0+1)*72+kc]=vs[1];
      Vt[0][(sseg0+2)*72+kc]=vs[2]; Vt[0][(sseg0+3)*72+kc]=vs[3]; }
    *reinterpret_cast<uint2*>(vs) = v1v;
    { const int kc = skey1 ^ VSW(sseg1);
      Vt[0][(sseg1  )*72+kc]=vs[0]; Vt[0][(sseg1+1)*72+kc]=vs[1];
      Vt[0][(sseg1+2)*72+kc]=vs[2]; Vt[0][(sseg1+3)*72+kc]=vs[3]; }
  }
  __syncthreads();

  for(int t=0; t<16; t++){
    const int cur = t & 1;
    // issue next-tile loads early (latency hides under compute)
    uint2 kn0, vn0, kn1, vn1;
    if(t < 15){
      const unsigned short* s0 = KVbase + (size_t)((t+1)*64 + skey0)*QKVN + sseg0;
      const unsigned short* s1 = KVbase + (size_t)((t+1)*64 + skey1)*QKVN + sseg1;
      kn0 = *reinterpret_cast<const uint2*>(s0);
      vn0 = *reinterpret_cast<const uint2*>(s0 + DD);
      kn1 = *reinterpret_cast<const uint2*>(s1);
      vn1 = *reinterpret_cast<const uint2*>(s1 + DD);
    }
    // QK^T
    f32x4 s[4];
#pragma unroll
    for(int f=0;f<4;f++){
      bf16x8 kb = *reinterpret_cast<const bf16x8*>(&Ks[cur][(f*16+lr)*40 + lg*8]);
      f32x4 z = {};
      s[f] = __builtin_amdgcn_mfma_f32_16x16x32_bf16(qa,kb,z,0,0,0);
    }
    // defer-max softmax
    float tmax[4]; bool need=false;
#pragma unroll
    for(int r=0;r<4;r++){
      tmax[r] = fmaxf(fmaxf(s[0][r],s[1][r]),fmaxf(s[2][r],s[3][r]));
      need = need || (tmax[r] > m[r] + 8.0f);
    }
    if(__any(need)){
#pragma unroll
      for(int r=0;r<4;r++){
        float t2 = tmax[r];
#pragma unroll
        for(int off=1;off<16;off<<=1) t2 = fmaxf(t2,__shfl_xor(t2,off,64));
        float nm = fmaxf(m[r],t2);
        float sc = __builtin_amdgcn_exp2f(m[r]-nm);
        m[r] = nm; o0[r] *= sc; o1[r] *= sc; o2[r] *= sc;
      }
    }
#pragma unroll
    for(int r=0;r<4;r++){
      const int q = lg*4+r;
      const int cw = PSW(q);
#pragma unroll
      for(int f=0;f<4;f++){
        float p = __builtin_amdgcn_exp2f(s[f][r]-m[r]);
        Ps[w][q*72 + ((f*16+lr)^cw)] = f2bf(p);
      }
    }
    // PV + row-sum
    const int pw_ = PSW(lr);
    bf16x8 pa0 = *reinterpret_cast<const bf16x8*>(&Ps[w][lr*72 + ((lg*8   )^pw_)]);
    bf16x8 pa1 = *reinterpret_cast<const bf16x8*>(&Ps[w][lr*72 + ((lg*8+32)^pw_)]);
    {
      const int r_ = lr, vw = VSW(r_);
      bf16x8 vb0 = *reinterpret_cast<const bf16x8*>(&Vt[cur][r_*72 + ((lg*8   )^vw)]);
      bf16x8 vb1 = *reinterpret_cast<const bf16x8*>(&Vt[cur][r_*72 + ((lg*8+32)^vw)]);
      o0 = __builtin_amdgcn_mfma_f32_16x16x32_bf16(pa0,vb0,o0,0,0,0);
      o0 = __builtin_amdgcn_mfma_f32_16x16x32_bf16(pa1,vb1,o0,0,0,0);
    }
    {
      const int r_ = 16+lr, vw = VSW(r_);
      bf16x8 vb0 = *reinterpret_cast<const bf16x8*>(&Vt[cur][(r_-16)*72 + ((lg*8   )^vw)+16*72]);
      bf16x8 vb1 = *reinterpret_cast<const bf16x8*>(&Vt[cur][(r_-16)*72 + ((lg*8+32)^vw)+16*72]);
      o1 = __builtin_amdgcn_mfma_f32_16x16x32_bf16(pa0,vb0,o1,0,0,0);
      o1 = __builtin_amdgcn_mfma_f32_16x16x32_bf16(pa1,vb1,o1,0,0,0);
    }
    {
      const int r_ = 32+lr, vw = VSW(r_);
      bf16x8 vb0 = *reinterpret_cast<const bf16x8*>(&Vones[lr*72 + ((lg*8   )^vw)]);
      bf16x8 vb1 = *reinterpret_cast<const bf16x8*>(&Vones[lr*72 + ((lg*8+32)^vw)]);
      o2 = __builtin_amdgcn_mfma_f32_16x16x32_bf16(pa0,vb0,o2,0,0,0);
      o2 = __builtin_amdgcn_mfma_f32_16x16x32_bf16(pa1,vb1,o2,0,0,0);
    }
    // write next tile into alternate buffer (loads have completed under compute)
    if(t < 15){
      const int nb = cur ^ 1;
      *reinterpret_cast<uint2*>(&Ks[nb][skey0*40+sseg0]) = kn0;
      *reinterpret_cast<uint2*>(&Ks[nb][skey1*40+sseg1]) = kn1;
      unsigned short vs[4];
      *reinterpret_cast<uint2*>(vs) = vn0;
      { const int kc = skey0 ^ VSW(sseg0);
        Vt[nb][(sseg0  )*72+kc]=vs[0]; Vt[nb][(sseg0+1)*72+kc]=vs[1];
        Vt[nb][(sseg0+2)*72+kc]=vs[2]; Vt[nb][(sseg0+3)*72+kc]=vs[3]; }
      *reinterpret_cast<uint2*>(vs) = vn1;
      { const int kc = skey1 ^ VSW(sseg1);
        Vt[nb][(sseg1  )*72+kc]=vs[0]; Vt[nb][(sseg1+1)*72+kc]=vs[1];
        Vt[nb][(sseg1+2)*72+kc]=vs[2]; Vt[nb][(sseg1+3)*72+kc]=vs[3]; }
    }
    __syncthreads();
  }
#pragma unroll
  for(int r=0;r<4;r++){
    float lsr = __shfl(o2[r], lane & 48, 64);   // broadcast col-0 (row-sum)
    float inv = 1.0f/lsr;
    int row = qtok0 + lg*4 + r;
    unsigned short* orow = obuf + (size_t)br*NTOK*DD + (size_t)row*DD + h*HDD;
    orow[lr]    = f2bf(o0[r]*inv);
    orow[16+lr] = f2bf(o1[r]*inv);
  }
}

// ---------------- launch ----------------
extern "C" void kernel_launch(void* const* d_in, const int* in_sizes, int n_in,
                              void* d_out, int out_size, void* d_ws, size_t ws_size,
                              hipStream_t stream){
  (void)in_sizes; (void)n_in; (void)out_size; (void)ws_size;
  const float* x       = (const float*)d_in[0];
  const float* gr_g    = (const float*)d_in[1];
  const float* gr_b    = (const float*)d_in[2];
  const float* q6_w    = (const float*)d_in[3];
  const float* logtemp = (const float*)d_in[4];
  const float* grp_g   = (const float*)d_in[5];
  const float* grp_b   = (const float*)d_in[6];
  const float* gpw     = (const float*)d_in[7];
  const float* gpb     = (const float*)d_in[8];
  const float* me_g    = (const float*)d_in[9];
  const float* me_b    = (const float*)d_in[10];
  const float* me_gate = (const float*)d_in[11];
  const float* me_val  = (const float*)d_in[12];
  const float* me_out  = (const float*)d_in[13];
  const float* br_in   = (const float*)d_in[14];
  const float* br_outw = (const float*)d_in[15];
  const float* nq_g    = (const float*)d_in[16];
  const float* nq_b    = (const float*)d_in[17];
  const float* nkv_g   = (const float*)d_in[18];
  const float* nkv_b   = (const float*)d_in[19];
  const float* nff_g   = (const float*)d_in[20];
  const float* nff_b   = (const float*)d_in[21];
  const float* brg_w   = (const float*)d_in[22];
  const float* brv_w   = (const float*)d_in[23];
  const float* brf_w   = (const float*)d_in[24];
  const float* br_gate = (const float*)d_in[25];
  const float* on_g    = (const float*)d_in[26];
  const float* on_b    = (const float*)d_in[27];
  const float* out_w   = (const float*)d_in[28];
  float* out = (float*)d_out;
  float* ws  = (float*)d_ws;

  float* coef  = ws;                                        // 49152
  float* part  = ws + 65536;                                // 18432
  unsigned short* gvb6 = (unsigned short*)(ws + 131072);    // 6*8192*256 bf16
  float* go    = ws + 6731072;                              // 3*1048576 fp32
  unsigned short* qkv  = (unsigned short*)(ws + 9900000);   // 3*8192*384 bf16
  unsigned short* obuf = (unsigned short*)(ws + 14700000);  // 3*8192*128 bf16
  unsigned short* wbf  = (unsigned short*)(ws + 21400000);  // WB_TOT bf16 weights
  float* xb    = ws + 23000000;                             // 3*1048576 fp32
  unsigned short* gvb2 = (unsigned short*)(ws + 26200000);  // 3*8192*256 bf16
  float* bsum  = ws + 29400000;                             // 3*1048576 fp32
  float* gw    = ws + 32700000;                             // 24576

  // 1/sqrt(32) * log2(e): softmax runs in the exp2 domain (folded into Q weights)
  const float qscale = 0.17677669529663687f * 1.4426950408889634f;

  // 0. one-time weight conversion fp32 -> bf16 (qscale folded into br_in Q rows)
  wconv<<<1072,256,0,stream>>>(me_gate, me_val, me_out, br_in, br_outw,
                               brg_w, brv_w, brf_w, out_w, wbf, qscale);

  // 1. routing (fused LN) + lb
  routing_kernel<<<2048,256,0,stream>>>(x, gr_g, gr_b, q6_w, logtemp,
                                        grp_g, grp_b, gpw, gpb, gw, coef, part);
  lb_kernel<<<1,256,0,stream>>>(part, out + 1048576);

  // 2. MoE: all 6 experts in one dual dispatch; pair-combine into go (z=group)
  gemm_dual<<<dim3(4,128,6),256,0,stream>>>(x, wbf+WB_MEGATE, wbf+WB_MEVAL, gvb6,
      NTOK,DFF,DD, me_g, me_b, 0, (size_t)DFF*DD, (size_t)NTOK*DFF, DD);
  gemm_moe2<<<dim3(2,128,3),256,0,stream>>>(gvb6, wbf+WB_MEOUT, go, coef);

  // 3. bridges: fused QKV projection, attn (dbuf, XCD-swizzled, bf16 out), out-proj+resid, FFN, bridge-scale
  gemm_mfma<0,1,0,1,0,0,0,1><<<dim3(6,128,3),256,0,stream>>>(go, wbf+WB_BRIN, qkv,
      NTOK,QKVN,DD, nq_g, nq_b, nkv_g, nkv_b,
      0, (size_t)QKVN*DD, (size_t)NTOK*QKVN, DD, 0, 0);
  attn_fused<<<1536,256,0,stream>>>(qkv, obuf);
  gemm_mfma<3,0,1,0,0,1,0,0><<<dim3(2,128,3),256,0,stream>>>(obuf, wbf+WB_BROUT, xb,
      NTOK,DD,DD, nullptr, nullptr, go, nullptr,
      (size_t)NTOK*DD, (size_t)DD*DD, (size_t)NTOK*DD, 0, 0, 0);
  gemm_dual<<<dim3(4,128,3),256,0,stream>>>(xb, wbf+WB_BRG, wbf+WB_BRV, gvb2,
      NTOK,2*DD,DD, nff_g, nff_b, (size_t)NTOK*DD, (size_t)2*DD*DD, (size_t)NTOK*2*DD, DD);
  gemm_mfma<5,0,1,0,0,0,0,0><<<dim3(2,128,3),256,0,stream>>>(gvb2, wbf+WB_BRF, bsum,
      NTOK,DD,2*DD, nullptr, nullptr, xb, br_gate,
      (size_t)NTOK*2*DD, (size_t)DD*2*DD, (size_t)NTOK*DD, 0, (size_t)NTOK*DD, 1);

  // 4. final: LN over (go0+go1+go2+bsum0+bsum1+bsum2), projection
  gemm_mfma<0,1,0,0,0,0,1,0><<<dim3(2,128,1),256,0,stream>>>(go, wbf+WB_OUTW, out,
      NTOK,DD,DD, on_g, on_b, bsum, nullptr,
      0, 0, 0, 0, 0, 0);
}

// Round 18
// 184.145 us; speedup vs baseline: 1.0818x; 1.0376x over previous
//
#include <hip/hip_runtime.h>
#include <math.h>

#define DD    128
#define DFF   256
#define NHH   4
#define HDD   32
#define BB    8
#define TT    1024
#define NTOK  (BB*TT)          // 8192
#define LDK   72               // padded LDS row stride (bf16 elements) for GEMM tiles
#define QKVN  384              // fused QKV row width

// bf16 weight workspace offsets (elements)
#define WB_MEGATE 0
#define WB_MEVAL  196608
#define WB_MEOUT  393216
#define WB_BRIN   589824
#define WB_BROUT  737280
#define WB_BRG    786432
#define WB_BRV    884736
#define WB_BRF    983040
#define WB_OUTW   1081344
#define WB_TOT    1097728

typedef __bf16 bf16x8 __attribute__((ext_vector_type(8)));
typedef float  f32x4  __attribute__((ext_vector_type(4)));

// ---------------- wave helpers (wave64) ----------------
__device__ __forceinline__ float wsum(float v){
#pragma unroll
  for(int o=32;o>0;o>>=1) v += __shfl_xor(v,o,64);
  return v;
}
__device__ __forceinline__ float wmaxr(float v){
#pragma unroll
  for(int o=32;o>0;o>>=1) v = fmaxf(v,__shfl_xor(v,o,64));
  return v;
}
__device__ __forceinline__ unsigned short f2bf(float x){
  __bf16 h = (__bf16)x;
  unsigned short u;
  __builtin_memcpy(&u, &h, 2);
  return u;
}

// stage 16 consecutive fp32 (global) -> 16 bf16 in LDS
__device__ __forceinline__ void stage16(const float* __restrict__ gp,
                                        unsigned short* __restrict__ dst){
  float4 f0 = *reinterpret_cast<const float4*>(gp);
  float4 f1 = *reinterpret_cast<const float4*>(gp+4);
  float4 f2 = *reinterpret_cast<const float4*>(gp+8);
  float4 f3 = *reinterpret_cast<const float4*>(gp+12);
  float f[16] = {f0.x,f0.y,f0.z,f0.w, f1.x,f1.y,f1.z,f1.w,
                 f2.x,f2.y,f2.z,f2.w, f3.x,f3.y,f3.z,f3.w};
  unsigned short h[16];
#pragma unroll
  for(int j=0;j<16;j++) h[j] = f2bf(f[j]);
  *reinterpret_cast<uint4*>(dst)   = *reinterpret_cast<const uint4*>(h);
  *reinterpret_cast<uint4*>(dst+8) = *reinterpret_cast<const uint4*>(h+8);
}

// stage 16 consecutive bf16 (global) -> LDS (pure copy, 2x16B)
__device__ __forceinline__ void stage16bf(const unsigned short* __restrict__ gp,
                                          unsigned short* __restrict__ dst){
  const uint4* s = reinterpret_cast<const uint4*>(gp);
  *reinterpret_cast<uint4*>(dst)   = s[0];
  *reinterpret_cast<uint4*>(dst+8) = s[1];
}

// stage 16 fp32 from registers with LN affine -> LDS bf16 (fr base must be compile-time)
__device__ __forceinline__ void stageLN(const float* __restrict__ fr,
                                        float mean, float rstd,
                                        const float* __restrict__ g,
                                        const float* __restrict__ b,
                                        unsigned short* __restrict__ dst){
  unsigned short h[16];
#pragma unroll
  for(int j=0;j<16;j++){
    float y = (fr[j]-mean)*rstd*g[j] + b[j];
    h[j] = f2bf(y);
  }
  *reinterpret_cast<uint4*>(dst)   = *reinterpret_cast<const uint4*>(h);
  *reinterpret_cast<uint4*>(dst+8) = *reinterpret_cast<const uint4*>(h+8);
}

// ---------------- one-time weight fp32->bf16 conversion (qscale folded into br_in Q rows) ----------------
__global__ __launch_bounds__(256) void wconv(
    const float* __restrict__ a0, const float* __restrict__ a1, const float* __restrict__ a2,
    const float* __restrict__ a3, const float* __restrict__ a4, const float* __restrict__ a5,
    const float* __restrict__ a6, const float* __restrict__ a7, const float* __restrict__ a8,
    unsigned short* __restrict__ dst, float qsc){
  size_t i = ((size_t)blockIdx.x*256 + threadIdx.x)*4;
  if(i >= WB_TOT) return;
  const float* s; size_t off = i; float sc = 1.0f;
  if(i < WB_MEVAL){ s=a0; }
  else if(i < WB_MEOUT){ s=a1; off = i-WB_MEVAL; }
  else if(i < WB_BRIN ){ s=a2; off = i-WB_MEOUT; }
  else if(i < WB_BROUT){ s=a3; off = i-WB_BRIN;
    int row = (int)(off>>7); if((row % 384) < 128) sc = qsc; }
  else if(i < WB_BRG ){ s=a4; off = i-WB_BROUT; }
  else if(i < WB_BRV ){ s=a5; off = i-WB_BRG; }
  else if(i < WB_BRF ){ s=a6; off = i-WB_BRV; }
  else if(i < WB_OUTW){ s=a7; off = i-WB_BRF; }
  else { s=a8; off = i-WB_OUTW; }
  float4 v = *reinterpret_cast<const float4*>(s + off);
  unsigned short h4[4] = {f2bf(v.x*sc), f2bf(v.y*sc), f2bf(v.z*sc), f2bf(v.w*sc)};
  *reinterpret_cast<uint2*>(dst + i) = *reinterpret_cast<const uint2*>(h4);
}

// ---------------- routing: one wave per token (LN fused) ----------------
__global__ __launch_bounds__(256) void routing_kernel(
    const float* __restrict__ x,
    const float* __restrict__ gr_g, const float* __restrict__ gr_b,
    const float* __restrict__ q6,   const float* __restrict__ logtemp,
    const float* __restrict__ grp_g,const float* __restrict__ grp_b,
    const float* __restrict__ gpw,  const float* __restrict__ gpb,
    float* __restrict__ gw_out, float* __restrict__ coef, float* __restrict__ part){
  __shared__ float sp[4][9];
  int lane = threadIdx.x & 63;
  int wv   = threadIdx.x >> 6;
  int t    = (blockIdx.x<<2) + wv;
  const float* xr = x + (size_t)t*DD;
  float r0 = xr[lane], r1 = xr[lane+64];
  float mn = wsum(r0+r1) * (1.0f/DD);
  float d0 = r0-mn, d1 = r1-mn;
  float vv = wsum(d0*d0 + d1*d1) * (1.0f/DD);
  float rstd = rsqrtf(vv + 1e-5f);
  float x0 = d0*rstd, x1 = d1*rstd;
  float h0 = x0*gr_g[lane]+gr_b[lane];
  float h1 = x1*gr_g[lane+64]+gr_b[lane+64];
  float sb[6];
#pragma unroll
  for(int j=0;j<6;j++){
    float p = h0*q6[j*DD+lane] + h1*q6[j*DD+lane+64];
    sb[j] = tanhf(wsum(p));
  }
  float sim = 0.f;
#pragma unroll
  for(int j=0;j<6;j++) sim += ((lane>>(5-j))&1) ? sb[j] : -sb[j];
  float temp = expf(logtemp[0]); temp = fminf(fmaxf(temp,0.1f),5.0f);
  float mx = wmaxr(sim);
  float p  = expf((sim-mx)/temp);
  float w  = p / wsum(p);
  float sh[6];
#pragma unroll
  for(int j=0;j<6;j++) sh[j] = wsum(((lane>>(5-j))&1) ? w : -w);
  const float A0[6]={0,1,1,0,1,1}, A1[6]={0,-1,0,1,0,0}, A2[6]={-1,0,-1,-1,0,-1};
  float l0=0,l1=0,l2=0;
#pragma unroll
  for(int j=0;j<6;j++){ l0+=sh[j]*A0[j]; l1+=sh[j]*A1[j]; l2+=sh[j]*A2[j]; }
  float m3 = fmaxf(l0,fmaxf(l1,l2));
  float e0=expf(l0-m3), e1=expf(l1-m3), e2=expf(l2-m3);
  float inv3 = 1.0f/(e0+e1+e2);
  float g0=e0*inv3, g1=e1*inv3, g2=e2*inv3;
  if(lane==0){ gw_out[t*3]=g0; gw_out[t*3+1]=g1; gw_out[t*3+2]=g2; }
  float gwv[3]={g0,g1,g2};
  float pw[6];
#pragma unroll
  for(int g=0; g<3; g++){
    float hg0 = x0*grp_g[g*DD+lane]    + grp_b[g*DD+lane];
    float hg1 = x1*grp_g[g*DD+lane+64] + grp_b[g*DD+lane+64];
    float q0 = wsum(hg0*gpw[(g*2+0)*DD+lane] + hg1*gpw[(g*2+0)*DD+lane+64]) + gpb[g*2+0];
    float q1 = wsum(hg0*gpw[(g*2+1)*DD+lane] + hg1*gpw[(g*2+1)*DD+lane+64]) + gpb[g*2+1];
    float mm = fmaxf(q0,q1);
    float a0 = expf(q0-mm), a1 = expf(q1-mm);
    float inv = 1.0f/(a0+a1);
    float w0 = a0*inv, w1 = a1*inv;
    pw[g*2]=w0; pw[g*2+1]=w1;
    float invs = 1.0f/(w0+w1+1e-8f);
    if(lane==0){
      coef[(size_t)(2*g  )*NTOK + t] = gwv[g]*w0*invs;
      coef[(size_t)(2*g+1)*NTOK + t] = gwv[g]*w1*invs;
    }
  }
  if(lane==0){
    sp[wv][0]=g0; sp[wv][1]=g1; sp[wv][2]=g2;
#pragma unroll
    for(int k=0;k<6;k++) sp[wv][3+k]=pw[k];
  }
  __syncthreads();
  if(threadIdx.x<9){
    part[blockIdx.x*9+threadIdx.x] =
      sp[0][threadIdx.x]+sp[1][threadIdx.x]+sp[2][threadIdx.x]+sp[3][threadIdx.x];
  }
}

// ---------------- load-balance loss reduce (deterministic, parallel) ----------------
__global__ __launch_bounds__(256) void lb_kernel(const float* __restrict__ part, float* __restrict__ outlb){
  __shared__ float sm[4][9];
  float acc[9] = {};
  for(int i=threadIdx.x; i<2048; i+=256){
#pragma unroll
    for(int c=0;c<9;c++) acc[c] += part[i*9+c];
  }
#pragma unroll
  for(int c=0;c<9;c++) acc[c] = wsum(acc[c]);
  int wv = threadIdx.x>>6, lane = threadIdx.x&63;
  if(lane==0){
#pragma unroll
    for(int c=0;c<9;c++) sm[wv][c]=acc[c];
  }
  __syncthreads();
  if(threadIdx.x==0){
    const float invN = 1.0f/(float)NTOK;
    float lb=0;
#pragma unroll
    for(int c=0;c<9;c++){
      float s = sm[0][c]+sm[1][c]+sm[2][c]+sm[3][c];
      float mw = s*invN;
      lb -= mw*logf(mw+1e-8f);
    }
    outlb[0] = lb*0.01f;
  }
}

// ---------------- bf16 MFMA GEMM (z-batched): C = epi(LN?(A) @ W^T), W pre-converted bf16 ----------------
// MODE 0: store (OBF->bf16)  3: resid+acc  5: BW*sigmoid(gptr[0])*(resid+acc)
// LN=1: K==128, A fp32, LN fused. SUM=1 (with LN): A-row = sum of 3 go + 3 bsum rows.
// ABF=1: A bf16. PSEL/RSEL: 0 = z*stride, 1 = pairsA[z], 2 = pairsB[z].
// QKV=1: blockIdx.x<2 -> Q (pairsA A, sv/bv LN), else KV (pairsB A, resid/gptr LN).
template<int MODE,int LN,int ABF,int OBF,int PSEL,int RSEL,int SUM,int QKV>
__global__ __launch_bounds__(256) void gemm_mfma(
    const void* __restrict__ Ap, const unsigned short* __restrict__ W, void* __restrict__ Cp,
    int M, int N, int K,
    const float* __restrict__ sv, const float* __restrict__ bv,
    const float* __restrict__ resid, const float* __restrict__ gptr,
    size_t az, size_t wz, size_t cz, size_t pz, size_t rz, size_t gz){
  __shared__ unsigned short As[64*LDK];
  __shared__ unsigned short Ws[64*LDK];
  const int z = blockIdx.z;
  const float* A = (const float*)Ap;
  const unsigned short* Ab = (const unsigned short*)Ap;
  if(QKV){
    bool isQ = (blockIdx.x < 2);
    int s = isQ ? ((z==1)?1:0) : ((z==0)?1:2);
    A += (size_t)s*NTOK*DD;
    if(!isQ){ sv = resid; bv = gptr; }
  } else if(PSEL==0){ A += z*az; Ab += z*az; }
  else if(PSEL==1){ int s = (z==1)?1:0; A += (size_t)s*NTOK*DD; Ab += (size_t)s*NTOK*DD; }
  else            { int s = (z==0)?1:2; A += (size_t)s*NTOK*DD; Ab += (size_t)s*NTOK*DD; }
  W += z*wz;
  float* C = (float*)Cp + z*cz;
  unsigned short* Cb = (unsigned short*)Cp + z*cz;
  const float* rs = resid;
  if(RSEL==0) rs += z*rz;
  else { int s = (z==1)?1:0; rs += (size_t)s*NTOK*DD; }
  sv += z*pz; bv += z*pz;
  const float* gp2 = gptr + z*gz;
  int tid  = threadIdx.x;
  int m0   = blockIdx.y*64, n0 = blockIdx.x*64;
  int w    = tid>>6, lane = tid&63;
  int wr   = (w>>1)*32, wc = (w&1)*32;
  int r    = tid>>2, seg = (tid&3)*16;
  f32x4 acc[2][2] = {};
  auto step = [&](){
#pragma unroll
    for(int kk=0;kk<64;kk+=32){
      int ko = kk + (lane>>4)*8;
      bf16x8 a0 = *reinterpret_cast<const bf16x8*>(&As[(wr    + (lane&15))*LDK + ko]);
      bf16x8 a1 = *reinterpret_cast<const bf16x8*>(&As[(wr+16 + (lane&15))*LDK + ko]);
      bf16x8 b0 = *reinterpret_cast<const bf16x8*>(&Ws[(wc    + (lane&15))*LDK + ko]);
      bf16x8 b1 = *reinterpret_cast<const bf16x8*>(&Ws[(wc+16 + (lane&15))*LDK + ko]);
      acc[0][0] = __builtin_amdgcn_mfma_f32_16x16x32_bf16(a0,b0,acc[0][0],0,0,0);
      acc[0][1] = __builtin_amdgcn_mfma_f32_16x16x32_bf16(a0,b1,acc[0][1],0,0,0);
      acc[1][0] = __builtin_amdgcn_mfma_f32_16x16x32_bf16(a1,b0,acc[1][0],0,0,0);
      acc[1][1] = __builtin_amdgcn_mfma_f32_16x16x32_bf16(a1,b1,acc[1][1],0,0,0);
    }
  };
  if(LN){
    float fr[32]; float mean, rstd;
    if(SUM){
#pragma unroll
      for(int j=0;j<32;j++) fr[j]=0.f;
#pragma unroll
      for(int s=0;s<3;s++){
        const float* r1 = A     + (size_t)s*NTOK*DD + (size_t)(m0+r)*K + seg;
        const float* r2 = resid + (size_t)s*NTOK*DD + (size_t)(m0+r)*K + seg;
#pragma unroll
        for(int j=0;j<4;j++){
          float4 v1 = *reinterpret_cast<const float4*>(r1 + j*4);
          float4 v2 = *reinterpret_cast<const float4*>(r2 + j*4);
          fr[j*4]+=v1.x+v2.x; fr[j*4+1]+=v1.y+v2.y; fr[j*4+2]+=v1.z+v2.z; fr[j*4+3]+=v1.w+v2.w;
          float4 w1 = *reinterpret_cast<const float4*>(r1 + 64 + j*4);
          float4 w2 = *reinterpret_cast<const float4*>(r2 + 64 + j*4);
          fr[16+j*4]+=w1.x+w2.x; fr[16+j*4+1]+=w1.y+w2.y; fr[16+j*4+2]+=w1.z+w2.z; fr[16+j*4+3]+=w1.w+w2.w;
        }
      }
    } else {
      const float* arow = A + (size_t)(m0+r)*K + seg;   // K==128
#pragma unroll
      for(int j=0;j<4;j++) *reinterpret_cast<float4*>(&fr[j*4])    = *reinterpret_cast<const float4*>(arow + j*4);
#pragma unroll
      for(int j=0;j<4;j++) *reinterpret_cast<float4*>(&fr[16+j*4]) = *reinterpret_cast<const float4*>(arow + 64 + j*4);
    }
    float s1=0.f, s2=0.f;
#pragma unroll
    for(int j=0;j<32;j++){ s1 += fr[j]; s2 += fr[j]*fr[j]; }
    s1 += __shfl_xor(s1,1,64); s1 += __shfl_xor(s1,2,64);
    s2 += __shfl_xor(s2,1,64); s2 += __shfl_xor(s2,2,64);
    mean = s1*(1.0f/DD);
    float var = s2*(1.0f/DD) - mean*mean;
    rstd = rsqrtf(var + 1e-5f);
#pragma unroll
    for(int kh=0; kh<2; ++kh){            // static unroll: fr index compile-time
      __syncthreads();
      stageLN(fr + kh*16, mean, rstd, sv + kh*64 + seg, bv + kh*64 + seg, &As[r*LDK + seg]);
      stage16bf(W + (size_t)(n0+r)*K + kh*64 + seg, &Ws[r*LDK + seg]);
      __syncthreads();
      step();
    }
  } else {
    for(int k0=0;k0<K;k0+=64){
      __syncthreads();
      if(ABF) stage16bf(Ab + (size_t)(m0+r)*K + k0 + seg, &As[r*LDK + seg]);
      else    stage16(A  + (size_t)(m0+r)*K + k0 + seg, &As[r*LDK + seg]);
      stage16bf(W + (size_t)(n0+r)*K + k0 + seg, &Ws[r*LDK + seg]);
      __syncthreads();
      step();
    }
  }
#pragma unroll
  for(int i=0;i<2;i++){
#pragma unroll
    for(int j=0;j<2;j++){
      int mb = m0 + wr + i*16 + (lane>>4)*4;
      int n  = n0 + wc + j*16 + (lane&15);
#pragma unroll
      for(int rg=0;rg<4;rg++){
        int m = mb + rg;
        float v = acc[i][j][rg];
        size_t o = (size_t)m*N + n;
        if(MODE==0){ if(OBF) Cb[o] = f2bf(v); else C[o] = v; }
        else if(MODE==3){ C[o] = rs[o] + v; }
        else if(MODE==5){
          float gs = (0.5f/3.0f)/(1.0f+expf(-gp2[0]));
          C[o] = gs*(rs[o]+v);
        }
      }
    }
  }
}

// ---------------- dual-W bf16 MFMA GEMM (z-batched): C(bf16) = silu(LN(A)@G^T)*(LN(A)@V^T), K==128 ----------------
__global__ __launch_bounds__(256) void gemm_dual(
    const float* __restrict__ A, const unsigned short* __restrict__ G,
    const unsigned short* __restrict__ V,
    unsigned short* __restrict__ C, int M, int N, int K,
    const float* __restrict__ sv, const float* __restrict__ bv,
    size_t az, size_t wz, size_t cz, size_t pz){
  __shared__ unsigned short As[64*LDK];
  __shared__ unsigned short Gs[64*LDK];
  __shared__ unsigned short Vs[64*LDK];
  const int z = blockIdx.z;
  A += z*az; G += z*wz; V += z*wz; C += z*cz; sv += z*pz; bv += z*pz;
  int tid  = threadIdx.x;
  int m0   = blockIdx.y*64, n0 = blockIdx.x*64;
  int w    = tid>>6, lane = tid&63;
  int wr   = (w>>1)*32, wc = (w&1)*32;
  int r    = tid>>2, seg = (tid&3)*16;
  f32x4 accg[2][2] = {};
  f32x4 accv[2][2] = {};
  float fr[32]; float mean, rstd;
  {
    const float* arow = A + (size_t)(m0+r)*K + seg;   // K==128
#pragma unroll
    for(int j=0;j<4;j++) *reinterpret_cast<float4*>(&fr[j*4])    = *reinterpret_cast<const float4*>(arow + j*4);
#pragma unroll
    for(int j=0;j<4;j++) *reinterpret_cast<float4*>(&fr[16+j*4]) = *reinterpret_cast<const float4*>(arow + 64 + j*4);
    float s1=0.f, s2=0.f;
#pragma unroll
    for(int j=0;j<32;j++){ s1 += fr[j]; s2 += fr[j]*fr[j]; }
    s1 += __shfl_xor(s1,1,64); s1 += __shfl_xor(s1,2,64);
    s2 += __shfl_xor(s2,1,64); s2 += __shfl_xor(s2,2,64);
    mean = s1*(1.0f/DD);
    float var = s2*(1.0f/DD) - mean*mean;
    rstd = rsqrtf(var + 1e-5f);
  }
#pragma unroll
  for(int kh=0; kh<2; ++kh){              // static unroll: fr index compile-time
    int k0 = kh*64;
    __syncthreads();
    stageLN(fr + kh*16, mean, rstd, sv + k0 + seg, bv + k0 + seg, &As[r*LDK + seg]);
    stage16bf(G + (size_t)(n0+r)*K + k0 + seg, &Gs[r*LDK + seg]);
    stage16bf(V + (size_t)(n0+r)*K + k0 + seg, &Vs[r*LDK + seg]);
    __syncthreads();
#pragma unroll
    for(int kk=0;kk<64;kk+=32){
      int ko = kk + (lane>>4)*8;
      bf16x8 a0 = *reinterpret_cast<const bf16x8*>(&As[(wr    + (lane&15))*LDK + ko]);
      bf16x8 a1 = *reinterpret_cast<const bf16x8*>(&As[(wr+16 + (lane&15))*LDK + ko]);
      bf16x8 g0 = *reinterpret_cast<const bf16x8*>(&Gs[(wc    + (lane&15))*LDK + ko]);
      bf16x8 g1 = *reinterpret_cast<const bf16x8*>(&Gs[(wc+16 + (lane&15))*LDK + ko]);
      bf16x8 v0 = *reinterpret_cast<const bf16x8*>(&Vs[(wc    + (lane&15))*LDK + ko]);
      bf16x8 v1 = *reinterpret_cast<const bf16x8*>(&Vs[(wc+16 + (lane&15))*LDK + ko]);
      accg[0][0] = __builtin_amdgcn_mfma_f32_16x16x32_bf16(a0,g0,accg[0][0],0,0,0);
      accg[0][1] = __builtin_amdgcn_mfma_f32_16x16x32_bf16(a0,g1,accg[0][1],0,0,0);
      accg[1][0] = __builtin_amdgcn_mfma_f32_16x16x32_bf16(a1,g0,accg[1][0],0,0,0);
      accg[1][1] = __builtin_amdgcn_mfma_f32_16x16x32_bf16(a1,g1,accg[1][1],0,0,0);
      accv[0][0] = __builtin_amdgcn_mfma_f32_16x16x32_bf16(a0,v0,accv[0][0],0,0,0);
      accv[0][1] = __builtin_amdgcn_mfma_f32_16x16x32_bf16(a0,v1,accv[0][1],0,0,0);
      accv[1][0] = __builtin_amdgcn_mfma_f32_16x16x32_bf16(a1,v0,accv[1][0],0,0,0);
      accv[1][1] = __builtin_amdgcn_mfma_f32_16x16x32_bf16(a1,v1,accv[1][1],0,0,0);
    }
  }
#pragma unroll
  for(int i=0;i<2;i++){
#pragma unroll
    for(int j=0;j<2;j++){
      int mb = m0 + wr + i*16 + (lane>>4)*4;
      int n  = n0 + wc + j*16 + (lane&15);
#pragma unroll
      for(int rg=0;rg<4;rg++){
        float gg = accg[i][j][rg];
        float vv = accv[i][j][rg];
        float sg = gg/(1.0f+expf(-gg));
        C[(size_t)(mb+rg)*N + n] = f2bf(sg*vv);
      }
    }
  }
}

// ---------------- MoE pair-combine GEMM: go[g] = c0*(A0@W0^T) + c1*(A1@W1^T), K=DFF ----------------
__global__ __launch_bounds__(256) void gemm_moe2(
    const unsigned short* __restrict__ Ab, const unsigned short* __restrict__ Wb,
    float* __restrict__ Cb, const float* __restrict__ coef){
  __shared__ unsigned short As0[64*LDK];
  __shared__ unsigned short As1[64*LDK];
  __shared__ unsigned short Ws0[64*LDK];
  __shared__ unsigned short Ws1[64*LDK];
  const int g = blockIdx.z;
  const unsigned short* A0 = Ab + (size_t)(2*g)*NTOK*DFF;
  const unsigned short* A1 = A0 + (size_t)NTOK*DFF;
  const unsigned short* W0 = Wb + (size_t)(2*g)*DD*DFF;
  const unsigned short* W1 = W0 + (size_t)DD*DFF;
  float* C = Cb + (size_t)g*NTOK*DD;
  const float* c0 = coef + (size_t)(2*g)*NTOK;
  const float* c1 = c0 + NTOK;
  int tid  = threadIdx.x;
  int m0   = blockIdx.y*64, n0 = blockIdx.x*64;
  int w    = tid>>6, lane = tid&63;
  int wr   = (w>>1)*32, wc = (w&1)*32;
  int r    = tid>>2, seg = (tid&3)*16;
  f32x4 a0acc[2][2] = {};
  f32x4 a1acc[2][2] = {};
  for(int k0=0;k0<DFF;k0+=64){
    __syncthreads();
    stage16bf(A0 + (size_t)(m0+r)*DFF + k0 + seg, &As0[r*LDK + seg]);
    stage16bf(A1 + (size_t)(m0+r)*DFF + k0 + seg, &As1[r*LDK + seg]);
    stage16bf(W0 + (size_t)(n0+r)*DFF + k0 + seg, &Ws0[r*LDK + seg]);
    stage16bf(W1 + (size_t)(n0+r)*DFF + k0 + seg, &Ws1[r*LDK + seg]);
    __syncthreads();
#pragma unroll
    for(int kk=0;kk<64;kk+=32){
      int ko = kk + (lane>>4)*8;
      bf16x8 x00 = *reinterpret_cast<const bf16x8*>(&As0[(wr    + (lane&15))*LDK + ko]);
      bf16x8 x01 = *reinterpret_cast<const bf16x8*>(&As0[(wr+16 + (lane&15))*LDK + ko]);
      bf16x8 x10 = *reinterpret_cast<const bf16x8*>(&As1[(wr    + (lane&15))*LDK + ko]);
      bf16x8 x11 = *reinterpret_cast<const bf16x8*>(&As1[(wr+16 + (lane&15))*LDK + ko]);
      bf16x8 w00 = *reinterpret_cast<const bf16x8*>(&Ws0[(wc    + (lane&15))*LDK + ko]);
      bf16x8 w01 = *reinterpret_cast<const bf16x8*>(&Ws0[(wc+16 + (lane&15))*LDK + ko]);
      bf16x8 w10 = *reinterpret_cast<const bf16x8*>(&Ws1[(wc    + (lane&15))*LDK + ko]);
      bf16x8 w11 = *reinterpret_cast<const bf16x8*>(&Ws1[(wc+16 + (lane&15))*LDK + ko]);
      a0acc[0][0] = __builtin_amdgcn_mfma_f32_16x16x32_bf16(x00,w00,a0acc[0][0],0,0,0);
      a0acc[0][1] = __builtin_amdgcn_mfma_f32_16x16x32_bf16(x00,w01,a0acc[0][1],0,0,0);
      a0acc[1][0] = __builtin_amdgcn_mfma_f32_16x16x32_bf16(x01,w00,a0acc[1][0],0,0,0);
      a0acc[1][1] = __builtin_amdgcn_mfma_f32_16x16x32_bf16(x01,w01,a0acc[1][1],0,0,0);
      a1acc[0][0] = __builtin_amdgcn_mfma_f32_16x16x32_bf16(x10,w10,a1acc[0][0],0,0,0);
      a1acc[0][1] = __builtin_amdgcn_mfma_f32_16x16x32_bf16(x10,w11,a1acc[0][1],0,0,0);
      a1acc[1][0] = __builtin_amdgcn_mfma_f32_16x16x32_bf16(x11,w10,a1acc[1][0],0,0,0);
      a1acc[1][1] = __builtin_amdgcn_mfma_f32_16x16x32_bf16(x11,w11,a1acc[1][1],0,0,0);
    }
  }
#pragma unroll
  for(int i=0;i<2;i++){
#pragma unroll
    for(int j=0;j<2;j++){
      int mb = m0 + wr + i*16 + (lane>>4)*4;
      int n  = n0 + wc + j*16 + (lane&15);
#pragma unroll
      for(int rg=0;rg<4;rg++){
        int m = mb + rg;
        C[(size_t)m*DD + n] = c0[m]*a0acc[i][j][rg] + c1[m]*a1acc[i][j][rg];
      }
    }
  }
}

// ---------------- fused MFMA flash attention: 8 waves (128 q-rows), dbuf K/V, 1 barrier/tile ----------------
// grid 768 flat, XCD-aware: residue n%8 owns 12 complete (h,b,br) groups of 8 q-blocks.
#define PSW(row) (((row)&8)<<1)              // Ps col ^= 16 when row bit3 set
#define VSW(row) ((((row)>>3)&3)<<3)         // Vt col ^= 8*((row>>3)&3)
__global__ __launch_bounds__(512) void attn_fused(
    const unsigned short* __restrict__ qkv,
    unsigned short* __restrict__ obuf){
  __shared__ __align__(16) unsigned short Ks[2][64*40];
  __shared__ __align__(16) unsigned short Vt[2][32*72];
  __shared__ __align__(16) unsigned short Vones[16*72];
  __shared__ __align__(16) unsigned short Ps[8][16*72];
  const int tid = threadIdx.x;
  const int w = tid>>6, lane = tid&63;
  const int lr = lane&15, lg = lane>>4;
  // XCD-aware decode: n%8 = residue; each residue owns 12 groups of 8 q-blocks (bijective)
  const int n_  = blockIdx.x;
  const int kx  = n_ & 7, jx = n_ >> 3;        // jx: 0..95
  const int grp = kx*12 + (jx>>3);             // 0..95
  const int bx  = jx & 7;
  const int h   = grp & 3;
  const int b   = (grp>>2) & 7;
  const int br  = grp >> 5;
  const int qtok0 = b*TT + bx*128 + w*16;
  for(int idx=tid; idx<16*72; idx+=512)
    Vones[idx] = (idx < 64) ? (unsigned short)0x3F80 : (unsigned short)0;
  const unsigned short* qp = qkv + (size_t)br*NTOK*QKVN + (size_t)(qtok0 + lr)*QKVN + h*HDD + lg*8;
  bf16x8 qa = *reinterpret_cast<const bf16x8*>(qp);
  f32x4 o0 = {}, o1 = {}, o2 = {};
  float m[4] = {-1e30f,-1e30f,-1e30f,-1e30f};
  const unsigned short* KVbase = qkv + (size_t)br*NTOK*QKVN + (size_t)(b*TT)*QKVN + DD + h*HDD;
  const int skey = tid>>3, sseg = (tid&7)*4;   // one 8B K + one 8B V load per thread

  // prologue: stage tile 0 into buffer 0
  {
    const unsigned short* s0 = KVbase + (size_t)skey*QKVN + sseg;
    uint2 kv = *reinterpret_cast<const uint2*>(s0);
    uint2 vv = *reinterpret_cast<const uint2*>(s0 + DD);
    *reinterpret_cast<uint2*>(&Ks[0][skey*40+sseg]) = kv;
    unsigned short vs[4];
    *reinterpret_cast<uint2*>(vs) = vv;
    const int kc = skey ^ VSW(sseg);
    Vt[0][(sseg  )*72+kc]=vs[0]; Vt[0][(sseg+1)*72+kc]=vs[1];
    Vt[0][(sseg+2)*72+kc]=vs[2]; Vt[0][(sseg+3)*72+kc]=vs[3];
  }
  __syncthreads();

  for(int t=0; t<16; t++){
    const int cur = t & 1;
    // issue next-tile loads early (latency hides under compute)
    uint2 kn, vn;
    if(t < 15){
      const unsigned short* s0 = KVbase + (size_t)((t+1)*64 + skey)*QKVN + sseg;
      kn = *reinterpret_cast<const uint2*>(s0);
      vn = *reinterpret_cast<const uint2*>(s0 + DD);
    }
    // QK^T
    f32x4 s[4];
#pragma unroll
    for(int f=0;f<4;f++){
      bf16x8 kb = *reinterpret_cast<const bf16x8*>(&Ks[cur][(f*16+lr)*40 + lg*8]);
      f32x4 z = {};
      s[f] = __builtin_amdgcn_mfma_f32_16x16x32_bf16(qa,kb,z,0,0,0);
    }
    // defer-max softmax
    float tmax[4]; bool need=false;
#pragma unroll
    for(int r=0;r<4;r++){
      tmax[r] = fmaxf(fmaxf(s[0][r],s[1][r]),fmaxf(s[2][r],s[3][r]));
      need = need || (tmax[r] > m[r] + 8.0f);
    }
    if(__any(need)){
#pragma unroll
      for(int r=0;r<4;r++){
        float t2 = tmax[r];
#pragma unroll
        for(int off=1;off<16;off<<=1) t2 = fmaxf(t2,__shfl_xor(t2,off,64));
        float nm = fmaxf(m[r],t2);
        float sc = __builtin_amdgcn_exp2f(m[r]-nm);
        m[r] = nm; o0[r] *= sc; o1[r] *= sc; o2[r] *= sc;
      }
    }
#pragma unroll
    for(int r=0;r<4;r++){
      const int q = lg*4+r;
      const int cw = PSW(q);
#pragma unroll
      for(int f=0;f<4;f++){
        float p = __builtin_amdgcn_exp2f(s[f][r]-m[r]);
        Ps[w][q*72 + ((f*16+lr)^cw)] = f2bf(p);
      }
    }
    // PV + row-sum
    const int pw_ = PSW(lr);
    bf16x8 pa0 = *reinterpret_cast<const bf16x8*>(&Ps[w][lr*72 + ((lg*8   )^pw_)]);
    bf16x8 pa1 = *reinterpret_cast<const bf16x8*>(&Ps[w][lr*72 + ((lg*8+32)^pw_)]);
    {
      const int r_ = lr, vw = VSW(r_);
      bf16x8 vb0 = *reinterpret_cast<const bf16x8*>(&Vt[cur][r_*72 + ((lg*8   )^vw)]);
      bf16x8 vb1 = *reinterpret_cast<const bf16x8*>(&Vt[cur][r_*72 + ((lg*8+32)^vw)]);
      o0 = __builtin_amdgcn_mfma_f32_16x16x32_bf16(pa0,vb0,o0,0,0,0);
      o0 = __builtin_amdgcn_mfma_f32_16x16x32_bf16(pa1,vb1,o0,0,0,0);
    }
    {
      const int r_ = 16+lr, vw = VSW(r_);
      bf16x8 vb0 = *reinterpret_cast<const bf16x8*>(&Vt[cur][(r_-16)*72 + ((lg*8   )^vw)+16*72]);
      bf16x8 vb1 = *reinterpret_cast<const bf16x8*>(&Vt[cur][(r_-16)*72 + ((lg*8+32)^vw)+16*72]);
      o1 = __builtin_amdgcn_mfma_f32_16x16x32_bf16(pa0,vb0,o1,0,0,0);
      o1 = __builtin_amdgcn_mfma_f32_16x16x32_bf16(pa1,vb1,o1,0,0,0);
    }
    {
      const int r_ = 32+lr, vw = VSW(r_);
      bf16x8 vb0 = *reinterpret_cast<const bf16x8*>(&Vones[lr*72 + ((lg*8   )^vw)]);
      bf16x8 vb1 = *reinterpret_cast<const bf16x8*>(&Vones[lr*72 + ((lg*8+32)^vw)]);
      o2 = __builtin_amdgcn_mfma_f32_16x16x32_bf16(pa0,vb0,o2,0,0,0);
      o2 = __builtin_amdgcn_mfma_f32_16x16x32_bf16(pa1,vb1,o2,0,0,0);
    }
    // write next tile into alternate buffer (loads completed under compute)
    if(t < 15){
      const int nb = cur ^ 1;
      *reinterpret_cast<uint2*>(&Ks[nb][skey*40+sseg]) = kn;
      unsigned short vs[4];
      *reinterpret_cast<uint2*>(vs) = vn;
      const int kc = skey ^ VSW(sseg);
      Vt[nb][(sseg  )*72+kc]=vs[0]; Vt[nb][(sseg+1)*72+kc]=vs[1];
      Vt[nb][(sseg+2)*72+kc]=vs[2]; Vt[nb][(sseg+3)*72+kc]=vs[3];
    }
    __syncthreads();
  }
#pragma unroll
  for(int r=0;r<4;r++){
    float lsr = __shfl(o2[r], lane & 48, 64);   // broadcast col-0 (row-sum)
    float inv = 1.0f/lsr;
    int row = qtok0 + lg*4 + r;
    unsigned short* orow = obuf + (size_t)br*NTOK*DD + (size_t)row*DD + h*HDD;
    orow[lr]    = f2bf(o0[r]*inv);
    orow[16+lr] = f2bf(o1[r]*inv);
  }
}

// ---------------- launch ----------------
extern "C" void kernel_launch(void* const* d_in, const int* in_sizes, int n_in,
                              void* d_out, int out_size, void* d_ws, size_t ws_size,
                              hipStream_t stream){
  (void)in_sizes; (void)n_in; (void)out_size; (void)ws_size;
  const float* x       = (const float*)d_in[0];
  const float* gr_g    = (const float*)d_in[1];
  const float* gr_b    = (const float*)d_in[2];
  const float* q6_w    = (const float*)d_in[3];
  const float* logtemp = (const float*)d_in[4];
  const float* grp_g   = (const float*)d_in[5];
  const float* grp_b   = (const float*)d_in[6];
  const float* gpw     = (const float*)d_in[7];
  const float* gpb     = (const float*)d_in[8];
  const float* me_g    = (const float*)d_in[9];
  const float* me_b    = (const float*)d_in[10];
  const float* me_gate = (const float*)d_in[11];
  const float* me_val  = (const float*)d_in[12];
  const float* me_out  = (const float*)d_in[13];
  const float* br_in   = (const float*)d_in[14];
  const float* br_outw = (const float*)d_in[15];
  const float* nq_g    = (const float*)d_in[16];
  const float* nq_b    = (const float*)d_in[17];
  const float* nkv_g   = (const float*)d_in[18];
  const float* nkv_b   = (const float*)d_in[19];
  const float* nff_g   = (const float*)d_in[20];
  const float* nff_b   = (const float*)d_in[21];
  const float* brg_w   = (const float*)d_in[22];
  const float* brv_w   = (const float*)d_in[23];
  const float* brf_w   = (const float*)d_in[24];
  const float* br_gate = (const float*)d_in[25];
  const float* on_g    = (const float*)d_in[26];
  const float* on_b    = (const float*)d_in[27];
  const float* out_w   = (const float*)d_in[28];
  float* out = (float*)d_out;
  float* ws  = (float*)d_ws;

  float* coef  = ws;                                        // 49152
  float* part  = ws + 65536;                                // 18432
  unsigned short* gvb6 = (unsigned short*)(ws + 131072);    // 6*8192*256 bf16
  float* go    = ws + 6731072;                              // 3*1048576 fp32
  unsigned short* qkv  = (unsigned short*)(ws + 9900000);   // 3*8192*384 bf16
  unsigned short* obuf = (unsigned short*)(ws + 14700000);  // 3*8192*128 bf16
  unsigned short* wbf  = (unsigned short*)(ws + 21400000);  // WB_TOT bf16 weights
  float* xb    = ws + 23000000;                             // 3*1048576 fp32
  unsigned short* gvb2 = (unsigned short*)(ws + 26200000);  // 3*8192*256 bf16
  float* bsum  = ws + 29400000;                             // 3*1048576 fp32
  float* gw    = ws + 32700000;                             // 24576

  // 1/sqrt(32) * log2(e): softmax runs in the exp2 domain (folded into Q weights)
  const float qscale = 0.17677669529663687f * 1.4426950408889634f;

  // 0. one-time weight conversion fp32 -> bf16 (qscale folded into br_in Q rows)
  wconv<<<1072,256,0,stream>>>(me_gate, me_val, me_out, br_in, br_outw,
                               brg_w, brv_w, brf_w, out_w, wbf, qscale);

  // 1. routing (fused LN) + lb
  routing_kernel<<<2048,256,0,stream>>>(x, gr_g, gr_b, q6_w, logtemp,
                                        grp_g, grp_b, gpw, gpb, gw, coef, part);
  lb_kernel<<<1,256,0,stream>>>(part, out + 1048576);

  // 2. MoE: all 6 experts in one dual dispatch; pair-combine into go (z=group)
  gemm_dual<<<dim3(4,128,6),256,0,stream>>>(x, wbf+WB_MEGATE, wbf+WB_MEVAL, gvb6,
      NTOK,DFF,DD, me_g, me_b, 0, (size_t)DFF*DD, (size_t)NTOK*DFF, DD);
  gemm_moe2<<<dim3(2,128,3),256,0,stream>>>(gvb6, wbf+WB_MEOUT, go, coef);

  // 3. bridges: fused QKV projection, attn (8-wave dbuf, XCD-swizzled), out-proj+resid, FFN, bridge-scale
  gemm_mfma<0,1,0,1,0,0,0,1><<<dim3(6,128,3),256,0,stream>>>(go, wbf+WB_BRIN, qkv,
      NTOK,QKVN,DD, nq_g, nq_b, nkv_g, nkv_b,
      0, (size_t)QKVN*DD, (size_t)NTOK*QKVN, DD, 0, 0);
  attn_fused<<<768,512,0,stream>>>(qkv, obuf);
  gemm_mfma<3,0,1,0,0,1,0,0><<<dim3(2,128,3),256,0,stream>>>(obuf, wbf+WB_BROUT, xb,
      NTOK,DD,DD, nullptr, nullptr, go, nullptr,
      (size_t)NTOK*DD, (size_t)DD*DD, (size_t)NTOK*DD, 0, 0, 0);
  gemm_dual<<<dim3(4,128,3),256,0,stream>>>(xb, wbf+WB_BRG, wbf+WB_BRV, gvb2,
      NTOK,2*DD,DD, nff_g, nff_b, (size_t)NTOK*DD, (size_t)2*DD*DD, (size_t)NTOK*2*DD, DD);
  gemm_mfma<5,0,1,0,0,0,0,0><<<dim3(2,128,3),256,0,stream>>>(gvb2, wbf+WB_BRF, bsum,
      NTOK,DD,2*DD, nullptr, nullptr, xb, br_gate,
      (size_t)NTOK*2*DD, (size_t)DD*2*DD, (size_t)NTOK*DD, 0, (size_t)NTOK*DD, 1);

  // 4. final: LN over (go0+go1+go2+bsum0+bsum1+bsum2), projection
  gemm_mfma<0,1,0,0,0,0,1,0><<<dim3(2,128,1),256,0,stream>>>(go, wbf+WB_OUTW, out,
      NTOK,DD,DD, on_g, on_b, bsum, nullptr,
      0, 0, 0, 0, 0, 0);
}

// Round 19
// 168.751 us; speedup vs baseline: 1.1805x; 1.0912x over previous
//
#include <hip/hip_runtime.h>
#include <math.h>

#define DD    128
#define DFF   256
#define NHH   4
#define HDD   32
#define BB    8
#define TT    1024
#define NTOK  (BB*TT)          // 8192
#define LDK   72               // padded LDS row stride (bf16 elements) for GEMM tiles
#define QKVN  384              // fused QKV row width

// bf16 weight workspace offsets (elements)
#define WB_MEGATE 0
#define WB_MEVAL  196608
#define WB_MEOUT  393216
#define WB_BRIN   589824
#define WB_BROUT  737280
#define WB_BRG    786432
#define WB_BRV    884736
#define WB_BRF    983040
#define WB_OUTW   1081344
#define WB_TOT    1097728

typedef __bf16 bf16x8 __attribute__((ext_vector_type(8)));
typedef float  f32x4  __attribute__((ext_vector_type(4)));

// ---------------- wave helpers (wave64) ----------------
__device__ __forceinline__ float wsum(float v){
#pragma unroll
  for(int o=32;o>0;o>>=1) v += __shfl_xor(v,o,64);
  return v;
}
__device__ __forceinline__ float wmaxr(float v){
#pragma unroll
  for(int o=32;o>0;o>>=1) v = fmaxf(v,__shfl_xor(v,o,64));
  return v;
}
__device__ __forceinline__ unsigned short f2bf(float x){
  __bf16 h = (__bf16)x;
  unsigned short u;
  __builtin_memcpy(&u, &h, 2);
  return u;
}
__device__ __forceinline__ float bf2f(unsigned short u){
  unsigned int x = ((unsigned int)u)<<16;
  float f; __builtin_memcpy(&f, &x, 4); return f;
}

// stage 16 consecutive fp32 (global) -> 16 bf16 in LDS
__device__ __forceinline__ void stage16(const float* __restrict__ gp,
                                        unsigned short* __restrict__ dst){
  float4 f0 = *reinterpret_cast<const float4*>(gp);
  float4 f1 = *reinterpret_cast<const float4*>(gp+4);
  float4 f2 = *reinterpret_cast<const float4*>(gp+8);
  float4 f3 = *reinterpret_cast<const float4*>(gp+12);
  float f[16] = {f0.x,f0.y,f0.z,f0.w, f1.x,f1.y,f1.z,f1.w,
                 f2.x,f2.y,f2.z,f2.w, f3.x,f3.y,f3.z,f3.w};
  unsigned short h[16];
#pragma unroll
  for(int j=0;j<16;j++) h[j] = f2bf(f[j]);
  *reinterpret_cast<uint4*>(dst)   = *reinterpret_cast<const uint4*>(h);
  *reinterpret_cast<uint4*>(dst+8) = *reinterpret_cast<const uint4*>(h+8);
}

// stage 16 consecutive bf16 (global) -> LDS (pure copy, 2x16B)
__device__ __forceinline__ void stage16bf(const unsigned short* __restrict__ gp,
                                          unsigned short* __restrict__ dst){
  const uint4* s = reinterpret_cast<const uint4*>(gp);
  *reinterpret_cast<uint4*>(dst)   = s[0];
  *reinterpret_cast<uint4*>(dst+8) = s[1];
}

// stage 16 fp32 from registers with LN affine -> LDS bf16 (fr base must be compile-time)
__device__ __forceinline__ void stageLN(const float* __restrict__ fr,
                                        float mean, float rstd,
                                        const float* __restrict__ g,
                                        const float* __restrict__ b,
                                        unsigned short* __restrict__ dst){
  unsigned short h[16];
#pragma unroll
  for(int j=0;j<16;j++){
    float y = (fr[j]-mean)*rstd*g[j] + b[j];
    h[j] = f2bf(y);
  }
  *reinterpret_cast<uint4*>(dst)   = *reinterpret_cast<const uint4*>(h);
  *reinterpret_cast<uint4*>(dst+8) = *reinterpret_cast<const uint4*>(h+8);
}

// ---------------- one-time weight fp32->bf16 conversion (qscale folded into br_in Q rows) ----------------
__global__ __launch_bounds__(256) void wconv(
    const float* __restrict__ a0, const float* __restrict__ a1, const float* __restrict__ a2,
    const float* __restrict__ a3, const float* __restrict__ a4, const float* __restrict__ a5,
    const float* __restrict__ a6, const float* __restrict__ a7, const float* __restrict__ a8,
    unsigned short* __restrict__ dst, float qsc){
  size_t i = ((size_t)blockIdx.x*256 + threadIdx.x)*4;
  if(i >= WB_TOT) return;
  const float* s; size_t off = i; float sc = 1.0f;
  if(i < WB_MEVAL){ s=a0; }
  else if(i < WB_MEOUT){ s=a1; off = i-WB_MEVAL; }
  else if(i < WB_BRIN ){ s=a2; off = i-WB_MEOUT; }
  else if(i < WB_BROUT){ s=a3; off = i-WB_BRIN;
    int row = (int)(off>>7); if((row % 384) < 128) sc = qsc; }
  else if(i < WB_BRG ){ s=a4; off = i-WB_BROUT; }
  else if(i < WB_BRV ){ s=a5; off = i-WB_BRG; }
  else if(i < WB_BRF ){ s=a6; off = i-WB_BRV; }
  else if(i < WB_OUTW){ s=a7; off = i-WB_BRF; }
  else { s=a8; off = i-WB_OUTW; }
  float4 v = *reinterpret_cast<const float4*>(s + off);
  unsigned short h4[4] = {f2bf(v.x*sc), f2bf(v.y*sc), f2bf(v.z*sc), f2bf(v.w*sc)};
  *reinterpret_cast<uint2*>(dst + i) = *reinterpret_cast<const uint2*>(h4);
}

// ---------------- routing: one wave per token (LN fused) ----------------
__global__ __launch_bounds__(256) void routing_kernel(
    const float* __restrict__ x,
    const float* __restrict__ gr_g, const float* __restrict__ gr_b,
    const float* __restrict__ q6,   const float* __restrict__ logtemp,
    const float* __restrict__ grp_g,const float* __restrict__ grp_b,
    const float* __restrict__ gpw,  const float* __restrict__ gpb,
    float* __restrict__ gw_out, float* __restrict__ coef, float* __restrict__ part){
  __shared__ float sp[4][9];
  int lane = threadIdx.x & 63;
  int wv   = threadIdx.x >> 6;
  int t    = (blockIdx.x<<2) + wv;
  const float* xr = x + (size_t)t*DD;
  float r0 = xr[lane], r1 = xr[lane+64];
  float mn = wsum(r0+r1) * (1.0f/DD);
  float d0 = r0-mn, d1 = r1-mn;
  float vv = wsum(d0*d0 + d1*d1) * (1.0f/DD);
  float rstd = rsqrtf(vv + 1e-5f);
  float x0 = d0*rstd, x1 = d1*rstd;
  float h0 = x0*gr_g[lane]+gr_b[lane];
  float h1 = x1*gr_g[lane+64]+gr_b[lane+64];
  float sb[6];
#pragma unroll
  for(int j=0;j<6;j++){
    float p = h0*q6[j*DD+lane] + h1*q6[j*DD+lane+64];
    sb[j] = tanhf(wsum(p));
  }
  float sim = 0.f;
#pragma unroll
  for(int j=0;j<6;j++) sim += ((lane>>(5-j))&1) ? sb[j] : -sb[j];
  float temp = expf(logtemp[0]); temp = fminf(fmaxf(temp,0.1f),5.0f);
  float mx = wmaxr(sim);
  float p  = expf((sim-mx)/temp);
  float w  = p / wsum(p);
  float sh[6];
#pragma unroll
  for(int j=0;j<6;j++) sh[j] = wsum(((lane>>(5-j))&1) ? w : -w);
  const float A0[6]={0,1,1,0,1,1}, A1[6]={0,-1,0,1,0,0}, A2[6]={-1,0,-1,-1,0,-1};
  float l0=0,l1=0,l2=0;
#pragma unroll
  for(int j=0;j<6;j++){ l0+=sh[j]*A0[j]; l1+=sh[j]*A1[j]; l2+=sh[j]*A2[j]; }
  float m3 = fmaxf(l0,fmaxf(l1,l2));
  float e0=expf(l0-m3), e1=expf(l1-m3), e2=expf(l2-m3);
  float inv3 = 1.0f/(e0+e1+e2);
  float g0=e0*inv3, g1=e1*inv3, g2=e2*inv3;
  if(lane==0){ gw_out[t*3]=g0; gw_out[t*3+1]=g1; gw_out[t*3+2]=g2; }
  float gwv[3]={g0,g1,g2};
  float pw[6];
#pragma unroll
  for(int g=0; g<3; g++){
    float hg0 = x0*grp_g[g*DD+lane]    + grp_b[g*DD+lane];
    float hg1 = x1*grp_g[g*DD+lane+64] + grp_b[g*DD+lane+64];
    float q0 = wsum(hg0*gpw[(g*2+0)*DD+lane] + hg1*gpw[(g*2+0)*DD+lane+64]) + gpb[g*2+0];
    float q1 = wsum(hg0*gpw[(g*2+1)*DD+lane] + hg1*gpw[(g*2+1)*DD+lane+64]) + gpb[g*2+1];
    float mm = fmaxf(q0,q1);
    float a0 = expf(q0-mm), a1 = expf(q1-mm);
    float inv = 1.0f/(a0+a1);
    float w0 = a0*inv, w1 = a1*inv;
    pw[g*2]=w0; pw[g*2+1]=w1;
    float invs = 1.0f/(w0+w1+1e-8f);
    if(lane==0){
      coef[(size_t)(2*g  )*NTOK + t] = gwv[g]*w0*invs;
      coef[(size_t)(2*g+1)*NTOK + t] = gwv[g]*w1*invs;
    }
  }
  if(lane==0){
    sp[wv][0]=g0; sp[wv][1]=g1; sp[wv][2]=g2;
#pragma unroll
    for(int k=0;k<6;k++) sp[wv][3+k]=pw[k];
  }
  __syncthreads();
  if(threadIdx.x<9){
    part[blockIdx.x*9+threadIdx.x] =
      sp[0][threadIdx.x]+sp[1][threadIdx.x]+sp[2][threadIdx.x]+sp[3][threadIdx.x];
  }
}

// ---------------- load-balance loss reduce (deterministic, parallel) ----------------
__global__ __launch_bounds__(256) void lb_kernel(const float* __restrict__ part, float* __restrict__ outlb){
  __shared__ float sm[4][9];
  float acc[9] = {};
  for(int i=threadIdx.x; i<2048; i+=256){
#pragma unroll
    for(int c=0;c<9;c++) acc[c] += part[i*9+c];
  }
#pragma unroll
  for(int c=0;c<9;c++) acc[c] = wsum(acc[c]);
  int wv = threadIdx.x>>6, lane = threadIdx.x&63;
  if(lane==0){
#pragma unroll
    for(int c=0;c<9;c++) sm[wv][c]=acc[c];
  }
  __syncthreads();
  if(threadIdx.x==0){
    const float invN = 1.0f/(float)NTOK;
    float lb=0;
#pragma unroll
    for(int c=0;c<9;c++){
      float s = sm[0][c]+sm[1][c]+sm[2][c]+sm[3][c];
      float mw = s*invN;
      lb -= mw*logf(mw+1e-8f);
    }
    outlb[0] = lb*0.01f;
  }
}

// ---------------- bf16 MFMA GEMM (z-batched): C = epi(LN?(A) @ W^T), W pre-converted bf16 ----------------
// MODE 0: store  3: resid+acc  5: in-place C += BW*sigmoid(gptr[0])*(resid+acc)  (bf16 r-m-w)
// LN=1: K==128, LN fused (A fp32 unless ABF). SUM=1 (with LN+ABF): A-row = sum of 3 bf16 go rows.
// ABF=1: A bf16. RBF=1: resid bf16. OBF=1: C bf16.
// PSEL/RSEL: 0 = z*stride, 1 = pairsA[z]. QKV=1: blockIdx.x<2 -> Q else KV.
template<int MODE,int LN,int ABF,int OBF,int PSEL,int RSEL,int SUM,int QKV,int RBF>
__global__ __launch_bounds__(256) void gemm_mfma(
    const void* __restrict__ Ap, const unsigned short* __restrict__ W, void* __restrict__ Cp,
    int M, int N, int K,
    const float* __restrict__ sv, const float* __restrict__ bv,
    const void* __restrict__ resid, const float* __restrict__ gptr,
    size_t az, size_t wz, size_t cz, size_t pz, size_t rz, size_t gz){
  __shared__ unsigned short As[64*LDK];
  __shared__ unsigned short Ws[64*LDK];
  const int z = blockIdx.z;
  const float* A = (const float*)Ap;
  const unsigned short* Ab = (const unsigned short*)Ap;
  if(QKV){
    bool isQ = (blockIdx.x < 2);
    int s = isQ ? ((z==1)?1:0) : ((z==0)?1:2);
    A  += (size_t)s*NTOK*DD;
    Ab += (size_t)s*NTOK*DD;
    if(!isQ){ sv = (const float*)resid; bv = gptr; }
  } else if(PSEL==0){ A += z*az; Ab += z*az; }
  else { int s = (z==1)?1:0; A += (size_t)s*NTOK*DD; Ab += (size_t)s*NTOK*DD; }
  W += z*wz;
  float* C = (float*)Cp + z*cz;
  unsigned short* Cb = (unsigned short*)Cp + z*cz;
  const float* rsf = (const float*)resid;
  const unsigned short* rsb = (const unsigned short*)resid;
  if(RSEL==0){ rsf += z*rz; rsb += z*rz; }
  else { int s = (z==1)?1:0; rsf += (size_t)s*NTOK*DD; rsb += (size_t)s*NTOK*DD; }
  sv += z*pz; bv += z*pz;
  const float* gp2 = gptr + z*gz;
  int tid  = threadIdx.x;
  int m0   = blockIdx.y*64, n0 = blockIdx.x*64;
  int w    = tid>>6, lane = tid&63;
  int wr   = (w>>1)*32, wc = (w&1)*32;
  int r    = tid>>2, seg = (tid&3)*16;
  f32x4 acc[2][2] = {};
  auto step = [&](){
#pragma unroll
    for(int kk=0;kk<64;kk+=32){
      int ko = kk + (lane>>4)*8;
      bf16x8 a0 = *reinterpret_cast<const bf16x8*>(&As[(wr    + (lane&15))*LDK + ko]);
      bf16x8 a1 = *reinterpret_cast<const bf16x8*>(&As[(wr+16 + (lane&15))*LDK + ko]);
      bf16x8 b0 = *reinterpret_cast<const bf16x8*>(&Ws[(wc    + (lane&15))*LDK + ko]);
      bf16x8 b1 = *reinterpret_cast<const bf16x8*>(&Ws[(wc+16 + (lane&15))*LDK + ko]);
      acc[0][0] = __builtin_amdgcn_mfma_f32_16x16x32_bf16(a0,b0,acc[0][0],0,0,0);
      acc[0][1] = __builtin_amdgcn_mfma_f32_16x16x32_bf16(a0,b1,acc[0][1],0,0,0);
      acc[1][0] = __builtin_amdgcn_mfma_f32_16x16x32_bf16(a1,b0,acc[1][0],0,0,0);
      acc[1][1] = __builtin_amdgcn_mfma_f32_16x16x32_bf16(a1,b1,acc[1][1],0,0,0);
    }
  };
  if(LN){
    float fr[32]; float mean, rstd;
    if(SUM){
#pragma unroll
      for(int j=0;j<32;j++) fr[j]=0.f;
#pragma unroll
      for(int s=0;s<3;s++){
        const unsigned short* r1 = Ab + (size_t)s*NTOK*DD + (size_t)(m0+r)*K + seg;
#pragma unroll
        for(int j=0;j<16;j++){ fr[j] += bf2f(r1[j]); fr[16+j] += bf2f(r1[64+j]); }
      }
    } else if(ABF){
      const unsigned short* arow = Ab + (size_t)(m0+r)*K + seg;   // K==128
#pragma unroll
      for(int j=0;j<16;j++){ fr[j] = bf2f(arow[j]); fr[16+j] = bf2f(arow[64+j]); }
    } else {
      const float* arow = A + (size_t)(m0+r)*K + seg;   // K==128
#pragma unroll
      for(int j=0;j<4;j++) *reinterpret_cast<float4*>(&fr[j*4])    = *reinterpret_cast<const float4*>(arow + j*4);
#pragma unroll
      for(int j=0;j<4;j++) *reinterpret_cast<float4*>(&fr[16+j*4]) = *reinterpret_cast<const float4*>(arow + 64 + j*4);
    }
    float s1=0.f, s2=0.f;
#pragma unroll
    for(int j=0;j<32;j++){ s1 += fr[j]; s2 += fr[j]*fr[j]; }
    s1 += __shfl_xor(s1,1,64); s1 += __shfl_xor(s1,2,64);
    s2 += __shfl_xor(s2,1,64); s2 += __shfl_xor(s2,2,64);
    mean = s1*(1.0f/DD);
    float var = s2*(1.0f/DD) - mean*mean;
    rstd = rsqrtf(var + 1e-5f);
#pragma unroll
    for(int kh=0; kh<2; ++kh){            // static unroll: fr index compile-time
      __syncthreads();
      stageLN(fr + kh*16, mean, rstd, sv + kh*64 + seg, bv + kh*64 + seg, &As[r*LDK + seg]);
      stage16bf(W + (size_t)(n0+r)*K + kh*64 + seg, &Ws[r*LDK + seg]);
      __syncthreads();
      step();
    }
  } else {
    for(int k0=0;k0<K;k0+=64){
      __syncthreads();
      if(ABF) stage16bf(Ab + (size_t)(m0+r)*K + k0 + seg, &As[r*LDK + seg]);
      else    stage16(A  + (size_t)(m0+r)*K + k0 + seg, &As[r*LDK + seg]);
      stage16bf(W + (size_t)(n0+r)*K + k0 + seg, &Ws[r*LDK + seg]);
      __syncthreads();
      step();
    }
  }
#pragma unroll
  for(int i=0;i<2;i++){
#pragma unroll
    for(int j=0;j<2;j++){
      int mb = m0 + wr + i*16 + (lane>>4)*4;
      int n  = n0 + wc + j*16 + (lane&15);
#pragma unroll
      for(int rg=0;rg<4;rg++){
        int m = mb + rg;
        float v = acc[i][j][rg];
        size_t o = (size_t)m*N + n;
        if(MODE==0){ if(OBF) Cb[o] = f2bf(v); else C[o] = v; }
        else if(MODE==3){
          float rv = RBF ? bf2f(rsb[o]) : rsf[o];
          float res = rv + v;
          if(OBF) Cb[o] = f2bf(res); else C[o] = res;
        }
        else if(MODE==5){
          float gs = (0.5f/3.0f)/(1.0f+expf(-gp2[0]));
          float rv = RBF ? bf2f(rsb[o]) : rsf[o];
          if(OBF) Cb[o] = f2bf(bf2f(Cb[o]) + gs*(rv+v));
          else    C[o] += gs*(rv+v);
        }
      }
    }
  }
}

// ---------------- dual-W bf16 MFMA GEMM (z-batched): C(bf16) = silu(LN(A)@G^T)*(LN(A)@V^T), K==128 ----------------
template<int ABF>
__global__ __launch_bounds__(256) void gemm_dual(
    const void* __restrict__ Ap, const unsigned short* __restrict__ G,
    const unsigned short* __restrict__ V,
    unsigned short* __restrict__ C, int M, int N, int K,
    const float* __restrict__ sv, const float* __restrict__ bv,
    size_t az, size_t wz, size_t cz, size_t pz){
  __shared__ unsigned short As[64*LDK];
  __shared__ unsigned short Gs[64*LDK];
  __shared__ unsigned short Vs[64*LDK];
  const int z = blockIdx.z;
  const float* A = (const float*)Ap + z*az;
  const unsigned short* Ab = (const unsigned short*)Ap + z*az;
  G += z*wz; V += z*wz; C += z*cz; sv += z*pz; bv += z*pz;
  int tid  = threadIdx.x;
  int m0   = blockIdx.y*64, n0 = blockIdx.x*64;
  int w    = tid>>6, lane = tid&63;
  int wr   = (w>>1)*32, wc = (w&1)*32;
  int r    = tid>>2, seg = (tid&3)*16;
  f32x4 accg[2][2] = {};
  f32x4 accv[2][2] = {};
  float fr[32]; float mean, rstd;
  if(ABF){
    const unsigned short* arow = Ab + (size_t)(m0+r)*K + seg;   // K==128
#pragma unroll
    for(int j=0;j<16;j++){ fr[j] = bf2f(arow[j]); fr[16+j] = bf2f(arow[64+j]); }
  } else {
    const float* arow = A + (size_t)(m0+r)*K + seg;   // K==128
#pragma unroll
    for(int j=0;j<4;j++) *reinterpret_cast<float4*>(&fr[j*4])    = *reinterpret_cast<const float4*>(arow + j*4);
#pragma unroll
    for(int j=0;j<4;j++) *reinterpret_cast<float4*>(&fr[16+j*4]) = *reinterpret_cast<const float4*>(arow + 64 + j*4);
  }
  {
    float s1=0.f, s2=0.f;
#pragma unroll
    for(int j=0;j<32;j++){ s1 += fr[j]; s2 += fr[j]*fr[j]; }
    s1 += __shfl_xor(s1,1,64); s1 += __shfl_xor(s1,2,64);
    s2 += __shfl_xor(s2,1,64); s2 += __shfl_xor(s2,2,64);
    mean = s1*(1.0f/DD);
    float var = s2*(1.0f/DD) - mean*mean;
    rstd = rsqrtf(var + 1e-5f);
  }
#pragma unroll
  for(int kh=0; kh<2; ++kh){              // static unroll: fr index compile-time
    int k0 = kh*64;
    __syncthreads();
    stageLN(fr + kh*16, mean, rstd, sv + k0 + seg, bv + k0 + seg, &As[r*LDK + seg]);
    stage16bf(G + (size_t)(n0+r)*K + k0 + seg, &Gs[r*LDK + seg]);
    stage16bf(V + (size_t)(n0+r)*K + k0 + seg, &Vs[r*LDK + seg]);
    __syncthreads();
#pragma unroll
    for(int kk=0;kk<64;kk+=32){
      int ko = kk + (lane>>4)*8;
      bf16x8 a0 = *reinterpret_cast<const bf16x8*>(&As[(wr    + (lane&15))*LDK + ko]);
      bf16x8 a1 = *reinterpret_cast<const bf16x8*>(&As[(wr+16 + (lane&15))*LDK + ko]);
      bf16x8 g0 = *reinterpret_cast<const bf16x8*>(&Gs[(wc    + (lane&15))*LDK + ko]);
      bf16x8 g1 = *reinterpret_cast<const bf16x8*>(&Gs[(wc+16 + (lane&15))*LDK + ko]);
      bf16x8 v0 = *reinterpret_cast<const bf16x8*>(&Vs[(wc    + (lane&15))*LDK + ko]);
      bf16x8 v1 = *reinterpret_cast<const bf16x8*>(&Vs[(wc+16 + (lane&15))*LDK + ko]);
      accg[0][0] = __builtin_amdgcn_mfma_f32_16x16x32_bf16(a0,g0,accg[0][0],0,0,0);
      accg[0][1] = __builtin_amdgcn_mfma_f32_16x16x32_bf16(a0,g1,accg[0][1],0,0,0);
      accg[1][0] = __builtin_amdgcn_mfma_f32_16x16x32_bf16(a1,g0,accg[1][0],0,0,0);
      accg[1][1] = __builtin_amdgcn_mfma_f32_16x16x32_bf16(a1,g1,accg[1][1],0,0,0);
      accv[0][0] = __builtin_amdgcn_mfma_f32_16x16x32_bf16(a0,v0,accv[0][0],0,0,0);
      accv[0][1] = __builtin_amdgcn_mfma_f32_16x16x32_bf16(a0,v1,accv[0][1],0,0,0);
      accv[1][0] = __builtin_amdgcn_mfma_f32_16x16x32_bf16(a1,v0,accv[1][0],0,0,0);
      accv[1][1] = __builtin_amdgcn_mfma_f32_16x16x32_bf16(a1,v1,accv[1][1],0,0,0);
    }
  }
#pragma unroll
  for(int i=0;i<2;i++){
#pragma unroll
    for(int j=0;j<2;j++){
      int mb = m0 + wr + i*16 + (lane>>4)*4;
      int n  = n0 + wc + j*16 + (lane&15);
#pragma unroll
      for(int rg=0;rg<4;rg++){
        float gg = accg[i][j][rg];
        float vv = accv[i][j][rg];
        float sg = gg/(1.0f+expf(-gg));
        C[(size_t)(mb+rg)*N + n] = f2bf(sg*vv);
      }
    }
  }
}

// ---------------- MoE pair-combine GEMM: go[g](bf16) = c0*(A0@W0^T) + c1*(A1@W1^T), K=DFF ----------------
__global__ __launch_bounds__(256) void gemm_moe2(
    const unsigned short* __restrict__ Ab, const unsigned short* __restrict__ Wb,
    unsigned short* __restrict__ Cb, const float* __restrict__ coef){
  __shared__ unsigned short As0[64*LDK];
  __shared__ unsigned short As1[64*LDK];
  __shared__ unsigned short Ws0[64*LDK];
  __shared__ unsigned short Ws1[64*LDK];
  const int g = blockIdx.z;
  const unsigned short* A0 = Ab + (size_t)(2*g)*NTOK*DFF;
  const unsigned short* A1 = A0 + (size_t)NTOK*DFF;
  const unsigned short* W0 = Wb + (size_t)(2*g)*DD*DFF;
  const unsigned short* W1 = W0 + (size_t)DD*DFF;
  unsigned short* C = Cb + (size_t)g*NTOK*DD;
  const float* c0 = coef + (size_t)(2*g)*NTOK;
  const float* c1 = c0 + NTOK;
  int tid  = threadIdx.x;
  int m0   = blockIdx.y*64, n0 = blockIdx.x*64;
  int w    = tid>>6, lane = tid&63;
  int wr   = (w>>1)*32, wc = (w&1)*32;
  int r    = tid>>2, seg = (tid&3)*16;
  f32x4 a0acc[2][2] = {};
  f32x4 a1acc[2][2] = {};
  for(int k0=0;k0<DFF;k0+=64){
    __syncthreads();
    stage16bf(A0 + (size_t)(m0+r)*DFF + k0 + seg, &As0[r*LDK + seg]);
    stage16bf(A1 + (size_t)(m0+r)*DFF + k0 + seg, &As1[r*LDK + seg]);
    stage16bf(W0 + (size_t)(n0+r)*DFF + k0 + seg, &Ws0[r*LDK + seg]);
    stage16bf(W1 + (size_t)(n0+r)*DFF + k0 + seg, &Ws1[r*LDK + seg]);
    __syncthreads();
#pragma unroll
    for(int kk=0;kk<64;kk+=32){
      int ko = kk + (lane>>4)*8;
      bf16x8 x00 = *reinterpret_cast<const bf16x8*>(&As0[(wr    + (lane&15))*LDK + ko]);
      bf16x8 x01 = *reinterpret_cast<const bf16x8*>(&As0[(wr+16 + (lane&15))*LDK + ko]);
      bf16x8 x10 = *reinterpret_cast<const bf16x8*>(&As1[(wr    + (lane&15))*LDK + ko]);
      bf16x8 x11 = *reinterpret_cast<const bf16x8*>(&As1[(wr+16 + (lane&15))*LDK + ko]);
      bf16x8 w00 = *reinterpret_cast<const bf16x8*>(&Ws0[(wc    + (lane&15))*LDK + ko]);
      bf16x8 w01 = *reinterpret_cast<const bf16x8*>(&Ws0[(wc+16 + (lane&15))*LDK + ko]);
      bf16x8 w10 = *reinterpret_cast<const bf16x8*>(&Ws1[(wc    + (lane&15))*LDK + ko]);
      bf16x8 w11 = *reinterpret_cast<const bf16x8*>(&Ws1[(wc+16 + (lane&15))*LDK + ko]);
      a0acc[0][0] = __builtin_amdgcn_mfma_f32_16x16x32_bf16(x00,w00,a0acc[0][0],0,0,0);
      a0acc[0][1] = __builtin_amdgcn_mfma_f32_16x16x32_bf16(x00,w01,a0acc[0][1],0,0,0);
      a0acc[1][0] = __builtin_amdgcn_mfma_f32_16x16x32_bf16(x01,w00,a0acc[1][0],0,0,0);
      a0acc[1][1] = __builtin_amdgcn_mfma_f32_16x16x32_bf16(x01,w01,a0acc[1][1],0,0,0);
      a1acc[0][0] = __builtin_amdgcn_mfma_f32_16x16x32_bf16(x10,w10,a1acc[0][0],0,0,0);
      a1acc[0][1] = __builtin_amdgcn_mfma_f32_16x16x32_bf16(x10,w11,a1acc[0][1],0,0,0);
      a1acc[1][0] = __builtin_amdgcn_mfma_f32_16x16x32_bf16(x11,w10,a1acc[1][0],0,0,0);
      a1acc[1][1] = __builtin_amdgcn_mfma_f32_16x16x32_bf16(x11,w11,a1acc[1][1],0,0,0);
    }
  }
#pragma unroll
  for(int i=0;i<2;i++){
#pragma unroll
    for(int j=0;j<2;j++){
      int mb = m0 + wr + i*16 + (lane>>4)*4;
      int n  = n0 + wc + j*16 + (lane&15);
#pragma unroll
      for(int rg=0;rg<4;rg++){
        int m = mb + rg;
        C[(size_t)m*DD + n] = f2bf(c0[m]*a0acc[i][j][rg] + c1[m]*a1acc[i][j][rg]);
      }
    }
  }
}

// ---------------- fused MFMA flash attention: 8 waves (128 q-rows), dbuf K/V, 1 barrier/tile ----------------
// grid 768 flat, XCD-aware: residue n%8 owns 12 complete (h,b,br) groups of 8 q-blocks.
#define PSW(row) (((row)&8)<<1)              // Ps col ^= 16 when row bit3 set
#define VSW(row) ((((row)>>3)&3)<<3)         // Vt col ^= 8*((row>>3)&3)
__global__ __launch_bounds__(512) void attn_fused(
    const unsigned short* __restrict__ qkv,
    unsigned short* __restrict__ obuf){
  __shared__ __align__(16) unsigned short Ks[2][64*40];
  __shared__ __align__(16) unsigned short Vt[2][32*72];
  __shared__ __align__(16) unsigned short Vones[16*72];
  __shared__ __align__(16) unsigned short Ps[8][16*72];
  const int tid = threadIdx.x;
  const int w = tid>>6, lane = tid&63;
  const int lr = lane&15, lg = lane>>4;
  // XCD-aware decode: n%8 = residue; each residue owns 12 groups of 8 q-blocks (bijective)
  const int n_  = blockIdx.x;
  const int kx  = n_ & 7, jx = n_ >> 3;        // jx: 0..95
  const int grp = kx*12 + (jx>>3);             // 0..95
  const int bx  = jx & 7;
  const int h   = grp & 3;
  const int b   = (grp>>2) & 7;
  const int br  = grp >> 5;
  const int qtok0 = b*TT + bx*128 + w*16;
  for(int idx=tid; idx<16*72; idx+=512)
    Vones[idx] = (idx < 64) ? (unsigned short)0x3F80 : (unsigned short)0;
  const unsigned short* qp = qkv + (size_t)br*NTOK*QKVN + (size_t)(qtok0 + lr)*QKVN + h*HDD + lg*8;
  bf16x8 qa = *reinterpret_cast<const bf16x8*>(qp);
  f32x4 o0 = {}, o1 = {}, o2 = {};
  float m[4] = {-1e30f,-1e30f,-1e30f,-1e30f};
  const unsigned short* KVbase = qkv + (size_t)br*NTOK*QKVN + (size_t)(b*TT)*QKVN + DD + h*HDD;
  const int skey = tid>>3, sseg = (tid&7)*4;   // one 8B K + one 8B V load per thread

  // prologue: stage tile 0 into buffer 0
  {
    const unsigned short* s0 = KVbase + (size_t)skey*QKVN + sseg;
    uint2 kv = *reinterpret_cast<const uint2*>(s0);
    uint2 vv = *reinterpret_cast<const uint2*>(s0 + DD);
    *reinterpret_cast<uint2*>(&Ks[0][skey*40+sseg]) = kv;
    unsigned short vs[4];
    *reinterpret_cast<uint2*>(vs) = vv;
    const int kc = skey ^ VSW(sseg);
    Vt[0][(sseg  )*72+kc]=vs[0]; Vt[0][(sseg+1)*72+kc]=vs[1];
    Vt[0][(sseg+2)*72+kc]=vs[2]; Vt[0][(sseg+3)*72+kc]=vs[3];
  }
  __syncthreads();

  for(int t=0; t<16; t++){
    const int cur = t & 1;
    // issue next-tile loads early (latency hides under compute)
    uint2 kn, vn;
    if(t < 15){
      const unsigned short* s0 = KVbase + (size_t)((t+1)*64 + skey)*QKVN + sseg;
      kn = *reinterpret_cast<const uint2*>(s0);
      vn = *reinterpret_cast<const uint2*>(s0 + DD);
    }
    // QK^T
    f32x4 s[4];
#pragma unroll
    for(int f=0;f<4;f++){
      bf16x8 kb = *reinterpret_cast<const bf16x8*>(&Ks[cur][(f*16+lr)*40 + lg*8]);
      f32x4 z = {};
      s[f] = __builtin_amdgcn_mfma_f32_16x16x32_bf16(qa,kb,z,0,0,0);
    }
    // defer-max softmax
    float tmax[4]; bool need=false;
#pragma unroll
    for(int r=0;r<4;r++){
      tmax[r] = fmaxf(fmaxf(s[0][r],s[1][r]),fmaxf(s[2][r],s[3][r]));
      need = need || (tmax[r] > m[r] + 8.0f);
    }
    if(__any(need)){
#pragma unroll
      for(int r=0;r<4;r++){
        float t2 = tmax[r];
#pragma unroll
        for(int off=1;off<16;off<<=1) t2 = fmaxf(t2,__shfl_xor(t2,off,64));
        float nm = fmaxf(m[r],t2);
        float sc = __builtin_amdgcn_exp2f(m[r]-nm);
        m[r] = nm; o0[r] *= sc; o1[r] *= sc; o2[r] *= sc;
      }
    }
#pragma unroll
    for(int r=0;r<4;r++){
      const int q = lg*4+r;
      const int cw = PSW(q);
#pragma unroll
      for(int f=0;f<4;f++){
        float p = __builtin_amdgcn_exp2f(s[f][r]-m[r]);
        Ps[w][q*72 + ((f*16+lr)^cw)] = f2bf(p);
      }
    }
    // PV + row-sum
    const int pw_ = PSW(lr);
    bf16x8 pa0 = *reinterpret_cast<const bf16x8*>(&Ps[w][lr*72 + ((lg*8   )^pw_)]);
    bf16x8 pa1 = *reinterpret_cast<const bf16x8*>(&Ps[w][lr*72 + ((lg*8+32)^pw_)]);
    {
      const int r_ = lr, vw = VSW(r_);
      bf16x8 vb0 = *reinterpret_cast<const bf16x8*>(&Vt[cur][r_*72 + ((lg*8   )^vw)]);
      bf16x8 vb1 = *reinterpret_cast<const bf16x8*>(&Vt[cur][r_*72 + ((lg*8+32)^vw)]);
      o0 = __builtin_amdgcn_mfma_f32_16x16x32_bf16(pa0,vb0,o0,0,0,0);
      o0 = __builtin_amdgcn_mfma_f32_16x16x32_bf16(pa1,vb1,o0,0,0,0);
    }
    {
      const int r_ = 16+lr, vw = VSW(r_);
      bf16x8 vb0 = *reinterpret_cast<const bf16x8*>(&Vt[cur][(r_-16)*72 + ((lg*8   )^vw)+16*72]);
      bf16x8 vb1 = *reinterpret_cast<const bf16x8*>(&Vt[cur][(r_-16)*72 + ((lg*8+32)^vw)+16*72]);
      o1 = __builtin_amdgcn_mfma_f32_16x16x32_bf16(pa0,vb0,o1,0,0,0);
      o1 = __builtin_amdgcn_mfma_f32_16x16x32_bf16(pa1,vb1,o1,0,0,0);
    }
    {
      const int r_ = 32+lr, vw = VSW(r_);
      bf16x8 vb0 = *reinterpret_cast<const bf16x8*>(&Vones[lr*72 + ((lg*8   )^vw)]);
      bf16x8 vb1 = *reinterpret_cast<const bf16x8*>(&Vones[lr*72 + ((lg*8+32)^vw)]);
      o2 = __builtin_amdgcn_mfma_f32_16x16x32_bf16(pa0,vb0,o2,0,0,0);
      o2 = __builtin_amdgcn_mfma_f32_16x16x32_bf16(pa1,vb1,o2,0,0,0);
    }
    // write next tile into alternate buffer (loads completed under compute)
    if(t < 15){
      const int nb = cur ^ 1;
      *reinterpret_cast<uint2*>(&Ks[nb][skey*40+sseg]) = kn;
      unsigned short vs[4];
      *reinterpret_cast<uint2*>(vs) = vn;
      const int kc = skey ^ VSW(sseg);
      Vt[nb][(sseg  )*72+kc]=vs[0]; Vt[nb][(sseg+1)*72+kc]=vs[1];
      Vt[nb][(sseg+2)*72+kc]=vs[2]; Vt[nb][(sseg+3)*72+kc]=vs[3];
    }
    __syncthreads();
  }
#pragma unroll
  for(int r=0;r<4;r++){
    float lsr = __shfl(o2[r], lane & 48, 64);   // broadcast col-0 (row-sum)
    float inv = 1.0f/lsr;
    int row = qtok0 + lg*4 + r;
    unsigned short* orow = obuf + (size_t)br*NTOK*DD + (size_t)row*DD + h*HDD;
    orow[lr]    = f2bf(o0[r]*inv);
    orow[16+lr] = f2bf(o1[r]*inv);
  }
}

// ---------------- launch ----------------
extern "C" void kernel_launch(void* const* d_in, const int* in_sizes, int n_in,
                              void* d_out, int out_size, void* d_ws, size_t ws_size,
                              hipStream_t stream){
  (void)in_sizes; (void)n_in; (void)out_size; (void)ws_size;
  const float* x       = (const float*)d_in[0];
  const float* gr_g    = (const float*)d_in[1];
  const float* gr_b    = (const float*)d_in[2];
  const float* q6_w    = (const float*)d_in[3];
  const float* logtemp = (const float*)d_in[4];
  const float* grp_g   = (const float*)d_in[5];
  const float* grp_b   = (const float*)d_in[6];
  const float* gpw     = (const float*)d_in[7];
  const float* gpb     = (const float*)d_in[8];
  const float* me_g    = (const float*)d_in[9];
  const float* me_b    = (const float*)d_in[10];
  const float* me_gate = (const float*)d_in[11];
  const float* me_val  = (const float*)d_in[12];
  const float* me_out  = (const float*)d_in[13];
  const float* br_in   = (const float*)d_in[14];
  const float* br_outw = (const float*)d_in[15];
  const float* nq_g    = (const float*)d_in[16];
  const float* nq_b    = (const float*)d_in[17];
  const float* nkv_g   = (const float*)d_in[18];
  const float* nkv_b   = (const float*)d_in[19];
  const float* nff_g   = (const float*)d_in[20];
  const float* nff_b   = (const float*)d_in[21];
  const float* brg_w   = (const float*)d_in[22];
  const float* brv_w   = (const float*)d_in[23];
  const float* brf_w   = (const float*)d_in[24];
  const float* br_gate = (const float*)d_in[25];
  const float* on_g    = (const float*)d_in[26];
  const float* on_b    = (const float*)d_in[27];
  const float* out_w   = (const float*)d_in[28];
  float* out = (float*)d_out;
  float* ws  = (float*)d_ws;

  float* coef  = ws;                                        // 49152
  float* part  = ws + 65536;                                // 18432
  unsigned short* gvb6 = (unsigned short*)(ws + 131072);    // 6*8192*256 bf16
  unsigned short* gob  = (unsigned short*)(ws + 6731072);   // 3*NTOK*DD bf16
  unsigned short* qkv  = (unsigned short*)(ws + 9900000);   // 3*8192*384 bf16
  unsigned short* obuf = (unsigned short*)(ws + 14700000);  // 3*8192*128 bf16
  unsigned short* wbf  = (unsigned short*)(ws + 21400000);  // WB_TOT bf16 weights
  unsigned short* xbb  = (unsigned short*)(ws + 23000000);  // 3*NTOK*DD bf16
  unsigned short* gvb2 = (unsigned short*)(ws + 26200000);  // 3*8192*256 bf16
  float* gw    = ws + 32700000;                             // 24576

  // 1/sqrt(32) * log2(e): softmax runs in the exp2 domain (folded into Q weights)
  const float qscale = 0.17677669529663687f * 1.4426950408889634f;

  // 0. one-time weight conversion fp32 -> bf16 (qscale folded into br_in Q rows)
  wconv<<<1072,256,0,stream>>>(me_gate, me_val, me_out, br_in, br_outw,
                               brg_w, brv_w, brf_w, out_w, wbf, qscale);

  // 1. routing (fused LN) + lb
  routing_kernel<<<2048,256,0,stream>>>(x, gr_g, gr_b, q6_w, logtemp,
                                        grp_g, grp_b, gpw, gpb, gw, coef, part);
  lb_kernel<<<1,256,0,stream>>>(part, out + 1048576);

  // 2. MoE: all 6 experts in one dual dispatch; pair-combine into go (bf16)
  gemm_dual<0><<<dim3(4,128,6),256,0,stream>>>(x, wbf+WB_MEGATE, wbf+WB_MEVAL, gvb6,
      NTOK,DFF,DD, me_g, me_b, 0, (size_t)DFF*DD, (size_t)NTOK*DFF, DD);
  gemm_moe2<<<dim3(2,128,3),256,0,stream>>>(gvb6, wbf+WB_MEOUT, gob, coef);

  // 3. bridges: QKV proj (bf16 A), attn, out-proj (bf16 resid/out), FFN (bf16 A), bridge-scale in-place into go
  gemm_mfma<0,1,1,1,0,0,0,1,0><<<dim3(6,128,3),256,0,stream>>>(gob, wbf+WB_BRIN, qkv,
      NTOK,QKVN,DD, nq_g, nq_b, nkv_g, nkv_b,
      0, (size_t)QKVN*DD, (size_t)NTOK*QKVN, DD, 0, 0);
  attn_fused<<<768,512,0,stream>>>(qkv, obuf);
  gemm_mfma<3,0,1,1,0,1,0,0,1><<<dim3(2,128,3),256,0,stream>>>(obuf, wbf+WB_BROUT, xbb,
      NTOK,DD,DD, nullptr, nullptr, gob, nullptr,
      (size_t)NTOK*DD, (size_t)DD*DD, (size_t)NTOK*DD, 0, 0, 0);
  gemm_dual<1><<<dim3(4,128,3),256,0,stream>>>(xbb, wbf+WB_BRG, wbf+WB_BRV, gvb2,
      NTOK,2*DD,DD, nff_g, nff_b, (size_t)NTOK*DD, (size_t)2*DD*DD, (size_t)NTOK*2*DD, DD);
  gemm_mfma<5,0,1,1,0,0,0,0,1><<<dim3(2,128,3),256,0,stream>>>(gvb2, wbf+WB_BRF, gob,
      NTOK,DD,2*DD, nullptr, nullptr, xbb, br_gate,
      (size_t)NTOK*2*DD, (size_t)DD*2*DD, (size_t)NTOK*DD, 0, (size_t)NTOK*DD, 1);

  // 4. final: LN over sum of 3 bf16 go buffers, projection
  gemm_mfma<0,1,1,0,0,0,1,0,0><<<dim3(2,128,1),256,0,stream>>>(gob, wbf+WB_OUTW, out,
      NTOK,DD,DD, on_g, on_b, nullptr, nullptr,
      0, 0, 0, 0, 0, 0);
}

// Round 20
// 168.341 us; speedup vs baseline: 1.1834x; 1.0024x over previous
//
#include <hip/hip_runtime.h>
#include <math.h>

#define DD    128
#define DFF   256
#define NHH   4
#define HDD   32
#define BB    8
#define TT    1024
#define NTOK  (BB*TT)          // 8192
#define LDK   72               // padded LDS row stride (bf16 elements) for GEMM tiles
#define QKVN  384              // fused QKV row width

// bf16 weight workspace offsets (elements)
#define WB_MEGATE 0
#define WB_MEVAL  196608
#define WB_MEOUT  393216
#define WB_BRIN   589824
#define WB_BROUT  737280
#define WB_BRG    786432
#define WB_BRV    884736
#define WB_BRF    983040
#define WB_OUTW   1081344
#define WB_TOT    1097728

typedef __bf16 bf16x8 __attribute__((ext_vector_type(8)));
typedef float  f32x4  __attribute__((ext_vector_type(4)));

// ---------------- wave helpers (wave64) ----------------
__device__ __forceinline__ float wsum(float v){
#pragma unroll
  for(int o=32;o>0;o>>=1) v += __shfl_xor(v,o,64);
  return v;
}
__device__ __forceinline__ float wmaxr(float v){
#pragma unroll
  for(int o=32;o>0;o>>=1) v = fmaxf(v,__shfl_xor(v,o,64));
  return v;
}
__device__ __forceinline__ unsigned short f2bf(float x){
  __bf16 h = (__bf16)x;
  unsigned short u;
  __builtin_memcpy(&u, &h, 2);
  return u;
}
__device__ __forceinline__ float bf2f(unsigned short u){
  unsigned int x = ((unsigned int)u)<<16;
  float f; __builtin_memcpy(&f, &x, 4); return f;
}

// stage 16 consecutive fp32 (global) -> 16 bf16 in LDS
__device__ __forceinline__ void stage16(const float* __restrict__ gp,
                                        unsigned short* __restrict__ dst){
  float4 f0 = *reinterpret_cast<const float4*>(gp);
  float4 f1 = *reinterpret_cast<const float4*>(gp+4);
  float4 f2 = *reinterpret_cast<const float4*>(gp+8);
  float4 f3 = *reinterpret_cast<const float4*>(gp+12);
  float f[16] = {f0.x,f0.y,f0.z,f0.w, f1.x,f1.y,f1.z,f1.w,
                 f2.x,f2.y,f2.z,f2.w, f3.x,f3.y,f3.z,f3.w};
  unsigned short h[16];
#pragma unroll
  for(int j=0;j<16;j++) h[j] = f2bf(f[j]);
  *reinterpret_cast<uint4*>(dst)   = *reinterpret_cast<const uint4*>(h);
  *reinterpret_cast<uint4*>(dst+8) = *reinterpret_cast<const uint4*>(h+8);
}

// stage 16 consecutive bf16 (global) -> LDS (pure copy, 2x16B)
__device__ __forceinline__ void stage16bf(const unsigned short* __restrict__ gp,
                                          unsigned short* __restrict__ dst){
  const uint4* s = reinterpret_cast<const uint4*>(gp);
  *reinterpret_cast<uint4*>(dst)   = s[0];
  *reinterpret_cast<uint4*>(dst+8) = s[1];
}

// stage 16 fp32 from registers with LN affine -> LDS bf16 (fr base must be compile-time)
__device__ __forceinline__ void stageLN(const float* __restrict__ fr,
                                        float mean, float rstd,
                                        const float* __restrict__ g,
                                        const float* __restrict__ b,
                                        unsigned short* __restrict__ dst){
  unsigned short h[16];
#pragma unroll
  for(int j=0;j<16;j++){
    float y = (fr[j]-mean)*rstd*g[j] + b[j];
    h[j] = f2bf(y);
  }
  *reinterpret_cast<uint4*>(dst)   = *reinterpret_cast<const uint4*>(h);
  *reinterpret_cast<uint4*>(dst+8) = *reinterpret_cast<const uint4*>(h+8);
}

// ---------------- one-time weight fp32->bf16 conversion (qscale folded into br_in Q rows) ----------------
__global__ __launch_bounds__(256) void wconv(
    const float* __restrict__ a0, const float* __restrict__ a1, const float* __restrict__ a2,
    const float* __restrict__ a3, const float* __restrict__ a4, const float* __restrict__ a5,
    const float* __restrict__ a6, const float* __restrict__ a7, const float* __restrict__ a8,
    unsigned short* __restrict__ dst, float qsc){
  size_t i = ((size_t)blockIdx.x*256 + threadIdx.x)*4;
  if(i >= WB_TOT) return;
  const float* s; size_t off = i; float sc = 1.0f;
  if(i < WB_MEVAL){ s=a0; }
  else if(i < WB_MEOUT){ s=a1; off = i-WB_MEVAL; }
  else if(i < WB_BRIN ){ s=a2; off = i-WB_MEOUT; }
  else if(i < WB_BROUT){ s=a3; off = i-WB_BRIN;
    int row = (int)(off>>7); if((row % 384) < 128) sc = qsc; }
  else if(i < WB_BRG ){ s=a4; off = i-WB_BROUT; }
  else if(i < WB_BRV ){ s=a5; off = i-WB_BRG; }
  else if(i < WB_BRF ){ s=a6; off = i-WB_BRV; }
  else if(i < WB_OUTW){ s=a7; off = i-WB_BRF; }
  else { s=a8; off = i-WB_OUTW; }
  float4 v = *reinterpret_cast<const float4*>(s + off);
  unsigned short h4[4] = {f2bf(v.x*sc), f2bf(v.y*sc), f2bf(v.z*sc), f2bf(v.w*sc)};
  *reinterpret_cast<uint2*>(dst + i) = *reinterpret_cast<const uint2*>(h4);
}

// ---------------- routing: one wave per token (LN fused) ----------------
__global__ __launch_bounds__(256) void routing_kernel(
    const float* __restrict__ x,
    const float* __restrict__ gr_g, const float* __restrict__ gr_b,
    const float* __restrict__ q6,   const float* __restrict__ logtemp,
    const float* __restrict__ grp_g,const float* __restrict__ grp_b,
    const float* __restrict__ gpw,  const float* __restrict__ gpb,
    float* __restrict__ gw_out, float* __restrict__ coef, float* __restrict__ part){
  __shared__ float sp[4][9];
  int lane = threadIdx.x & 63;
  int wv   = threadIdx.x >> 6;
  int t    = (blockIdx.x<<2) + wv;
  const float* xr = x + (size_t)t*DD;
  float r0 = xr[lane], r1 = xr[lane+64];
  float mn = wsum(r0+r1) * (1.0f/DD);
  float d0 = r0-mn, d1 = r1-mn;
  float vv = wsum(d0*d0 + d1*d1) * (1.0f/DD);
  float rstd = rsqrtf(vv + 1e-5f);
  float x0 = d0*rstd, x1 = d1*rstd;
  float h0 = x0*gr_g[lane]+gr_b[lane];
  float h1 = x1*gr_g[lane+64]+gr_b[lane+64];
  float sb[6];
#pragma unroll
  for(int j=0;j<6;j++){
    float p = h0*q6[j*DD+lane] + h1*q6[j*DD+lane+64];
    sb[j] = tanhf(wsum(p));
  }
  float sim = 0.f;
#pragma unroll
  for(int j=0;j<6;j++) sim += ((lane>>(5-j))&1) ? sb[j] : -sb[j];
  float temp = expf(logtemp[0]); temp = fminf(fmaxf(temp,0.1f),5.0f);
  float mx = wmaxr(sim);
  float p  = expf((sim-mx)/temp);
  float w  = p / wsum(p);
  float sh[6];
#pragma unroll
  for(int j=0;j<6;j++) sh[j] = wsum(((lane>>(5-j))&1) ? w : -w);
  const float A0[6]={0,1,1,0,1,1}, A1[6]={0,-1,0,1,0,0}, A2[6]={-1,0,-1,-1,0,-1};
  float l0=0,l1=0,l2=0;
#pragma unroll
  for(int j=0;j<6;j++){ l0+=sh[j]*A0[j]; l1+=sh[j]*A1[j]; l2+=sh[j]*A2[j]; }
  float m3 = fmaxf(l0,fmaxf(l1,l2));
  float e0=expf(l0-m3), e1=expf(l1-m3), e2=expf(l2-m3);
  float inv3 = 1.0f/(e0+e1+e2);
  float g0=e0*inv3, g1=e1*inv3, g2=e2*inv3;
  if(lane==0){ gw_out[t*3]=g0; gw_out[t*3+1]=g1; gw_out[t*3+2]=g2; }
  float gwv[3]={g0,g1,g2};
  float pw[6];
#pragma unroll
  for(int g=0; g<3; g++){
    float hg0 = x0*grp_g[g*DD+lane]    + grp_b[g*DD+lane];
    float hg1 = x1*grp_g[g*DD+lane+64] + grp_b[g*DD+lane+64];
    float q0 = wsum(hg0*gpw[(g*2+0)*DD+lane] + hg1*gpw[(g*2+0)*DD+lane+64]) + gpb[g*2+0];
    float q1 = wsum(hg0*gpw[(g*2+1)*DD+lane] + hg1*gpw[(g*2+1)*DD+lane+64]) + gpb[g*2+1];
    float mm = fmaxf(q0,q1);
    float a0 = expf(q0-mm), a1 = expf(q1-mm);
    float inv = 1.0f/(a0+a1);
    float w0 = a0*inv, w1 = a1*inv;
    pw[g*2]=w0; pw[g*2+1]=w1;
    float invs = 1.0f/(w0+w1+1e-8f);
    if(lane==0){
      coef[(size_t)(2*g  )*NTOK + t] = gwv[g]*w0*invs;
      coef[(size_t)(2*g+1)*NTOK + t] = gwv[g]*w1*invs;
    }
  }
  if(lane==0){
    sp[wv][0]=g0; sp[wv][1]=g1; sp[wv][2]=g2;
#pragma unroll
    for(int k=0;k<6;k++) sp[wv][3+k]=pw[k];
  }
  __syncthreads();
  if(threadIdx.x<9){
    part[blockIdx.x*9+threadIdx.x] =
      sp[0][threadIdx.x]+sp[1][threadIdx.x]+sp[2][threadIdx.x]+sp[3][threadIdx.x];
  }
}

// ---------------- load-balance loss reduce (deterministic, parallel) ----------------
__global__ __launch_bounds__(256) void lb_kernel(const float* __restrict__ part, float* __restrict__ outlb){
  __shared__ float sm[4][9];
  float acc[9] = {};
  for(int i=threadIdx.x; i<2048; i+=256){
#pragma unroll
    for(int c=0;c<9;c++) acc[c] += part[i*9+c];
  }
#pragma unroll
  for(int c=0;c<9;c++) acc[c] = wsum(acc[c]);
  int wv = threadIdx.x>>6, lane = threadIdx.x&63;
  if(lane==0){
#pragma unroll
    for(int c=0;c<9;c++) sm[wv][c]=acc[c];
  }
  __syncthreads();
  if(threadIdx.x==0){
    const float invN = 1.0f/(float)NTOK;
    float lb=0;
#pragma unroll
    for(int c=0;c<9;c++){
      float s = sm[0][c]+sm[1][c]+sm[2][c]+sm[3][c];
      float mw = s*invN;
      lb -= mw*logf(mw+1e-8f);
    }
    outlb[0] = lb*0.01f;
  }
}

// ---------------- bf16 MFMA GEMM (z-batched): C = epi(LN?(A) @ W^T), W pre-converted bf16 ----------------
// MODE 0: store  3: resid+acc  5: in-place C += BW*sigmoid(gptr[0])*(resid+acc)  (bf16 r-m-w)
// LN=1: K==128, LN fused (A fp32 unless ABF). SUM=1 (with LN+ABF): A-row = sum of 3 bf16 go rows.
// ABF=1: A bf16. RBF=1: resid bf16. OBF=1: C bf16.
// PSEL/RSEL: 0 = z*stride, 1 = pairsA[z]. QKV=1: blockIdx.x<2 -> Q else KV.
template<int MODE,int LN,int ABF,int OBF,int PSEL,int RSEL,int SUM,int QKV,int RBF>
__global__ __launch_bounds__(256) void gemm_mfma(
    const void* __restrict__ Ap, const unsigned short* __restrict__ W, void* __restrict__ Cp,
    int M, int N, int K,
    const float* __restrict__ sv, const float* __restrict__ bv,
    const void* __restrict__ resid, const float* __restrict__ gptr,
    size_t az, size_t wz, size_t cz, size_t pz, size_t rz, size_t gz){
  __shared__ unsigned short As[64*LDK];
  __shared__ unsigned short Ws[64*LDK];
  const int z = blockIdx.z;
  const float* A = (const float*)Ap;
  const unsigned short* Ab = (const unsigned short*)Ap;
  if(QKV){
    bool isQ = (blockIdx.x < 2);
    int s = isQ ? ((z==1)?1:0) : ((z==0)?1:2);
    A  += (size_t)s*NTOK*DD;
    Ab += (size_t)s*NTOK*DD;
    if(!isQ){ sv = (const float*)resid; bv = gptr; }
  } else if(PSEL==0){ A += z*az; Ab += z*az; }
  else { int s = (z==1)?1:0; A += (size_t)s*NTOK*DD; Ab += (size_t)s*NTOK*DD; }
  W += z*wz;
  float* C = (float*)Cp + z*cz;
  unsigned short* Cb = (unsigned short*)Cp + z*cz;
  const float* rsf = (const float*)resid;
  const unsigned short* rsb = (const unsigned short*)resid;
  if(RSEL==0){ rsf += z*rz; rsb += z*rz; }
  else { int s = (z==1)?1:0; rsf += (size_t)s*NTOK*DD; rsb += (size_t)s*NTOK*DD; }
  sv += z*pz; bv += z*pz;
  const float* gp2 = gptr + z*gz;
  int tid  = threadIdx.x;
  int m0   = blockIdx.y*64, n0 = blockIdx.x*64;
  int w    = tid>>6, lane = tid&63;
  int wr   = (w>>1)*32, wc = (w&1)*32;
  int r    = tid>>2, seg = (tid&3)*16;
  f32x4 acc[2][2] = {};
  auto step = [&](){
#pragma unroll
    for(int kk=0;kk<64;kk+=32){
      int ko = kk + (lane>>4)*8;
      bf16x8 a0 = *reinterpret_cast<const bf16x8*>(&As[(wr    + (lane&15))*LDK + ko]);
      bf16x8 a1 = *reinterpret_cast<const bf16x8*>(&As[(wr+16 + (lane&15))*LDK + ko]);
      bf16x8 b0 = *reinterpret_cast<const bf16x8*>(&Ws[(wc    + (lane&15))*LDK + ko]);
      bf16x8 b1 = *reinterpret_cast<const bf16x8*>(&Ws[(wc+16 + (lane&15))*LDK + ko]);
      acc[0][0] = __builtin_amdgcn_mfma_f32_16x16x32_bf16(a0,b0,acc[0][0],0,0,0);
      acc[0][1] = __builtin_amdgcn_mfma_f32_16x16x32_bf16(a0,b1,acc[0][1],0,0,0);
      acc[1][0] = __builtin_amdgcn_mfma_f32_16x16x32_bf16(a1,b0,acc[1][0],0,0,0);
      acc[1][1] = __builtin_amdgcn_mfma_f32_16x16x32_bf16(a1,b1,acc[1][1],0,0,0);
    }
  };
  if(LN){
    float fr[32]; float mean, rstd;
    if(SUM){
#pragma unroll
      for(int j=0;j<32;j++) fr[j]=0.f;
#pragma unroll
      for(int s=0;s<3;s++){
        const unsigned short* r1 = Ab + (size_t)s*NTOK*DD + (size_t)(m0+r)*K + seg;
#pragma unroll
        for(int j=0;j<16;j++){ fr[j] += bf2f(r1[j]); fr[16+j] += bf2f(r1[64+j]); }
      }
    } else if(ABF){
      const unsigned short* arow = Ab + (size_t)(m0+r)*K + seg;   // K==128
#pragma unroll
      for(int j=0;j<16;j++){ fr[j] = bf2f(arow[j]); fr[16+j] = bf2f(arow[64+j]); }
    } else {
      const float* arow = A + (size_t)(m0+r)*K + seg;   // K==128
#pragma unroll
      for(int j=0;j<4;j++) *reinterpret_cast<float4*>(&fr[j*4])    = *reinterpret_cast<const float4*>(arow + j*4);
#pragma unroll
      for(int j=0;j<4;j++) *reinterpret_cast<float4*>(&fr[16+j*4]) = *reinterpret_cast<const float4*>(arow + 64 + j*4);
    }
    float s1=0.f, s2=0.f;
#pragma unroll
    for(int j=0;j<32;j++){ s1 += fr[j]; s2 += fr[j]*fr[j]; }
    s1 += __shfl_xor(s1,1,64); s1 += __shfl_xor(s1,2,64);
    s2 += __shfl_xor(s2,1,64); s2 += __shfl_xor(s2,2,64);
    mean = s1*(1.0f/DD);
    float var = s2*(1.0f/DD) - mean*mean;
    rstd = rsqrtf(var + 1e-5f);
#pragma unroll
    for(int kh=0; kh<2; ++kh){            // static unroll: fr index compile-time
      __syncthreads();
      stageLN(fr + kh*16, mean, rstd, sv + kh*64 + seg, bv + kh*64 + seg, &As[r*LDK + seg]);
      stage16bf(W + (size_t)(n0+r)*K + kh*64 + seg, &Ws[r*LDK + seg]);
      __syncthreads();
      step();
    }
  } else {
    for(int k0=0;k0<K;k0+=64){
      __syncthreads();
      if(ABF) stage16bf(Ab + (size_t)(m0+r)*K + k0 + seg, &As[r*LDK + seg]);
      else    stage16(A  + (size_t)(m0+r)*K + k0 + seg, &As[r*LDK + seg]);
      stage16bf(W + (size_t)(n0+r)*K + k0 + seg, &Ws[r*LDK + seg]);
      __syncthreads();
      step();
    }
  }
#pragma unroll
  for(int i=0;i<2;i++){
#pragma unroll
    for(int j=0;j<2;j++){
      int mb = m0 + wr + i*16 + (lane>>4)*4;
      int n  = n0 + wc + j*16 + (lane&15);
#pragma unroll
      for(int rg=0;rg<4;rg++){
        int m = mb + rg;
        float v = acc[i][j][rg];
        size_t o = (size_t)m*N + n;
        if(MODE==0){ if(OBF) Cb[o] = f2bf(v); else C[o] = v; }
        else if(MODE==3){
          float rv = RBF ? bf2f(rsb[o]) : rsf[o];
          float res = rv + v;
          if(OBF) Cb[o] = f2bf(res); else C[o] = res;
        }
        else if(MODE==5){
          float gs = (0.5f/3.0f)/(1.0f+expf(-gp2[0]));
          float rv = RBF ? bf2f(rsb[o]) : rsf[o];
          if(OBF) Cb[o] = f2bf(bf2f(Cb[o]) + gs*(rv+v));
          else    C[o] += gs*(rv+v);
        }
      }
    }
  }
}

// ---------------- dual-W bf16 MFMA GEMM (z-batched): C(bf16) = silu(LN(A)@G^T)*(LN(A)@V^T), K==128 ----------------
template<int ABF>
__global__ __launch_bounds__(256) void gemm_dual(
    const void* __restrict__ Ap, const unsigned short* __restrict__ G,
    const unsigned short* __restrict__ V,
    unsigned short* __restrict__ C, int M, int N, int K,
    const float* __restrict__ sv, const float* __restrict__ bv,
    size_t az, size_t wz, size_t cz, size_t pz){
  __shared__ unsigned short As[64*LDK];
  __shared__ unsigned short Gs[64*LDK];
  __shared__ unsigned short Vs[64*LDK];
  const int z = blockIdx.z;
  const float* A = (const float*)Ap + z*az;
  const unsigned short* Ab = (const unsigned short*)Ap + z*az;
  G += z*wz; V += z*wz; C += z*cz; sv += z*pz; bv += z*pz;
  int tid  = threadIdx.x;
  int m0   = blockIdx.y*64, n0 = blockIdx.x*64;
  int w    = tid>>6, lane = tid&63;
  int wr   = (w>>1)*32, wc = (w&1)*32;
  int r    = tid>>2, seg = (tid&3)*16;
  f32x4 accg[2][2] = {};
  f32x4 accv[2][2] = {};
  float fr[32]; float mean, rstd;
  if(ABF){
    const unsigned short* arow = Ab + (size_t)(m0+r)*K + seg;   // K==128
#pragma unroll
    for(int j=0;j<16;j++){ fr[j] = bf2f(arow[j]); fr[16+j] = bf2f(arow[64+j]); }
  } else {
    const float* arow = A + (size_t)(m0+r)*K + seg;   // K==128
#pragma unroll
    for(int j=0;j<4;j++) *reinterpret_cast<float4*>(&fr[j*4])    = *reinterpret_cast<const float4*>(arow + j*4);
#pragma unroll
    for(int j=0;j<4;j++) *reinterpret_cast<float4*>(&fr[16+j*4]) = *reinterpret_cast<const float4*>(arow + 64 + j*4);
  }
  {
    float s1=0.f, s2=0.f;
#pragma unroll
    for(int j=0;j<32;j++){ s1 += fr[j]; s2 += fr[j]*fr[j]; }
    s1 += __shfl_xor(s1,1,64); s1 += __shfl_xor(s1,2,64);
    s2 += __shfl_xor(s2,1,64); s2 += __shfl_xor(s2,2,64);
    mean = s1*(1.0f/DD);
    float var = s2*(1.0f/DD) - mean*mean;
    rstd = rsqrtf(var + 1e-5f);
  }
#pragma unroll
  for(int kh=0; kh<2; ++kh){              // static unroll: fr index compile-time
    int k0 = kh*64;
    __syncthreads();
    stageLN(fr + kh*16, mean, rstd, sv + k0 + seg, bv + k0 + seg, &As[r*LDK + seg]);
    stage16bf(G + (size_t)(n0+r)*K + k0 + seg, &Gs[r*LDK + seg]);
    stage16bf(V + (size_t)(n0+r)*K + k0 + seg, &Vs[r*LDK + seg]);
    __syncthreads();
#pragma unroll
    for(int kk=0;kk<64;kk+=32){
      int ko = kk + (lane>>4)*8;
      bf16x8 a0 = *reinterpret_cast<const bf16x8*>(&As[(wr    + (lane&15))*LDK + ko]);
      bf16x8 a1 = *reinterpret_cast<const bf16x8*>(&As[(wr+16 + (lane&15))*LDK + ko]);
      bf16x8 g0 = *reinterpret_cast<const bf16x8*>(&Gs[(wc    + (lane&15))*LDK + ko]);
      bf16x8 g1 = *reinterpret_cast<const bf16x8*>(&Gs[(wc+16 + (lane&15))*LDK + ko]);
      bf16x8 v0 = *reinterpret_cast<const bf16x8*>(&Vs[(wc    + (lane&15))*LDK + ko]);
      bf16x8 v1 = *reinterpret_cast<const bf16x8*>(&Vs[(wc+16 + (lane&15))*LDK + ko]);
      accg[0][0] = __builtin_amdgcn_mfma_f32_16x16x32_bf16(a0,g0,accg[0][0],0,0,0);
      accg[0][1] = __builtin_amdgcn_mfma_f32_16x16x32_bf16(a0,g1,accg[0][1],0,0,0);
      accg[1][0] = __builtin_amdgcn_mfma_f32_16x16x32_bf16(a1,g0,accg[1][0],0,0,0);
      accg[1][1] = __builtin_amdgcn_mfma_f32_16x16x32_bf16(a1,g1,accg[1][1],0,0,0);
      accv[0][0] = __builtin_amdgcn_mfma_f32_16x16x32_bf16(a0,v0,accv[0][0],0,0,0);
      accv[0][1] = __builtin_amdgcn_mfma_f32_16x16x32_bf16(a0,v1,accv[0][1],0,0,0);
      accv[1][0] = __builtin_amdgcn_mfma_f32_16x16x32_bf16(a1,v0,accv[1][0],0,0,0);
      accv[1][1] = __builtin_amdgcn_mfma_f32_16x16x32_bf16(a1,v1,accv[1][1],0,0,0);
    }
  }
#pragma unroll
  for(int i=0;i<2;i++){
#pragma unroll
    for(int j=0;j<2;j++){
      int mb = m0 + wr + i*16 + (lane>>4)*4;
      int n  = n0 + wc + j*16 + (lane&15);
#pragma unroll
      for(int rg=0;rg<4;rg++){
        float gg = accg[i][j][rg];
        float vv = accv[i][j][rg];
        float sg = gg/(1.0f+expf(-gg));
        C[(size_t)(mb+rg)*N + n] = f2bf(sg*vv);
      }
    }
  }
}

// ---------------- MoE pair-combine GEMM: go[g](bf16) = c0*(A0@W0^T) + c1*(A1@W1^T), K=DFF ----------------
__global__ __launch_bounds__(256) void gemm_moe2(
    const unsigned short* __restrict__ Ab, const unsigned short* __restrict__ Wb,
    unsigned short* __restrict__ Cb, const float* __restrict__ coef){
  __shared__ unsigned short As0[64*LDK];
  __shared__ unsigned short As1[64*LDK];
  __shared__ unsigned short Ws0[64*LDK];
  __shared__ unsigned short Ws1[64*LDK];
  const int g = blockIdx.z;
  const unsigned short* A0 = Ab + (size_t)(2*g)*NTOK*DFF;
  const unsigned short* A1 = A0 + (size_t)NTOK*DFF;
  const unsigned short* W0 = Wb + (size_t)(2*g)*DD*DFF;
  const unsigned short* W1 = W0 + (size_t)DD*DFF;
  unsigned short* C = Cb + (size_t)g*NTOK*DD;
  const float* c0 = coef + (size_t)(2*g)*NTOK;
  const float* c1 = c0 + NTOK;
  int tid  = threadIdx.x;
  int m0   = blockIdx.y*64, n0 = blockIdx.x*64;
  int w    = tid>>6, lane = tid&63;
  int wr   = (w>>1)*32, wc = (w&1)*32;
  int r    = tid>>2, seg = (tid&3)*16;
  f32x4 a0acc[2][2] = {};
  f32x4 a1acc[2][2] = {};
  for(int k0=0;k0<DFF;k0+=64){
    __syncthreads();
    stage16bf(A0 + (size_t)(m0+r)*DFF + k0 + seg, &As0[r*LDK + seg]);
    stage16bf(A1 + (size_t)(m0+r)*DFF + k0 + seg, &As1[r*LDK + seg]);
    stage16bf(W0 + (size_t)(n0+r)*DFF + k0 + seg, &Ws0[r*LDK + seg]);
    stage16bf(W1 + (size_t)(n0+r)*DFF + k0 + seg, &Ws1[r*LDK + seg]);
    __syncthreads();
#pragma unroll
    for(int kk=0;kk<64;kk+=32){
      int ko = kk + (lane>>4)*8;
      bf16x8 x00 = *reinterpret_cast<const bf16x8*>(&As0[(wr    + (lane&15))*LDK + ko]);
      bf16x8 x01 = *reinterpret_cast<const bf16x8*>(&As0[(wr+16 + (lane&15))*LDK + ko]);
      bf16x8 x10 = *reinterpret_cast<const bf16x8*>(&As1[(wr    + (lane&15))*LDK + ko]);
      bf16x8 x11 = *reinterpret_cast<const bf16x8*>(&As1[(wr+16 + (lane&15))*LDK + ko]);
      bf16x8 w00 = *reinterpret_cast<const bf16x8*>(&Ws0[(wc    + (lane&15))*LDK + ko]);
      bf16x8 w01 = *reinterpret_cast<const bf16x8*>(&Ws0[(wc+16 + (lane&15))*LDK + ko]);
      bf16x8 w10 = *reinterpret_cast<const bf16x8*>(&Ws1[(wc    + (lane&15))*LDK + ko]);
      bf16x8 w11 = *reinterpret_cast<const bf16x8*>(&Ws1[(wc+16 + (lane&15))*LDK + ko]);
      a0acc[0][0] = __builtin_amdgcn_mfma_f32_16x16x32_bf16(x00,w00,a0acc[0][0],0,0,0);
      a0acc[0][1] = __builtin_amdgcn_mfma_f32_16x16x32_bf16(x00,w01,a0acc[0][1],0,0,0);
      a0acc[1][0] = __builtin_amdgcn_mfma_f32_16x16x32_bf16(x01,w00,a0acc[1][0],0,0,0);
      a0acc[1][1] = __builtin_amdgcn_mfma_f32_16x16x32_bf16(x01,w01,a0acc[1][1],0,0,0);
      a1acc[0][0] = __builtin_amdgcn_mfma_f32_16x16x32_bf16(x10,w10,a1acc[0][0],0,0,0);
      a1acc[0][1] = __builtin_amdgcn_mfma_f32_16x16x32_bf16(x10,w11,a1acc[0][1],0,0,0);
      a1acc[1][0] = __builtin_amdgcn_mfma_f32_16x16x32_bf16(x11,w10,a1acc[1][0],0,0,0);
      a1acc[1][1] = __builtin_amdgcn_mfma_f32_16x16x32_bf16(x11,w11,a1acc[1][1],0,0,0);
    }
  }
#pragma unroll
  for(int i=0;i<2;i++){
#pragma unroll
    for(int j=0;j<2;j++){
      int mb = m0 + wr + i*16 + (lane>>4)*4;
      int n  = n0 + wc + j*16 + (lane&15);
#pragma unroll
      for(int rg=0;rg<4;rg++){
        int m = mb + rg;
        C[(size_t)m*DD + n] = f2bf(c0[m]*a0acc[i][j][rg] + c1[m]*a1acc[i][j][rg]);
      }
    }
  }
}

// ---------------- fused MFMA flash attention: 8 waves (128 q-rows), dbuf K/V, 1 barrier/tile ----------------
// grid 768 flat, XCD-aware: residue n%8 owns 12 complete (h,b,br) groups of 8 q-blocks.
// T5: s_setprio(1) around MFMA clusters (8-wave role diversity regime).
#define PSW(row) (((row)&8)<<1)              // Ps col ^= 16 when row bit3 set
#define VSW(row) ((((row)>>3)&3)<<3)         // Vt col ^= 8*((row>>3)&3)
__global__ __launch_bounds__(512) void attn_fused(
    const unsigned short* __restrict__ qkv,
    unsigned short* __restrict__ obuf){
  __shared__ __align__(16) unsigned short Ks[2][64*40];
  __shared__ __align__(16) unsigned short Vt[2][32*72];
  __shared__ __align__(16) unsigned short Vones[16*72];
  __shared__ __align__(16) unsigned short Ps[8][16*72];
  const int tid = threadIdx.x;
  const int w = tid>>6, lane = tid&63;
  const int lr = lane&15, lg = lane>>4;
  // XCD-aware decode: n%8 = residue; each residue owns 12 groups of 8 q-blocks (bijective)
  const int n_  = blockIdx.x;
  const int kx  = n_ & 7, jx = n_ >> 3;        // jx: 0..95
  const int grp = kx*12 + (jx>>3);             // 0..95
  const int bx  = jx & 7;
  const int h   = grp & 3;
  const int b   = (grp>>2) & 7;
  const int br  = grp >> 5;
  const int qtok0 = b*TT + bx*128 + w*16;
  for(int idx=tid; idx<16*72; idx+=512)
    Vones[idx] = (idx < 64) ? (unsigned short)0x3F80 : (unsigned short)0;
  const unsigned short* qp = qkv + (size_t)br*NTOK*QKVN + (size_t)(qtok0 + lr)*QKVN + h*HDD + lg*8;
  bf16x8 qa = *reinterpret_cast<const bf16x8*>(qp);
  f32x4 o0 = {}, o1 = {}, o2 = {};
  float m[4] = {-1e30f,-1e30f,-1e30f,-1e30f};
  const unsigned short* KVbase = qkv + (size_t)br*NTOK*QKVN + (size_t)(b*TT)*QKVN + DD + h*HDD;
  const int skey = tid>>3, sseg = (tid&7)*4;   // one 8B K + one 8B V load per thread

  // prologue: stage tile 0 into buffer 0
  {
    const unsigned short* s0 = KVbase + (size_t)skey*QKVN + sseg;
    uint2 kv = *reinterpret_cast<const uint2*>(s0);
    uint2 vv = *reinterpret_cast<const uint2*>(s0 + DD);
    *reinterpret_cast<uint2*>(&Ks[0][skey*40+sseg]) = kv;
    unsigned short vs[4];
    *reinterpret_cast<uint2*>(vs) = vv;
    const int kc = skey ^ VSW(sseg);
    Vt[0][(sseg  )*72+kc]=vs[0]; Vt[0][(sseg+1)*72+kc]=vs[1];
    Vt[0][(sseg+2)*72+kc]=vs[2]; Vt[0][(sseg+3)*72+kc]=vs[3];
  }
  __syncthreads();

  for(int t=0; t<16; t++){
    const int cur = t & 1;
    // issue next-tile loads early (latency hides under compute)
    uint2 kn, vn;
    if(t < 15){
      const unsigned short* s0 = KVbase + (size_t)((t+1)*64 + skey)*QKVN + sseg;
      kn = *reinterpret_cast<const uint2*>(s0);
      vn = *reinterpret_cast<const uint2*>(s0 + DD);
    }
    // QK^T  (T5: prefer MFMA-issuing waves)
    f32x4 s[4];
    __builtin_amdgcn_s_setprio(1);
#pragma unroll
    for(int f=0;f<4;f++){
      bf16x8 kb = *reinterpret_cast<const bf16x8*>(&Ks[cur][(f*16+lr)*40 + lg*8]);
      f32x4 z = {};
      s[f] = __builtin_amdgcn_mfma_f32_16x16x32_bf16(qa,kb,z,0,0,0);
    }
    __builtin_amdgcn_s_setprio(0);
    // defer-max softmax
    float tmax[4]; bool need=false;
#pragma unroll
    for(int r=0;r<4;r++){
      tmax[r] = fmaxf(fmaxf(s[0][r],s[1][r]),fmaxf(s[2][r],s[3][r]));
      need = need || (tmax[r] > m[r] + 8.0f);
    }
    if(__any(need)){
#pragma unroll
      for(int r=0;r<4;r++){
        float t2 = tmax[r];
#pragma unroll
        for(int off=1;off<16;off<<=1) t2 = fmaxf(t2,__shfl_xor(t2,off,64));
        float nm = fmaxf(m[r],t2);
        float sc = __builtin_amdgcn_exp2f(m[r]-nm);
        m[r] = nm; o0[r] *= sc; o1[r] *= sc; o2[r] *= sc;
      }
    }
#pragma unroll
    for(int r=0;r<4;r++){
      const int q = lg*4+r;
      const int cw = PSW(q);
#pragma unroll
      for(int f=0;f<4;f++){
        float p = __builtin_amdgcn_exp2f(s[f][r]-m[r]);
        Ps[w][q*72 + ((f*16+lr)^cw)] = f2bf(p);
      }
    }
    // PV + row-sum  (T5: prefer MFMA-issuing waves)
    const int pw_ = PSW(lr);
    bf16x8 pa0 = *reinterpret_cast<const bf16x8*>(&Ps[w][lr*72 + ((lg*8   )^pw_)]);
    bf16x8 pa1 = *reinterpret_cast<const bf16x8*>(&Ps[w][lr*72 + ((lg*8+32)^pw_)]);
    __builtin_amdgcn_s_setprio(1);
    {
      const int r_ = lr, vw = VSW(r_);
      bf16x8 vb0 = *reinterpret_cast<const bf16x8*>(&Vt[cur][r_*72 + ((lg*8   )^vw)]);
      bf16x8 vb1 = *reinterpret_cast<const bf16x8*>(&Vt[cur][r_*72 + ((lg*8+32)^vw)]);
      o0 = __builtin_amdgcn_mfma_f32_16x16x32_bf16(pa0,vb0,o0,0,0,0);
      o0 = __builtin_amdgcn_mfma_f32_16x16x32_bf16(pa1,vb1,o0,0,0,0);
    }
    {
      const int r_ = 16+lr, vw = VSW(r_);
      bf16x8 vb0 = *reinterpret_cast<const bf16x8*>(&Vt[cur][(r_-16)*72 + ((lg*8   )^vw)+16*72]);
      bf16x8 vb1 = *reinterpret_cast<const bf16x8*>(&Vt[cur][(r_-16)*72 + ((lg*8+32)^vw)+16*72]);
      o1 = __builtin_amdgcn_mfma_f32_16x16x32_bf16(pa0,vb0,o1,0,0,0);
      o1 = __builtin_amdgcn_mfma_f32_16x16x32_bf16(pa1,vb1,o1,0,0,0);
    }
    {
      const int r_ = 32+lr, vw = VSW(r_);
      bf16x8 vb0 = *reinterpret_cast<const bf16x8*>(&Vones[lr*72 + ((lg*8   )^vw)]);
      bf16x8 vb1 = *reinterpret_cast<const bf16x8*>(&Vones[lr*72 + ((lg*8+32)^vw)]);
      o2 = __builtin_amdgcn_mfma_f32_16x16x32_bf16(pa0,vb0,o2,0,0,0);
      o2 = __builtin_amdgcn_mfma_f32_16x16x32_bf16(pa1,vb1,o2,0,0,0);
    }
    __builtin_amdgcn_s_setprio(0);
    // write next tile into alternate buffer (loads completed under compute)
    if(t < 15){
      const int nb = cur ^ 1;
      *reinterpret_cast<uint2*>(&Ks[nb][skey*40+sseg]) = kn;
      unsigned short vs[4];
      *reinterpret_cast<uint2*>(vs) = vn;
      const int kc = skey ^ VSW(sseg);
      Vt[nb][(sseg  )*72+kc]=vs[0]; Vt[nb][(sseg+1)*72+kc]=vs[1];
      Vt[nb][(sseg+2)*72+kc]=vs[2]; Vt[nb][(sseg+3)*72+kc]=vs[3];
    }
    __syncthreads();
  }
#pragma unroll
  for(int r=0;r<4;r++){
    float lsr = __shfl(o2[r], lane & 48, 64);   // broadcast col-0 (row-sum)
    float inv = 1.0f/lsr;
    int row = qtok0 + lg*4 + r;
    unsigned short* orow = obuf + (size_t)br*NTOK*DD + (size_t)row*DD + h*HDD;
    orow[lr]    = f2bf(o0[r]*inv);
    orow[16+lr] = f2bf(o1[r]*inv);
  }
}

// ---------------- launch ----------------
extern "C" void kernel_launch(void* const* d_in, const int* in_sizes, int n_in,
                              void* d_out, int out_size, void* d_ws, size_t ws_size,
                              hipStream_t stream){
  (void)in_sizes; (void)n_in; (void)out_size; (void)ws_size;
  const float* x       = (const float*)d_in[0];
  const float* gr_g    = (const float*)d_in[1];
  const float* gr_b    = (const float*)d_in[2];
  const float* q6_w    = (const float*)d_in[3];
  const float* logtemp = (const float*)d_in[4];
  const float* grp_g   = (const float*)d_in[5];
  const float* grp_b   = (const float*)d_in[6];
  const float* gpw     = (const float*)d_in[7];
  const float* gpb     = (const float*)d_in[8];
  const float* me_g    = (const float*)d_in[9];
  const float* me_b    = (const float*)d_in[10];
  const float* me_gate = (const float*)d_in[11];
  const float* me_val  = (const float*)d_in[12];
  const float* me_out  = (const float*)d_in[13];
  const float* br_in   = (const float*)d_in[14];
  const float* br_outw = (const float*)d_in[15];
  const float* nq_g    = (const float*)d_in[16];
  const float* nq_b    = (const float*)d_in[17];
  const float* nkv_g   = (const float*)d_in[18];
  const float* nkv_b   = (const float*)d_in[19];
  const float* nff_g   = (const float*)d_in[20];
  const float* nff_b   = (const float*)d_in[21];
  const float* brg_w   = (const float*)d_in[22];
  const float* brv_w   = (const float*)d_in[23];
  const float* brf_w   = (const float*)d_in[24];
  const float* br_gate = (const float*)d_in[25];
  const float* on_g    = (const float*)d_in[26];
  const float* on_b    = (const float*)d_in[27];
  const float* out_w   = (const float*)d_in[28];
  float* out = (float*)d_out;
  float* ws  = (float*)d_ws;

  float* coef  = ws;                                        // 49152
  float* part  = ws + 65536;                                // 18432
  unsigned short* gvb6 = (unsigned short*)(ws + 131072);    // 6*8192*256 bf16
  unsigned short* gob  = (unsigned short*)(ws + 6731072);   // 3*NTOK*DD bf16
  unsigned short* qkv  = (unsigned short*)(ws + 9900000);   // 3*8192*384 bf16
  unsigned short* obuf = (unsigned short*)(ws + 14700000);  // 3*8192*128 bf16
  unsigned short* wbf  = (unsigned short*)(ws + 21400000);  // WB_TOT bf16 weights
  unsigned short* xbb  = (unsigned short*)(ws + 23000000);  // 3*NTOK*DD bf16
  unsigned short* gvb2 = (unsigned short*)(ws + 26200000);  // 3*8192*256 bf16
  float* gw    = ws + 32700000;                             // 24576

  // 1/sqrt(32) * log2(e): softmax runs in the exp2 domain (folded into Q weights)
  const float qscale = 0.17677669529663687f * 1.4426950408889634f;

  // 0. one-time weight conversion fp32 -> bf16 (qscale folded into br_in Q rows)
  wconv<<<1072,256,0,stream>>>(me_gate, me_val, me_out, br_in, br_outw,
                               brg_w, brv_w, brf_w, out_w, wbf, qscale);

  // 1. routing (fused LN) + lb
  routing_kernel<<<2048,256,0,stream>>>(x, gr_g, gr_b, q6_w, logtemp,
                                        grp_g, grp_b, gpw, gpb, gw, coef, part);
  lb_kernel<<<1,256,0,stream>>>(part, out + 1048576);

  // 2. MoE: all 6 experts in one dual dispatch; pair-combine into go (bf16)
  gemm_dual<0><<<dim3(4,128,6),256,0,stream>>>(x, wbf+WB_MEGATE, wbf+WB_MEVAL, gvb6,
      NTOK,DFF,DD, me_g, me_b, 0, (size_t)DFF*DD, (size_t)NTOK*DFF, DD);
  gemm_moe2<<<dim3(2,128,3),256,0,stream>>>(gvb6, wbf+WB_MEOUT, gob, coef);

  // 3. bridges: QKV proj (bf16 A), attn, out-proj (bf16 resid/out), FFN (bf16 A), bridge-scale in-place into go
  gemm_mfma<0,1,1,1,0,0,0,1,0><<<dim3(6,128,3),256,0,stream>>>(gob, wbf+WB_BRIN, qkv,
      NTOK,QKVN,DD, nq_g, nq_b, nkv_g, nkv_b,
      0, (size_t)QKVN*DD, (size_t)NTOK*QKVN, DD, 0, 0);
  attn_fused<<<768,512,0,stream>>>(qkv, obuf);
  gemm_mfma<3,0,1,1,0,1,0,0,1><<<dim3(2,128,3),256,0,stream>>>(obuf, wbf+WB_BROUT, xbb,
      NTOK,DD,DD, nullptr, nullptr, gob, nullptr,
      (size_t)NTOK*DD, (size_t)DD*DD, (size_t)NTOK*DD, 0, 0, 0);
  gemm_dual<1><<<dim3(4,128,3),256,0,stream>>>(xbb, wbf+WB_BRG, wbf+WB_BRV, gvb2,
      NTOK,2*DD,DD, nff_g, nff_b, (size_t)NTOK*DD, (size_t)2*DD*DD, (size_t)NTOK*2*DD, DD);
  gemm_mfma<5,0,1,1,0,0,0,0,1><<<dim3(2,128,3),256,0,stream>>>(gvb2, wbf+WB_BRF, gob,
      NTOK,DD,2*DD, nullptr, nullptr, xbb, br_gate,
      (size_t)NTOK*2*DD, (size_t)DD*2*DD, (size_t)NTOK*DD, 0, (size_t)NTOK*DD, 1);

  // 4. final: LN over sum of 3 bf16 go buffers, projection
  gemm_mfma<0,1,1,0,0,0,1,0,0><<<dim3(2,128,1),256,0,stream>>>(gob, wbf+WB_OUTW, out,
      NTOK,DD,DD, on_g, on_b, nullptr, nullptr,
      0, 0, 0, 0, 0, 0);
}